// Round 9
// baseline (1015.298 us; speedup 1.0000x reference)
//
#include <hip/hip_runtime.h>
#include <hip/hip_bf16.h>
#include <cstdint>

// ---------------------------------------------------------------------------
// HGAT: 2-layer hetero GAT (user<->movie), H=4 heads, C=32, HC=128.
// GEMMs on bf16 MFMA 16x16x32, fp32 accumulate; folded attention matrix V
// appended to packed weights so hs+att come out of one GEMM (MODE 0).
// Edge aggregation: CSR by dst, 16 lanes/node, ushort8 (16B) loads; nodes
// assigned to lane groups in DEGREE-SORTED order (bucket sort, 256 bins) so
// the 4 nodes co-scheduled in a wave have ~equal degree -- kills the
// E[max4]/E[deg] SIMT idle waste (~30% at Poisson(5), ~17% at Poisson(25)).
// CSR build: rank-from-hist (atomic-free fill), dst-windowed scatter.
// Softmax max-subtraction skipped (logits bounded; shift-invariant; validated).
// ---------------------------------------------------------------------------

#define HC 128
#define HH 4
#define NWIN 4   // fill scatter windows

typedef __attribute__((ext_vector_type(8))) short bf16x8;
typedef __attribute__((ext_vector_type(4))) float f32x4;

__device__ __forceinline__ short f2bf(float f) {
    return __builtin_bit_cast(short, __float2bfloat16(f));
}
__device__ __forceinline__ float bf2f(ushort u) {
    return __builtin_bit_cast(float, ((unsigned)u) << 16);
}

// ---------------- fold attention: v[k, coff+h] = sum_c W[k,h*32+c]*a[h,c] ---
struct VT { const float* W[8]; const float* a[8]; float* v[8]; };
__global__ void make_v_all_k(VT t) {
    int gid = blockIdx.x * 256 + threadIdx.x;
    int task, base;
    if (gid < 1024) { task = gid >> 8; base = gid & 255; }
    else if (gid < 3072) { int g = gid - 1024; task = 4 + (g >> 9); base = g & 511; }
    else return;
    int k = base >> 2, h = base & 3;
    int coff = (task & 1) * 4;
    const float* wr = t.W[task] + (size_t)k * HC + h * 32;
    const float* ar = t.a[task] + h * 32;
    float s = 0.f;
    #pragma unroll
    for (int c = 0; c < 32; ++c) s = fmaf(wr[c], ar[c], s);
    t.v[task][k * 8 + coff + h] = s;
}

// ---------------- pack Wb[n][k] = bf16(W[k][n]); rows Nw..Nw+7 = V ----------
struct PT { const float* W[5]; const float* V[5]; ushort* Wb[5];
            int K[5]; int Nw[5]; int start[6]; };
__global__ void pack_all_k(PT t) {
    int gid = blockIdx.x * 256 + threadIdx.x;
    if (gid >= t.start[5]) return;
    int task = 0;
    while (gid >= t.start[task + 1]) ++task;
    int loc = gid - t.start[task];
    int K = t.K[task], Nw = t.Nw[task];
    int n = loc / K, k = loc % K;
    float v = 0.f;
    if (n < Nw) v = t.W[task][(size_t)k * Nw + n];
    else if (t.V[task] != nullptr && n < Nw + 8) v = t.V[task][k * 8 + (n - Nw)];
    t.Wb[task][loc] = (ushort)f2bf(v);
}

// ---------------- dual-segment bf16 MFMA GEMM -------------------------------
// MODE 0: hs out (bf16 [M,128]) + atts fp32 [M,4] + attd fp32 [M,4].
// MODE 1: fp32 C[M,ldc] + bias. ABF: A dense bf16 (ushort), else fp32 (+idx).
template <int NT, int MODE, bool ABF>
__global__ __launch_bounds__(256) void gemm_dual_k(
    const void* A0, const int* idx0, const ushort* Wb0, ushort* hsb0,
    float* atts0, float* attd0, float* C0, const float* bias0, int M0, int nb0,
    const void* A1, const int* idx1, const ushort* Wb1, ushort* hsb1,
    float* atts1, float* attd1, float* C1, const float* bias1, int M1,
    int K, int ldc) {
    const void* A; const int* aidx; const ushort* Wb; ushort* hsb;
    float* atts; float* attd; float* C; const float* bias; int M, bid;
    if ((int)blockIdx.x < nb0) {
        A = A0; aidx = idx0; Wb = Wb0; hsb = hsb0; atts = atts0; attd = attd0;
        C = C0; bias = bias0; M = M0; bid = blockIdx.x;
    } else {
        A = A1; aidx = idx1; Wb = Wb1; hsb = hsb1; atts = atts1; attd = attd1;
        C = C1; bias = bias1; M = M1; bid = blockIdx.x - nb0;
    }
    int lane = threadIdx.x & 63;
    int wave = threadIdx.x >> 6;
    int m_base = bid * 128 + wave * 32;
    int lm = lane & 15;      // A row-in-tile / C col-in-tile
    int kg = lane >> 4;      // k-group (8 consecutive k)

    int r0 = m_base + lm, r1 = r0 + 16;
    int cr0 = r0 < M ? r0 : M - 1;
    int cr1 = r1 < M ? r1 : M - 1;
    int row0 = aidx ? aidx[cr0] : cr0;
    int row1 = aidx ? aidx[cr1] : cr1;
    const ushort* bp = Wb + (size_t)lm * K + kg * 8;

    f32x4 acc[2][NT] = {};
    for (int k0 = 0; k0 < K; k0 += 32) {
        bf16x8 a[2];
        if (ABF) {
            const ushort* a0p = (const ushort*)A + (size_t)row0 * K + kg * 8;
            const ushort* a1p = (const ushort*)A + (size_t)row1 * K + kg * 8;
            a[0] = *reinterpret_cast<const bf16x8*>(a0p + k0);
            a[1] = *reinterpret_cast<const bf16x8*>(a1p + k0);
        } else {
            const float* a0p = (const float*)A + (size_t)row0 * K + kg * 8;
            const float* a1p = (const float*)A + (size_t)row1 * K + kg * 8;
            float af[2][8];
            *reinterpret_cast<float4*>(&af[0][0]) = *reinterpret_cast<const float4*>(a0p + k0);
            *reinterpret_cast<float4*>(&af[0][4]) = *reinterpret_cast<const float4*>(a0p + k0 + 4);
            *reinterpret_cast<float4*>(&af[1][0]) = *reinterpret_cast<const float4*>(a1p + k0);
            *reinterpret_cast<float4*>(&af[1][4]) = *reinterpret_cast<const float4*>(a1p + k0 + 4);
            #pragma unroll
            for (int mi = 0; mi < 2; ++mi)
                #pragma unroll
                for (int j = 0; j < 8; ++j) a[mi][j] = f2bf(af[mi][j]);
        }
        #pragma unroll
        for (int nt = 0; nt < NT; ++nt) {
            bf16x8 b = *reinterpret_cast<const bf16x8*>(bp + (size_t)nt * 16 * K + k0);
            acc[0][nt] = __builtin_amdgcn_mfma_f32_16x16x32_bf16(a[0], b, acc[0][nt], 0, 0, 0);
            acc[1][nt] = __builtin_amdgcn_mfma_f32_16x16x32_bf16(a[1], b, acc[1][nt], 0, 0, 0);
        }
    }
    #pragma unroll
    for (int mi = 0; mi < 2; ++mi) {
        int rowb = m_base + mi * 16 + kg * 4;
        if (MODE == 0) {
            #pragma unroll
            for (int nt = 0; nt < NT - 1; ++nt) {
                int col = nt * 16 + lm;
                #pragma unroll
                for (int r = 0; r < 4; ++r) {
                    int row = rowb + r;
                    if (row < M) hsb[(size_t)row * HC + col] = (ushort)f2bf(acc[mi][nt][r]);
                }
            }
            #pragma unroll
            for (int r = 0; r < 4; ++r) {
                int row = rowb + r;
                if (row < M) {
                    float v = acc[mi][NT - 1][r];
                    if (lm < 4) atts[(size_t)row * 4 + lm] = v;
                    else if (lm < 8) attd[(size_t)row * 4 + (lm - 4)] = v;
                }
            }
        } else {
            #pragma unroll
            for (int nt = 0; nt < NT; ++nt) {
                int col = nt * 16 + lm;
                float bv = bias[col];
                #pragma unroll
                for (int r = 0; r < 4; ++r) {
                    int row = rowb + r;
                    if (row < M) C[(size_t)row * ldc + col] = acc[mi][nt][r] + bv;
                }
            }
        }
    }
}

// ---------------- CSR build (dual edge-type) --------------------------------
__global__ void hist_dual_k(const int* __restrict__ d0, int* __restrict__ c0, int E0,
                            const int* __restrict__ d1, int* __restrict__ c1, int E1,
                            int* __restrict__ rank) {
    int e = blockIdx.x * 256 + threadIdx.x;
    if (e < E0) rank[e] = atomicAdd(&c0[d0[e]], 1);
    else if (e - E0 < E1) rank[e] = atomicAdd(&c1[d1[e - E0]], 1);
}

__device__ __forceinline__ void scan_block_body(
    const int* deg, int n, int len, int* out, int* partial, int b) {
    __shared__ int s[256];
    int i = b * 256 + threadIdx.x;
    int v = (i < n) ? deg[i] : 0;
    s[threadIdx.x] = v;
    __syncthreads();
    for (int off = 1; off < 256; off <<= 1) {
        int t = (threadIdx.x >= off) ? s[threadIdx.x - off] : 0;
        __syncthreads();
        s[threadIdx.x] += t;
        __syncthreads();
    }
    if (i < len) out[i] = s[threadIdx.x] - v;
    if (threadIdx.x == 255) partial[b] = s[255];
}

__global__ void scan_block_dual_k(const int* dM, int nM, int* rsM, int* pM, int nbM,
                                  const int* dU, int nU, int* rsU, int* pU) {
    if ((int)blockIdx.x < nbM)
        scan_block_body(dM, nM, nM + 1, rsM, pM, blockIdx.x);
    else
        scan_block_body(dU, nU, nU + 1, rsU, pU, blockIdx.x - nbM);
}

__global__ void scan_partial_dual_k(int* pM, int nbM, int* pU, int nbU) {
    __shared__ int s[512];
    int t = threadIdx.x;
    for (int seg = 0; seg < 2; ++seg) {
        int* p = seg ? pU : pM;
        int nb = seg ? nbU : nbM;
        int v = (t < nb) ? p[t] : 0;
        s[t] = v;
        __syncthreads();
        for (int off = 1; off < 512; off <<= 1) {
            int x = (t >= off) ? s[t - off] : 0;
            __syncthreads();
            s[t] += x;
            __syncthreads();
        }
        if (t < nb) p[t] = s[t] - v;
        __syncthreads();
    }
}

__global__ void add_off_dual_k(int* __restrict__ oM, const int* __restrict__ pM,
                               int lenM, int nbM,
                               int* __restrict__ oU, const int* __restrict__ pU,
                               int lenU) {
    int b = blockIdx.x;
    if (b < nbM) {
        int i = b * 256 + threadIdx.x;
        if (i < lenM) oM[i] += pM[b];
    } else {
        b -= nbM;
        int i = b * 256 + threadIdx.x;
        if (i < lenU) oU[i] += pU[b];
    }
}

// atomic-free, dst-windowed scatter: window w handles dst in [w*n/NWIN, ...).
__global__ void fill_dual_k(const int* __restrict__ s0, const int* __restrict__ d0,
                            const int* __restrict__ rs0, int* __restrict__ csr0,
                            int E0, int n0,
                            const int* __restrict__ s1, const int* __restrict__ d1,
                            const int* __restrict__ rs1, int* __restrict__ csr1,
                            int E1, int n1,
                            const int* __restrict__ rank) {
    int e = blockIdx.x * 256 + threadIdx.x;
    int w = blockIdx.y;
    if (e < E0) {
        int d = d0[e];
        int lo = (int)((long)w * n0 / NWIN), hi = (int)((long)(w + 1) * n0 / NWIN);
        if (d >= lo && d < hi) csr0[rs0[d] + rank[e]] = s0[e];
    } else if (e - E0 < E1) {
        int e1 = e - E0;
        int d = d1[e1];
        int lo = (int)((long)w * n1 / NWIN), hi = (int)((long)(w + 1) * n1 / NWIN);
        if (d >= lo && d < hi) csr1[rs1[d] + rank[e]] = s1[e1];
    }
}

// ---------------- degree-sorted node permutation (bucket sort, 256 bins) ----
// dh[0..255] = movie bins, dh[256..511] = user bins; dcnt same layout.
__global__ void deghist_dual_k(const int* __restrict__ c0, int n0,
                               const int* __restrict__ c1, int n1,
                               int* __restrict__ dh) {
    int i = blockIdx.x * 256 + threadIdx.x;
    if (i < n0) atomicAdd(&dh[min(c0[i], 255)], 1);
    else if (i - n0 < n1) atomicAdd(&dh[256 + min(c1[i - n0], 255)], 1);
}

__global__ void degscan_k(int* __restrict__ dh) {
    __shared__ int s[256];
    int t = threadIdx.x;
    for (int seg = 0; seg < 2; ++seg) {
        int* p = dh + seg * 256;
        int v = p[t];
        s[t] = v;
        __syncthreads();
        for (int off = 1; off < 256; off <<= 1) {
            int x = (t >= off) ? s[t - off] : 0;
            __syncthreads();
            s[t] += x;
            __syncthreads();
        }
        p[t] = s[t] - v;   // exclusive bin starts
        __syncthreads();
    }
}

__global__ void degscatter_dual_k(const int* __restrict__ c0, int n0,
                                  int* __restrict__ perm0,
                                  const int* __restrict__ c1, int n1,
                                  int* __restrict__ perm1,
                                  const int* __restrict__ dh,
                                  int* __restrict__ dcnt) {
    int i = blockIdx.x * 256 + threadIdx.x;
    if (i < n0) {
        int d = min(c0[i], 255);
        perm0[dh[d] + atomicAdd(&dcnt[d], 1)] = i;
    } else if (i - n0 < n1) {
        int j = i - n0;
        int d = min(c1[j], 255);
        perm1[dh[256 + d] + atomicAdd(&dcnt[256 + d], 1)] = j;
    }
}

// ---------------- per-dst aggregation: 16 lanes/node, ushort8 loads ---------
// Lane c in [0,16): channels 8c..8c+7 (16B load); head h = c>>2. Node ids come
// from the degree-sorted perm so co-scheduled nodes have ~equal degree.
template <bool WF32, bool WBF>
__global__ __launch_bounds__(256) void agg16_dual_k(
    const int* __restrict__ rs0, const int* __restrict__ csr0,
    const int* __restrict__ perm0,
    const ushort* __restrict__ hsb0, const float* __restrict__ atts0,
    const float* __restrict__ attd0, const float* __restrict__ bias0,
    float* __restrict__ out0, ushort* __restrict__ outb0, int n0,
    const int* __restrict__ rs1, const int* __restrict__ csr1,
    const int* __restrict__ perm1,
    const ushort* __restrict__ hsb1, const float* __restrict__ atts1,
    const float* __restrict__ attd1, const float* __restrict__ bias1,
    float* __restrict__ out1, ushort* __restrict__ outb1, int n1) {
    int g = (int)((blockIdx.x * 256u + threadIdx.x) >> 4);   // 16 nodes/block
    const int* rs; const int* csr; const ushort* hsb; const float* atts;
    const float* attd; const float* bias; float* out; ushort* outb; int node;
    if (g < n0) {
        rs = rs0; csr = csr0; hsb = hsb0; atts = atts0; attd = attd0;
        bias = bias0; out = out0; outb = outb0; node = perm0[g];
    } else {
        int j = g - n0;
        if (j >= n1) return;
        rs = rs1; csr = csr1; hsb = hsb1; atts = atts1; attd = attd1;
        bias = bias1; out = out1; outb = outb1; node = perm1[j];
    }
    int c = threadIdx.x & 15;    // channels 8c..8c+7
    int h = c >> 2;              // head (32 ch per head, 4 lanes per head)
    float ad = attd[node * 4 + h];
    int s0 = rs[node], s1 = rs[node + 1];
    float acc[8] = {};
    float wsum = 0.f;
    int i = s0;
    for (; i + 4 <= s1; i += 4) {            // 4 edge-rows in flight
        int sx[4];
        #pragma unroll
        for (int j = 0; j < 4; ++j) sx[j] = csr[i + j];
        bf16x8 hv[4]; float el[4];
        #pragma unroll
        for (int j = 0; j < 4; ++j) {
            hv[j] = *reinterpret_cast<const bf16x8*>(hsb + (size_t)sx[j] * HC + 8 * c);
            el[j] = atts[(size_t)sx[j] * 4 + h];
        }
        #pragma unroll
        for (int j = 0; j < 4; ++j) {
            float e = el[j] + ad;
            e = e > 0.f ? e : 0.2f * e;
            float w = __expf(e);
            wsum += w;
            #pragma unroll
            for (int k = 0; k < 8; ++k)
                acc[k] = fmaf(w, bf2f((ushort)hv[j][k]), acc[k]);
        }
    }
    for (; i < s1; ++i) {
        int src = csr[i];
        bf16x8 hv = *reinterpret_cast<const bf16x8*>(hsb + (size_t)src * HC + 8 * c);
        float e = atts[(size_t)src * 4 + h] + ad;
        e = e > 0.f ? e : 0.2f * e;
        float w = __expf(e);
        wsum += w;
        #pragma unroll
        for (int k = 0; k < 8; ++k)
            acc[k] = fmaf(w, bf2f((ushort)hv[k]), acc[k]);
    }
    float inv = 1.f / (wsum + 1e-16f);
    float v[8];
    #pragma unroll
    for (int k = 0; k < 8; ++k) {
        v[k] = fmaf(acc[k], inv, bias[8 * c + k]);
        v[k] = v[k] > 0.f ? v[k] : 0.01f * v[k];
    }
    if (WF32) {
        float4 o0 = make_float4(v[0], v[1], v[2], v[3]);
        float4 o1 = make_float4(v[4], v[5], v[6], v[7]);
        reinterpret_cast<float4*>(out + (size_t)node * HC + 8 * c)[0] = o0;
        reinterpret_cast<float4*>(out + (size_t)node * HC + 8 * c)[1] = o1;
    }
    if (WBF) {
        bf16x8 u;
        #pragma unroll
        for (int k = 0; k < 8; ++k) u[k] = f2bf(v[k]);
        *reinterpret_cast<bf16x8*>(outb + (size_t)node * HC + 8 * c) = u;
    }
}

// ---------------------------------------------------------------------------
extern "C" void kernel_launch(void* const* d_in, const int* in_sizes, int n_in,
                              void* d_out, int out_size, void* d_ws, size_t ws_size,
                              hipStream_t stream) {
    const int Nu = in_sizes[0];
    const int Nm = in_sizes[1];
    const int E1 = in_sizes[2];   // um edges
    const int E2 = in_sizes[4];   // mu edges
    const int D  = in_sizes[6] / Nu;   // 64
    const int O  = in_sizes[27];       // 64

    const int*   user_ids  = (const int*)d_in[0];
    const int*   movie_ids = (const int*)d_in[1];
    const int*   um_src    = (const int*)d_in[2];
    const int*   um_dst    = (const int*)d_in[3];
    const int*   mu_src    = (const int*)d_in[4];
    const int*   mu_dst    = (const int*)d_in[5];
    const float* user_emb  = (const float*)d_in[6];
    const float* movie_emb = (const float*)d_in[7];
    const float* l1_um_Wsrc = (const float*)d_in[8];
    const float* l1_um_Wdst = (const float*)d_in[9];
    const float* l1_um_asrc = (const float*)d_in[10];
    const float* l1_um_adst = (const float*)d_in[11];
    const float* l1_um_b    = (const float*)d_in[12];
    const float* l1_mu_Wsrc = (const float*)d_in[13];
    const float* l1_mu_Wdst = (const float*)d_in[14];
    const float* l1_mu_asrc = (const float*)d_in[15];
    const float* l1_mu_adst = (const float*)d_in[16];
    const float* l1_mu_b    = (const float*)d_in[17];
    const float* l2_um_W    = (const float*)d_in[18];
    const float* l2_um_asrc = (const float*)d_in[19];
    const float* l2_um_adst = (const float*)d_in[20];
    const float* l2_um_b    = (const float*)d_in[21];
    const float* l2_mu_W    = (const float*)d_in[22];
    const float* l2_mu_asrc = (const float*)d_in[23];
    const float* l2_mu_adst = (const float*)d_in[24];
    const float* l2_mu_b    = (const float*)d_in[25];
    const float* Wo         = (const float*)d_in[26];
    const float* bo         = (const float*)d_in[27];

    // ---- workspace carve ----
    char* p = (char*)d_ws;
    auto alloc = [&](size_t bytes) { void* r = p; p += (bytes + 255) & ~(size_t)255; return r; };
    ushort* hs_u = (ushort*)alloc((size_t)Nu * HC * 2);
    ushort* hs_m = (ushort*)alloc((size_t)Nm * HC * 2);
    ushort* XUb  = (ushort*)alloc((size_t)Nu * HC * 2);
    ushort* XMb  = (ushort*)alloc((size_t)Nm * HC * 2);
    float* atts_u = (float*)alloc((size_t)Nu * 4 * 4);
    float* attd_u = (float*)alloc((size_t)Nu * 4 * 4);
    float* atts_m = (float*)alloc((size_t)Nm * 4 * 4);
    float* attd_m = (float*)alloc((size_t)Nm * 4 * 4);
    float* V_u1  = (float*)alloc((size_t)HC * 8 * 4);
    float* V_m1  = (float*)alloc((size_t)HC * 8 * 4);
    float* V_u2  = (float*)alloc((size_t)HC * 8 * 4);
    float* V_m2  = (float*)alloc((size_t)HC * 8 * 4);
    ushort* Wb_u1 = (ushort*)alloc((size_t)144 * D * 2);
    ushort* Wb_m1 = (ushort*)alloc((size_t)144 * D * 2);
    ushort* Wb_u2 = (ushort*)alloc((size_t)144 * HC * 2);
    ushort* Wb_m2 = (ushort*)alloc((size_t)144 * HC * 2);
    ushort* Wb_o  = (ushort*)alloc((size_t)64 * HC * 2);
    int* um_rs  = (int*)alloc((size_t)(Nm + 1) * 4);
    int* mu_rs  = (int*)alloc((size_t)(Nu + 1) * 4);
    // cnts | dh(512) | dcnt(512) contiguous -> single memset
    int* cnts   = (int*)alloc((size_t)(Nm + Nu + 1024) * 4);
    int* um_cnt = cnts;
    int* mu_cnt = cnts + Nm;
    int* dh     = cnts + Nm + Nu;
    int* dcnt   = dh + 512;
    int* permM  = (int*)alloc((size_t)Nm * 4);
    int* permU  = (int*)alloc((size_t)Nu * 4);
    int* um_csr = (int*)alloc((size_t)E1 * 4);
    int* mu_csr = (int*)alloc((size_t)E2 * 4);
    int* rank   = (int*)alloc((size_t)(E1 + E2) * 4);
    int* partM  = (int*)alloc(512 * 4);
    int* partU  = (int*)alloc(512 * 4);

    auto cdiv = [](int a, int b) { return (a + b - 1) / b; };

    // ---- fold attention + pack weights (x-independent) ----
    {
        VT vt;
        const float* Ws[8] = {l1_um_Wsrc, l1_mu_Wdst, l1_mu_Wsrc, l1_um_Wdst,
                              l2_um_W, l2_mu_W, l2_mu_W, l2_um_W};
        const float* as[8] = {l1_um_asrc, l1_mu_adst, l1_mu_asrc, l1_um_adst,
                              l2_um_asrc, l2_mu_adst, l2_mu_asrc, l2_um_adst};
        float* vs[8] = {V_u1, V_u1, V_m1, V_m1, V_u2, V_u2, V_m2, V_m2};
        for (int i = 0; i < 8; ++i) { vt.W[i] = Ws[i]; vt.a[i] = as[i]; vt.v[i] = vs[i]; }
        make_v_all_k<<<12, 256, 0, stream>>>(vt);

        PT pt;
        const float* pW[5] = {l1_um_Wsrc, l1_mu_Wsrc, l2_um_W, l2_mu_W, Wo};
        const float* pV[5] = {V_u1, V_m1, V_u2, V_m2, nullptr};
        ushort* pB[5] = {Wb_u1, Wb_m1, Wb_u2, Wb_m2, Wb_o};
        int pK[5] = {D, D, HC, HC, HC};
        int pN[5] = {HC, HC, HC, HC, 64};
        int cum = 0;
        for (int i = 0; i < 5; ++i) {
            pt.W[i] = pW[i]; pt.V[i] = pV[i]; pt.Wb[i] = pB[i];
            pt.K[i] = pK[i]; pt.Nw[i] = pN[i];
            pt.start[i] = cum;
            cum += (i < 4 ? 144 : 64) * pK[i];
        }
        pt.start[5] = cum;
        pack_all_k<<<cdiv(cum, 256), 256, 0, stream>>>(pt);
    }

    // ---- CSR build + degree-sorted perms (reused by both layers) ----
    int nbM = cdiv(Nm + 1, 256), nbU = cdiv(Nu + 1, 256);
    hipMemsetAsync(cnts, 0, (size_t)(Nm + Nu + 1024) * 4, stream);
    hist_dual_k<<<cdiv(E1 + E2, 256), 256, 0, stream>>>(
        um_dst, um_cnt, E1, mu_dst, mu_cnt, E2, rank);
    scan_block_dual_k<<<nbM + nbU, 256, 0, stream>>>(um_cnt, Nm, um_rs, partM, nbM,
                                                     mu_cnt, Nu, mu_rs, partU);
    scan_partial_dual_k<<<1, 512, 0, stream>>>(partM, nbM, partU, nbU);
    add_off_dual_k<<<nbM + nbU, 256, 0, stream>>>(um_rs, partM, Nm + 1, nbM,
                                                  mu_rs, partU, Nu + 1);
    {
        dim3 g(cdiv(E1 + E2, 256), NWIN);
        fill_dual_k<<<g, 256, 0, stream>>>(
            um_src, um_dst, um_rs, um_csr, E1, Nm,
            mu_src, mu_dst, mu_rs, mu_csr, E2, Nu, rank);
    }
    // degree bucket sort (cnts still holds degrees)
    deghist_dual_k<<<cdiv(Nm + Nu, 256), 256, 0, stream>>>(um_cnt, Nm, mu_cnt, Nu, dh);
    degscan_k<<<1, 256, 0, stream>>>(dh);
    degscatter_dual_k<<<cdiv(Nm + Nu, 256), 256, 0, stream>>>(
        um_cnt, Nm, permM, mu_cnt, Nu, permU, dh, dcnt);

    // output slots: [out_user | out_movie | xu | xm]
    float* OU = (float*)d_out;
    float* OM = OU + (size_t)Nu * O;
    float* XU = OM + (size_t)Nm * O;
    float* XM = XU + (size_t)Nu * HC;

    int gbU = cdiv(Nu, 128), gbM = cdiv(Nm, 128);
    int aggBlocks = cdiv((Nm + Nu) * 16, 256);

    // ---- layer 1: A = fp32 embeddings (gathered), K = D ----
    gemm_dual_k<9, 0, false><<<gbU + gbM, 256, 0, stream>>>(
        user_emb, user_ids, Wb_u1, hs_u, atts_u, attd_u, nullptr, nullptr, Nu, gbU,
        movie_emb, movie_ids, Wb_m1, hs_m, atts_m, attd_m, nullptr, nullptr, Nm,
        D, 0);
    // layer-1 agg: bf16 activations only (fp32 slot would be overwritten by L2)
    agg16_dual_k<false, true><<<aggBlocks, 256, 0, stream>>>(
        um_rs, um_csr, permM, hs_u, atts_u, attd_m, l1_um_b, nullptr, XMb, Nm,
        mu_rs, mu_csr, permU, hs_m, atts_m, attd_u, l1_mu_b, nullptr, XUb, Nu);

    // ---- layer 2: A = bf16 activations, K = HC ----
    gemm_dual_k<9, 0, true><<<gbU + gbM, 256, 0, stream>>>(
        XUb, nullptr, Wb_u2, hs_u, atts_u, attd_u, nullptr, nullptr, Nu, gbU,
        XMb, nullptr, Wb_m2, hs_m, atts_m, attd_m, nullptr, nullptr, Nm,
        HC, 0);
    // layer-2 agg: fp32 only (xu/xm are outputs; proj reads fp32)
    agg16_dual_k<true, false><<<aggBlocks, 256, 0, stream>>>(
        um_rs, um_csr, permM, hs_u, atts_u, attd_m, l2_um_b, XM, nullptr, Nm,
        mu_rs, mu_csr, permU, hs_m, atts_m, attd_u, l2_mu_b, XU, nullptr, Nu);

    // ---- final projection: out = x @ Wo + bo (fp32 A) ----
    gemm_dual_k<4, 1, false><<<gbU + gbM, 256, 0, stream>>>(
        XU, nullptr, Wb_o, nullptr, nullptr, nullptr, OU, bo, Nu, gbU,
        XM, nullptr, Wb_o, nullptr, nullptr, nullptr, OM, bo, Nm,
        HC, O);
}

// Round 10
// 260.390 us; speedup vs baseline: 3.8991x; 3.8991x over previous
//
#include <hip/hip_runtime.h>
#include <hip/hip_bf16.h>
#include <cstdint>

// ---------------------------------------------------------------------------
// HGAT: 2-layer hetero GAT (user<->movie), H=4 heads, C=32, HC=128.
// GEMMs on bf16 MFMA 16x16x32, fp32 accumulate; folded attention matrix V
// appended to packed weights so hs+att come out of one GEMM (MODE 0).
// Edge aggregation: CSR by dst, 16 lanes/node, ushort8 (16B) loads; nodes
// assigned to lane groups in DEGREE-SORTED order (bucket sort, 256 bins) so
// co-scheduled nodes have ~equal degree (kills E[max4]/E[deg] SIMT idle).
// Bucket sort uses per-block LDS histograms + ONE global atomic per
// (block,bin) -- per-node returning atomics on ~30 hot bins serialized the
// GPU (381us/kernel in round 9).
// CSR build: rank-from-hist (atomic-free fill), dst-windowed scatter.
// Softmax max-subtraction skipped (logits bounded; shift-invariant; validated).
// ---------------------------------------------------------------------------

#define HC 128
#define HH 4
#define NWIN 4   // fill scatter windows

typedef __attribute__((ext_vector_type(8))) short bf16x8;
typedef __attribute__((ext_vector_type(4))) float f32x4;

__device__ __forceinline__ short f2bf(float f) {
    return __builtin_bit_cast(short, __float2bfloat16(f));
}
__device__ __forceinline__ float bf2f(ushort u) {
    return __builtin_bit_cast(float, ((unsigned)u) << 16);
}

// ---------------- fold attention: v[k, coff+h] = sum_c W[k,h*32+c]*a[h,c] ---
struct VT { const float* W[8]; const float* a[8]; float* v[8]; };
__global__ void make_v_all_k(VT t) {
    int gid = blockIdx.x * 256 + threadIdx.x;
    int task, base;
    if (gid < 1024) { task = gid >> 8; base = gid & 255; }
    else if (gid < 3072) { int g = gid - 1024; task = 4 + (g >> 9); base = g & 511; }
    else return;
    int k = base >> 2, h = base & 3;
    int coff = (task & 1) * 4;
    const float* wr = t.W[task] + (size_t)k * HC + h * 32;
    const float* ar = t.a[task] + h * 32;
    float s = 0.f;
    #pragma unroll
    for (int c = 0; c < 32; ++c) s = fmaf(wr[c], ar[c], s);
    t.v[task][k * 8 + coff + h] = s;
}

// ---------------- pack Wb[n][k] = bf16(W[k][n]); rows Nw..Nw+7 = V ----------
struct PT { const float* W[5]; const float* V[5]; ushort* Wb[5];
            int K[5]; int Nw[5]; int start[6]; };
__global__ void pack_all_k(PT t) {
    int gid = blockIdx.x * 256 + threadIdx.x;
    if (gid >= t.start[5]) return;
    int task = 0;
    while (gid >= t.start[task + 1]) ++task;
    int loc = gid - t.start[task];
    int K = t.K[task], Nw = t.Nw[task];
    int n = loc / K, k = loc % K;
    float v = 0.f;
    if (n < Nw) v = t.W[task][(size_t)k * Nw + n];
    else if (t.V[task] != nullptr && n < Nw + 8) v = t.V[task][k * 8 + (n - Nw)];
    t.Wb[task][loc] = (ushort)f2bf(v);
}

// ---------------- dual-segment bf16 MFMA GEMM -------------------------------
// MODE 0: hs out (bf16 [M,128]) + atts fp32 [M,4] + attd fp32 [M,4].
// MODE 1: fp32 C[M,ldc] + bias. ABF: A dense bf16 (ushort), else fp32 (+idx).
template <int NT, int MODE, bool ABF>
__global__ __launch_bounds__(256) void gemm_dual_k(
    const void* A0, const int* idx0, const ushort* Wb0, ushort* hsb0,
    float* atts0, float* attd0, float* C0, const float* bias0, int M0, int nb0,
    const void* A1, const int* idx1, const ushort* Wb1, ushort* hsb1,
    float* atts1, float* attd1, float* C1, const float* bias1, int M1,
    int K, int ldc) {
    const void* A; const int* aidx; const ushort* Wb; ushort* hsb;
    float* atts; float* attd; float* C; const float* bias; int M, bid;
    if ((int)blockIdx.x < nb0) {
        A = A0; aidx = idx0; Wb = Wb0; hsb = hsb0; atts = atts0; attd = attd0;
        C = C0; bias = bias0; M = M0; bid = blockIdx.x;
    } else {
        A = A1; aidx = idx1; Wb = Wb1; hsb = hsb1; atts = atts1; attd = attd1;
        C = C1; bias = bias1; M = M1; bid = blockIdx.x - nb0;
    }
    int lane = threadIdx.x & 63;
    int wave = threadIdx.x >> 6;
    int m_base = bid * 128 + wave * 32;
    int lm = lane & 15;      // A row-in-tile / C col-in-tile
    int kg = lane >> 4;      // k-group (8 consecutive k)

    int r0 = m_base + lm, r1 = r0 + 16;
    int cr0 = r0 < M ? r0 : M - 1;
    int cr1 = r1 < M ? r1 : M - 1;
    int row0 = aidx ? aidx[cr0] : cr0;
    int row1 = aidx ? aidx[cr1] : cr1;
    const ushort* bp = Wb + (size_t)lm * K + kg * 8;

    f32x4 acc[2][NT] = {};
    for (int k0 = 0; k0 < K; k0 += 32) {
        bf16x8 a[2];
        if (ABF) {
            const ushort* a0p = (const ushort*)A + (size_t)row0 * K + kg * 8;
            const ushort* a1p = (const ushort*)A + (size_t)row1 * K + kg * 8;
            a[0] = *reinterpret_cast<const bf16x8*>(a0p + k0);
            a[1] = *reinterpret_cast<const bf16x8*>(a1p + k0);
        } else {
            const float* a0p = (const float*)A + (size_t)row0 * K + kg * 8;
            const float* a1p = (const float*)A + (size_t)row1 * K + kg * 8;
            float af[2][8];
            *reinterpret_cast<float4*>(&af[0][0]) = *reinterpret_cast<const float4*>(a0p + k0);
            *reinterpret_cast<float4*>(&af[0][4]) = *reinterpret_cast<const float4*>(a0p + k0 + 4);
            *reinterpret_cast<float4*>(&af[1][0]) = *reinterpret_cast<const float4*>(a1p + k0);
            *reinterpret_cast<float4*>(&af[1][4]) = *reinterpret_cast<const float4*>(a1p + k0 + 4);
            #pragma unroll
            for (int mi = 0; mi < 2; ++mi)
                #pragma unroll
                for (int j = 0; j < 8; ++j) a[mi][j] = f2bf(af[mi][j]);
        }
        #pragma unroll
        for (int nt = 0; nt < NT; ++nt) {
            bf16x8 b = *reinterpret_cast<const bf16x8*>(bp + (size_t)nt * 16 * K + k0);
            acc[0][nt] = __builtin_amdgcn_mfma_f32_16x16x32_bf16(a[0], b, acc[0][nt], 0, 0, 0);
            acc[1][nt] = __builtin_amdgcn_mfma_f32_16x16x32_bf16(a[1], b, acc[1][nt], 0, 0, 0);
        }
    }
    #pragma unroll
    for (int mi = 0; mi < 2; ++mi) {
        int rowb = m_base + mi * 16 + kg * 4;
        if (MODE == 0) {
            #pragma unroll
            for (int nt = 0; nt < NT - 1; ++nt) {
                int col = nt * 16 + lm;
                #pragma unroll
                for (int r = 0; r < 4; ++r) {
                    int row = rowb + r;
                    if (row < M) hsb[(size_t)row * HC + col] = (ushort)f2bf(acc[mi][nt][r]);
                }
            }
            #pragma unroll
            for (int r = 0; r < 4; ++r) {
                int row = rowb + r;
                if (row < M) {
                    float v = acc[mi][NT - 1][r];
                    if (lm < 4) atts[(size_t)row * 4 + lm] = v;
                    else if (lm < 8) attd[(size_t)row * 4 + (lm - 4)] = v;
                }
            }
        } else {
            #pragma unroll
            for (int nt = 0; nt < NT; ++nt) {
                int col = nt * 16 + lm;
                float bv = bias[col];
                #pragma unroll
                for (int r = 0; r < 4; ++r) {
                    int row = rowb + r;
                    if (row < M) C[(size_t)row * ldc + col] = acc[mi][nt][r] + bv;
                }
            }
        }
    }
}

// ---------------- CSR build (dual edge-type) --------------------------------
__global__ void hist_dual_k(const int* __restrict__ d0, int* __restrict__ c0, int E0,
                            const int* __restrict__ d1, int* __restrict__ c1, int E1,
                            int* __restrict__ rank) {
    int e = blockIdx.x * 256 + threadIdx.x;
    if (e < E0) rank[e] = atomicAdd(&c0[d0[e]], 1);
    else if (e - E0 < E1) rank[e] = atomicAdd(&c1[d1[e - E0]], 1);
}

__device__ __forceinline__ void scan_block_body(
    const int* deg, int n, int len, int* out, int* partial, int b) {
    __shared__ int s[256];
    int i = b * 256 + threadIdx.x;
    int v = (i < n) ? deg[i] : 0;
    s[threadIdx.x] = v;
    __syncthreads();
    for (int off = 1; off < 256; off <<= 1) {
        int t = (threadIdx.x >= off) ? s[threadIdx.x - off] : 0;
        __syncthreads();
        s[threadIdx.x] += t;
        __syncthreads();
    }
    if (i < len) out[i] = s[threadIdx.x] - v;
    if (threadIdx.x == 255) partial[b] = s[255];
}

__global__ void scan_block_dual_k(const int* dM, int nM, int* rsM, int* pM, int nbM,
                                  const int* dU, int nU, int* rsU, int* pU) {
    if ((int)blockIdx.x < nbM)
        scan_block_body(dM, nM, nM + 1, rsM, pM, blockIdx.x);
    else
        scan_block_body(dU, nU, nU + 1, rsU, pU, blockIdx.x - nbM);
}

__global__ void scan_partial_dual_k(int* pM, int nbM, int* pU, int nbU) {
    __shared__ int s[512];
    int t = threadIdx.x;
    for (int seg = 0; seg < 2; ++seg) {
        int* p = seg ? pU : pM;
        int nb = seg ? nbU : nbM;
        int v = (t < nb) ? p[t] : 0;
        s[t] = v;
        __syncthreads();
        for (int off = 1; off < 512; off <<= 1) {
            int x = (t >= off) ? s[t - off] : 0;
            __syncthreads();
            s[t] += x;
            __syncthreads();
        }
        if (t < nb) p[t] = s[t] - v;
        __syncthreads();
    }
}

__global__ void add_off_dual_k(int* __restrict__ oM, const int* __restrict__ pM,
                               int lenM, int nbM,
                               int* __restrict__ oU, const int* __restrict__ pU,
                               int lenU) {
    int b = blockIdx.x;
    if (b < nbM) {
        int i = b * 256 + threadIdx.x;
        if (i < lenM) oM[i] += pM[b];
    } else {
        b -= nbM;
        int i = b * 256 + threadIdx.x;
        if (i < lenU) oU[i] += pU[b];
    }
}

// atomic-free, dst-windowed scatter: window w handles dst in [w*n/NWIN, ...).
__global__ void fill_dual_k(const int* __restrict__ s0, const int* __restrict__ d0,
                            const int* __restrict__ rs0, int* __restrict__ csr0,
                            int E0, int n0,
                            const int* __restrict__ s1, const int* __restrict__ d1,
                            const int* __restrict__ rs1, int* __restrict__ csr1,
                            int E1, int n1,
                            const int* __restrict__ rank) {
    int e = blockIdx.x * 256 + threadIdx.x;
    int w = blockIdx.y;
    if (e < E0) {
        int d = d0[e];
        int lo = (int)((long)w * n0 / NWIN), hi = (int)((long)(w + 1) * n0 / NWIN);
        if (d >= lo && d < hi) csr0[rs0[d] + rank[e]] = s0[e];
    } else if (e - E0 < E1) {
        int e1 = e - E0;
        int d = d1[e1];
        int lo = (int)((long)w * n1 / NWIN), hi = (int)((long)(w + 1) * n1 / NWIN);
        if (d >= lo && d < hi) csr1[rs1[d] + rank[e]] = s1[e1];
    }
}

// ---------------- degree-sorted node permutation (bucket sort, 256 bins) ----
// dh[0..255] = movie bins, dh[256..511] = user bins. Both passes use
// per-block LDS histograms: global atomics are one per (block,bin), never
// per node (per-node returning atomics on hot bins serialize ~200cy each).
__global__ __launch_bounds__(256) void deghist_dual_k(
    const int* __restrict__ c0, int n0,
    const int* __restrict__ c1, int n1, int* __restrict__ dh) {
    __shared__ int lh[512];
    int t = threadIdx.x;
    lh[t] = 0; lh[t + 256] = 0;
    __syncthreads();
    int i = blockIdx.x * 256 + t;
    if (i < n0) atomicAdd(&lh[min(c0[i], 255)], 1);
    else if (i - n0 < n1) atomicAdd(&lh[256 + min(c1[i - n0], 255)], 1);
    __syncthreads();
    if (lh[t]) atomicAdd(&dh[t], lh[t]);
    if (lh[t + 256]) atomicAdd(&dh[t + 256], lh[t + 256]);
}

__global__ void degscan_k(int* __restrict__ dh) {
    __shared__ int s[256];
    int t = threadIdx.x;
    for (int seg = 0; seg < 2; ++seg) {
        int* p = dh + seg * 256;
        int v = p[t];
        s[t] = v;
        __syncthreads();
        for (int off = 1; off < 256; off <<= 1) {
            int x = (t >= off) ? s[t - off] : 0;
            __syncthreads();
            s[t] += x;
            __syncthreads();
        }
        p[t] = s[t] - v;   // exclusive bin starts
        __syncthreads();
    }
}

__global__ __launch_bounds__(256) void degscatter_dual_k(
    const int* __restrict__ c0, int n0, int* __restrict__ perm0,
    const int* __restrict__ c1, int n1, int* __restrict__ perm1,
    const int* __restrict__ dh, int* __restrict__ dcnt) {
    __shared__ int lh[512];
    __shared__ int lbase[512];
    int t = threadIdx.x;
    lh[t] = 0; lh[t + 256] = 0;
    __syncthreads();
    int i = blockIdx.x * 256 + t;
    int b = -1, lrank = 0, node = 0;
    if (i < n0) {
        node = i; b = min(c0[i], 255);
        lrank = atomicAdd(&lh[b], 1);
    } else if (i - n0 < n1) {
        node = i - n0; b = 256 + min(c1[node], 255);
        lrank = atomicAdd(&lh[b], 1);
    }
    __syncthreads();
    if (lh[t]) lbase[t] = atomicAdd(&dcnt[t], lh[t]);
    if (lh[t + 256]) lbase[t + 256] = atomicAdd(&dcnt[t + 256], lh[t + 256]);
    __syncthreads();
    if (b >= 0) {
        int pos = dh[b] + lbase[b] + lrank;
        if (b < 256) perm0[pos] = node;
        else perm1[pos] = node;
    }
}

// ---------------- per-dst aggregation: 16 lanes/node, ushort8 loads ---------
// Lane c in [0,16): channels 8c..8c+7 (16B load); head h = c>>2. Node ids come
// from the degree-sorted perm so co-scheduled nodes have ~equal degree.
template <bool WF32, bool WBF>
__global__ __launch_bounds__(256) void agg16_dual_k(
    const int* __restrict__ rs0, const int* __restrict__ csr0,
    const int* __restrict__ perm0,
    const ushort* __restrict__ hsb0, const float* __restrict__ atts0,
    const float* __restrict__ attd0, const float* __restrict__ bias0,
    float* __restrict__ out0, ushort* __restrict__ outb0, int n0,
    const int* __restrict__ rs1, const int* __restrict__ csr1,
    const int* __restrict__ perm1,
    const ushort* __restrict__ hsb1, const float* __restrict__ atts1,
    const float* __restrict__ attd1, const float* __restrict__ bias1,
    float* __restrict__ out1, ushort* __restrict__ outb1, int n1) {
    int g = (int)((blockIdx.x * 256u + threadIdx.x) >> 4);   // 16 nodes/block
    const int* rs; const int* csr; const ushort* hsb; const float* atts;
    const float* attd; const float* bias; float* out; ushort* outb; int node;
    if (g < n0) {
        rs = rs0; csr = csr0; hsb = hsb0; atts = atts0; attd = attd0;
        bias = bias0; out = out0; outb = outb0; node = perm0[g];
    } else {
        int j = g - n0;
        if (j >= n1) return;
        rs = rs1; csr = csr1; hsb = hsb1; atts = atts1; attd = attd1;
        bias = bias1; out = out1; outb = outb1; node = perm1[j];
    }
    int c = threadIdx.x & 15;    // channels 8c..8c+7
    int h = c >> 2;              // head (32 ch per head, 4 lanes per head)
    float ad = attd[node * 4 + h];
    int s0 = rs[node], s1 = rs[node + 1];
    float acc[8] = {};
    float wsum = 0.f;
    int i = s0;
    for (; i + 4 <= s1; i += 4) {            // 4 edge-rows in flight
        int sx[4];
        #pragma unroll
        for (int j = 0; j < 4; ++j) sx[j] = csr[i + j];
        bf16x8 hv[4]; float el[4];
        #pragma unroll
        for (int j = 0; j < 4; ++j) {
            hv[j] = *reinterpret_cast<const bf16x8*>(hsb + (size_t)sx[j] * HC + 8 * c);
            el[j] = atts[(size_t)sx[j] * 4 + h];
        }
        #pragma unroll
        for (int j = 0; j < 4; ++j) {
            float e = el[j] + ad;
            e = e > 0.f ? e : 0.2f * e;
            float w = __expf(e);
            wsum += w;
            #pragma unroll
            for (int k = 0; k < 8; ++k)
                acc[k] = fmaf(w, bf2f((ushort)hv[j][k]), acc[k]);
        }
    }
    for (; i < s1; ++i) {
        int src = csr[i];
        bf16x8 hv = *reinterpret_cast<const bf16x8*>(hsb + (size_t)src * HC + 8 * c);
        float e = atts[(size_t)src * 4 + h] + ad;
        e = e > 0.f ? e : 0.2f * e;
        float w = __expf(e);
        wsum += w;
        #pragma unroll
        for (int k = 0; k < 8; ++k)
            acc[k] = fmaf(w, bf2f((ushort)hv[k]), acc[k]);
    }
    float inv = 1.f / (wsum + 1e-16f);
    float v[8];
    #pragma unroll
    for (int k = 0; k < 8; ++k) {
        v[k] = fmaf(acc[k], inv, bias[8 * c + k]);
        v[k] = v[k] > 0.f ? v[k] : 0.01f * v[k];
    }
    if (WF32) {
        float4 o0 = make_float4(v[0], v[1], v[2], v[3]);
        float4 o1 = make_float4(v[4], v[5], v[6], v[7]);
        reinterpret_cast<float4*>(out + (size_t)node * HC + 8 * c)[0] = o0;
        reinterpret_cast<float4*>(out + (size_t)node * HC + 8 * c)[1] = o1;
    }
    if (WBF) {
        bf16x8 u;
        #pragma unroll
        for (int k = 0; k < 8; ++k) u[k] = f2bf(v[k]);
        *reinterpret_cast<bf16x8*>(outb + (size_t)node * HC + 8 * c) = u;
    }
}

// ---------------------------------------------------------------------------
extern "C" void kernel_launch(void* const* d_in, const int* in_sizes, int n_in,
                              void* d_out, int out_size, void* d_ws, size_t ws_size,
                              hipStream_t stream) {
    const int Nu = in_sizes[0];
    const int Nm = in_sizes[1];
    const int E1 = in_sizes[2];   // um edges
    const int E2 = in_sizes[4];   // mu edges
    const int D  = in_sizes[6] / Nu;   // 64
    const int O  = in_sizes[27];       // 64

    const int*   user_ids  = (const int*)d_in[0];
    const int*   movie_ids = (const int*)d_in[1];
    const int*   um_src    = (const int*)d_in[2];
    const int*   um_dst    = (const int*)d_in[3];
    const int*   mu_src    = (const int*)d_in[4];
    const int*   mu_dst    = (const int*)d_in[5];
    const float* user_emb  = (const float*)d_in[6];
    const float* movie_emb = (const float*)d_in[7];
    const float* l1_um_Wsrc = (const float*)d_in[8];
    const float* l1_um_Wdst = (const float*)d_in[9];
    const float* l1_um_asrc = (const float*)d_in[10];
    const float* l1_um_adst = (const float*)d_in[11];
    const float* l1_um_b    = (const float*)d_in[12];
    const float* l1_mu_Wsrc = (const float*)d_in[13];
    const float* l1_mu_Wdst = (const float*)d_in[14];
    const float* l1_mu_asrc = (const float*)d_in[15];
    const float* l1_mu_adst = (const float*)d_in[16];
    const float* l1_mu_b    = (const float*)d_in[17];
    const float* l2_um_W    = (const float*)d_in[18];
    const float* l2_um_asrc = (const float*)d_in[19];
    const float* l2_um_adst = (const float*)d_in[20];
    const float* l2_um_b    = (const float*)d_in[21];
    const float* l2_mu_W    = (const float*)d_in[22];
    const float* l2_mu_asrc = (const float*)d_in[23];
    const float* l2_mu_adst = (const float*)d_in[24];
    const float* l2_mu_b    = (const float*)d_in[25];
    const float* Wo         = (const float*)d_in[26];
    const float* bo         = (const float*)d_in[27];

    // ---- workspace carve ----
    char* p = (char*)d_ws;
    auto alloc = [&](size_t bytes) { void* r = p; p += (bytes + 255) & ~(size_t)255; return r; };
    ushort* hs_u = (ushort*)alloc((size_t)Nu * HC * 2);
    ushort* hs_m = (ushort*)alloc((size_t)Nm * HC * 2);
    ushort* XUb  = (ushort*)alloc((size_t)Nu * HC * 2);
    ushort* XMb  = (ushort*)alloc((size_t)Nm * HC * 2);
    float* atts_u = (float*)alloc((size_t)Nu * 4 * 4);
    float* attd_u = (float*)alloc((size_t)Nu * 4 * 4);
    float* atts_m = (float*)alloc((size_t)Nm * 4 * 4);
    float* attd_m = (float*)alloc((size_t)Nm * 4 * 4);
    float* V_u1  = (float*)alloc((size_t)HC * 8 * 4);
    float* V_m1  = (float*)alloc((size_t)HC * 8 * 4);
    float* V_u2  = (float*)alloc((size_t)HC * 8 * 4);
    float* V_m2  = (float*)alloc((size_t)HC * 8 * 4);
    ushort* Wb_u1 = (ushort*)alloc((size_t)144 * D * 2);
    ushort* Wb_m1 = (ushort*)alloc((size_t)144 * D * 2);
    ushort* Wb_u2 = (ushort*)alloc((size_t)144 * HC * 2);
    ushort* Wb_m2 = (ushort*)alloc((size_t)144 * HC * 2);
    ushort* Wb_o  = (ushort*)alloc((size_t)64 * HC * 2);
    int* um_rs  = (int*)alloc((size_t)(Nm + 1) * 4);
    int* mu_rs  = (int*)alloc((size_t)(Nu + 1) * 4);
    // cnts | dh(512) | dcnt(512) contiguous -> single memset
    int* cnts   = (int*)alloc((size_t)(Nm + Nu + 1024) * 4);
    int* um_cnt = cnts;
    int* mu_cnt = cnts + Nm;
    int* dh     = cnts + Nm + Nu;
    int* dcnt   = dh + 512;
    int* permM  = (int*)alloc((size_t)Nm * 4);
    int* permU  = (int*)alloc((size_t)Nu * 4);
    int* um_csr = (int*)alloc((size_t)E1 * 4);
    int* mu_csr = (int*)alloc((size_t)E2 * 4);
    int* rank   = (int*)alloc((size_t)(E1 + E2) * 4);
    int* partM  = (int*)alloc(512 * 4);
    int* partU  = (int*)alloc(512 * 4);

    auto cdiv = [](int a, int b) { return (a + b - 1) / b; };

    // ---- fold attention + pack weights (x-independent) ----
    {
        VT vt;
        const float* Ws[8] = {l1_um_Wsrc, l1_mu_Wdst, l1_mu_Wsrc, l1_um_Wdst,
                              l2_um_W, l2_mu_W, l2_mu_W, l2_um_W};
        const float* as[8] = {l1_um_asrc, l1_mu_adst, l1_mu_asrc, l1_um_adst,
                              l2_um_asrc, l2_mu_adst, l2_mu_asrc, l2_um_adst};
        float* vs[8] = {V_u1, V_u1, V_m1, V_m1, V_u2, V_u2, V_m2, V_m2};
        for (int i = 0; i < 8; ++i) { vt.W[i] = Ws[i]; vt.a[i] = as[i]; vt.v[i] = vs[i]; }
        make_v_all_k<<<12, 256, 0, stream>>>(vt);

        PT pt;
        const float* pW[5] = {l1_um_Wsrc, l1_mu_Wsrc, l2_um_W, l2_mu_W, Wo};
        const float* pV[5] = {V_u1, V_m1, V_u2, V_m2, nullptr};
        ushort* pB[5] = {Wb_u1, Wb_m1, Wb_u2, Wb_m2, Wb_o};
        int pK[5] = {D, D, HC, HC, HC};
        int pN[5] = {HC, HC, HC, HC, 64};
        int cum = 0;
        for (int i = 0; i < 5; ++i) {
            pt.W[i] = pW[i]; pt.V[i] = pV[i]; pt.Wb[i] = pB[i];
            pt.K[i] = pK[i]; pt.Nw[i] = pN[i];
            pt.start[i] = cum;
            cum += (i < 4 ? 144 : 64) * pK[i];
        }
        pt.start[5] = cum;
        pack_all_k<<<cdiv(cum, 256), 256, 0, stream>>>(pt);
    }

    // ---- CSR build + degree-sorted perms (reused by both layers) ----
    int nbM = cdiv(Nm + 1, 256), nbU = cdiv(Nu + 1, 256);
    hipMemsetAsync(cnts, 0, (size_t)(Nm + Nu + 1024) * 4, stream);
    hist_dual_k<<<cdiv(E1 + E2, 256), 256, 0, stream>>>(
        um_dst, um_cnt, E1, mu_dst, mu_cnt, E2, rank);
    scan_block_dual_k<<<nbM + nbU, 256, 0, stream>>>(um_cnt, Nm, um_rs, partM, nbM,
                                                     mu_cnt, Nu, mu_rs, partU);
    scan_partial_dual_k<<<1, 512, 0, stream>>>(partM, nbM, partU, nbU);
    add_off_dual_k<<<nbM + nbU, 256, 0, stream>>>(um_rs, partM, Nm + 1, nbM,
                                                  mu_rs, partU, Nu + 1);
    {
        dim3 g(cdiv(E1 + E2, 256), NWIN);
        fill_dual_k<<<g, 256, 0, stream>>>(
            um_src, um_dst, um_rs, um_csr, E1, Nm,
            mu_src, mu_dst, mu_rs, mu_csr, E2, Nu, rank);
    }
    // degree bucket sort (cnts still holds degrees)
    deghist_dual_k<<<cdiv(Nm + Nu, 256), 256, 0, stream>>>(um_cnt, Nm, mu_cnt, Nu, dh);
    degscan_k<<<1, 256, 0, stream>>>(dh);
    degscatter_dual_k<<<cdiv(Nm + Nu, 256), 256, 0, stream>>>(
        um_cnt, Nm, permM, mu_cnt, Nu, permU, dh, dcnt);

    // output slots: [out_user | out_movie | xu | xm]
    float* OU = (float*)d_out;
    float* OM = OU + (size_t)Nu * O;
    float* XU = OM + (size_t)Nm * O;
    float* XM = XU + (size_t)Nu * HC;

    int gbU = cdiv(Nu, 128), gbM = cdiv(Nm, 128);
    int aggBlocks = cdiv((Nm + Nu) * 16, 256);

    // ---- layer 1: A = fp32 embeddings (gathered), K = D ----
    gemm_dual_k<9, 0, false><<<gbU + gbM, 256, 0, stream>>>(
        user_emb, user_ids, Wb_u1, hs_u, atts_u, attd_u, nullptr, nullptr, Nu, gbU,
        movie_emb, movie_ids, Wb_m1, hs_m, atts_m, attd_m, nullptr, nullptr, Nm,
        D, 0);
    // layer-1 agg: bf16 activations only (fp32 slot would be overwritten by L2)
    agg16_dual_k<false, true><<<aggBlocks, 256, 0, stream>>>(
        um_rs, um_csr, permM, hs_u, atts_u, attd_m, l1_um_b, nullptr, XMb, Nm,
        mu_rs, mu_csr, permU, hs_m, atts_m, attd_u, l1_mu_b, nullptr, XUb, Nu);

    // ---- layer 2: A = bf16 activations, K = HC ----
    gemm_dual_k<9, 0, true><<<gbU + gbM, 256, 0, stream>>>(
        XUb, nullptr, Wb_u2, hs_u, atts_u, attd_u, nullptr, nullptr, Nu, gbU,
        XMb, nullptr, Wb_m2, hs_m, atts_m, attd_m, nullptr, nullptr, Nm,
        HC, 0);
    // layer-2 agg: fp32 only (xu/xm are outputs; proj reads fp32)
    agg16_dual_k<true, false><<<aggBlocks, 256, 0, stream>>>(
        um_rs, um_csr, permM, hs_u, atts_u, attd_m, l2_um_b, XM, nullptr, Nm,
        mu_rs, mu_csr, permU, hs_m, atts_m, attd_u, l2_mu_b, XU, nullptr, Nu);

    // ---- final projection: out = x @ Wo + bo (fp32 A) ----
    gemm_dual_k<4, 1, false><<<gbU + gbM, 256, 0, stream>>>(
        XU, nullptr, Wb_o, nullptr, nullptr, nullptr, OU, bo, Nu, gbU,
        XM, nullptr, Wb_o, nullptr, nullptr, nullptr, OM, bo, Nm,
        HC, O);
}

// Round 11
// 252.970 us; speedup vs baseline: 4.0135x; 1.0293x over previous
//
#include <hip/hip_runtime.h>
#include <hip/hip_bf16.h>
#include <cstdint>

// ---------------------------------------------------------------------------
// HGAT: 2-layer hetero GAT (user<->movie), H=4 heads, C=32, HC=128.
// GEMMs on bf16 MFMA 16x16x32, fp32 accumulate; folded attention matrix V
// appended to packed weights so hs+att come out of one GEMM (MODE 0).
// Edge aggregation: CSR by dst, 16 lanes/node, ushort8 (16B) loads.
// CSR is partitioned by SRC-WINDOW ([window][dst] major order): movie-dst CSR
// has NWM=8 windows over Nu (hs_u gather slice 25.6/8 = 3.2MB, fits per-XCD
// 4MB L2), user-dst CSR has NWU=2 windows over Nm (hs_m slice 2.6MB). agg
// walks each node's NW dense segments in window order -> the 5x row reuse
// hits L2 instead of L3/HBM (round-7/8 FETCH showed ~all of the hs_u gather
// missing L2: 116MB L2-miss per agg dispatch).
// CSR build: rank-from-hist (atomic-free fill), dst-windowed scatter (NWIN=4
// over dst kills the 16x write amplification seen in round 5).
// Degree-sort experiment (r9/r10) reverted: perm indirection de-coalesced
// agg writes and cost more than the divergence it saved (248 -> 260us).
// Softmax max-subtraction skipped (logits bounded; shift-invariant; validated).
// ---------------------------------------------------------------------------

#define HC 128
#define HH 4
#define NWIN 4   // fill scatter windows (over dst)
#define NWM 8    // src windows in movie-dst CSR (gathers hs_u, 25.6MB)
#define NWU 2    // src windows in user-dst CSR (gathers hs_m, 5.1MB)

typedef __attribute__((ext_vector_type(8))) short bf16x8;
typedef __attribute__((ext_vector_type(4))) float f32x4;

__device__ __forceinline__ short f2bf(float f) {
    return __builtin_bit_cast(short, __float2bfloat16(f));
}
__device__ __forceinline__ float bf2f(ushort u) {
    return __builtin_bit_cast(float, ((unsigned)u) << 16);
}

// ---------------- fold attention: v[k, coff+h] = sum_c W[k,h*32+c]*a[h,c] ---
struct VT { const float* W[8]; const float* a[8]; float* v[8]; };
__global__ void make_v_all_k(VT t) {
    int gid = blockIdx.x * 256 + threadIdx.x;
    int task, base;
    if (gid < 1024) { task = gid >> 8; base = gid & 255; }
    else if (gid < 3072) { int g = gid - 1024; task = 4 + (g >> 9); base = g & 511; }
    else return;
    int k = base >> 2, h = base & 3;
    int coff = (task & 1) * 4;
    const float* wr = t.W[task] + (size_t)k * HC + h * 32;
    const float* ar = t.a[task] + h * 32;
    float s = 0.f;
    #pragma unroll
    for (int c = 0; c < 32; ++c) s = fmaf(wr[c], ar[c], s);
    t.v[task][k * 8 + coff + h] = s;
}

// ---------------- pack Wb[n][k] = bf16(W[k][n]); rows Nw..Nw+7 = V ----------
struct PT { const float* W[5]; const float* V[5]; ushort* Wb[5];
            int K[5]; int Nw[5]; int start[6]; };
__global__ void pack_all_k(PT t) {
    int gid = blockIdx.x * 256 + threadIdx.x;
    if (gid >= t.start[5]) return;
    int task = 0;
    while (gid >= t.start[task + 1]) ++task;
    int loc = gid - t.start[task];
    int K = t.K[task], Nw = t.Nw[task];
    int n = loc / K, k = loc % K;
    float v = 0.f;
    if (n < Nw) v = t.W[task][(size_t)k * Nw + n];
    else if (t.V[task] != nullptr && n < Nw + 8) v = t.V[task][k * 8 + (n - Nw)];
    t.Wb[task][loc] = (ushort)f2bf(v);
}

// ---------------- dual-segment bf16 MFMA GEMM -------------------------------
// MODE 0: hs out (bf16 [M,128]) + atts fp32 [M,4] + attd fp32 [M,4].
// MODE 1: fp32 C[M,ldc] + bias. ABF: A dense bf16 (ushort), else fp32 (+idx).
template <int NT, int MODE, bool ABF>
__global__ __launch_bounds__(256) void gemm_dual_k(
    const void* A0, const int* idx0, const ushort* Wb0, ushort* hsb0,
    float* atts0, float* attd0, float* C0, const float* bias0, int M0, int nb0,
    const void* A1, const int* idx1, const ushort* Wb1, ushort* hsb1,
    float* atts1, float* attd1, float* C1, const float* bias1, int M1,
    int K, int ldc) {
    const void* A; const int* aidx; const ushort* Wb; ushort* hsb;
    float* atts; float* attd; float* C; const float* bias; int M, bid;
    if ((int)blockIdx.x < nb0) {
        A = A0; aidx = idx0; Wb = Wb0; hsb = hsb0; atts = atts0; attd = attd0;
        C = C0; bias = bias0; M = M0; bid = blockIdx.x;
    } else {
        A = A1; aidx = idx1; Wb = Wb1; hsb = hsb1; atts = atts1; attd = attd1;
        C = C1; bias = bias1; M = M1; bid = blockIdx.x - nb0;
    }
    int lane = threadIdx.x & 63;
    int wave = threadIdx.x >> 6;
    int m_base = bid * 128 + wave * 32;
    int lm = lane & 15;      // A row-in-tile / C col-in-tile
    int kg = lane >> 4;      // k-group (8 consecutive k)

    int r0 = m_base + lm, r1 = r0 + 16;
    int cr0 = r0 < M ? r0 : M - 1;
    int cr1 = r1 < M ? r1 : M - 1;
    int row0 = aidx ? aidx[cr0] : cr0;
    int row1 = aidx ? aidx[cr1] : cr1;
    const ushort* bp = Wb + (size_t)lm * K + kg * 8;

    f32x4 acc[2][NT] = {};
    for (int k0 = 0; k0 < K; k0 += 32) {
        bf16x8 a[2];
        if (ABF) {
            const ushort* a0p = (const ushort*)A + (size_t)row0 * K + kg * 8;
            const ushort* a1p = (const ushort*)A + (size_t)row1 * K + kg * 8;
            a[0] = *reinterpret_cast<const bf16x8*>(a0p + k0);
            a[1] = *reinterpret_cast<const bf16x8*>(a1p + k0);
        } else {
            const float* a0p = (const float*)A + (size_t)row0 * K + kg * 8;
            const float* a1p = (const float*)A + (size_t)row1 * K + kg * 8;
            float af[2][8];
            *reinterpret_cast<float4*>(&af[0][0]) = *reinterpret_cast<const float4*>(a0p + k0);
            *reinterpret_cast<float4*>(&af[0][4]) = *reinterpret_cast<const float4*>(a0p + k0 + 4);
            *reinterpret_cast<float4*>(&af[1][0]) = *reinterpret_cast<const float4*>(a1p + k0);
            *reinterpret_cast<float4*>(&af[1][4]) = *reinterpret_cast<const float4*>(a1p + k0 + 4);
            #pragma unroll
            for (int mi = 0; mi < 2; ++mi)
                #pragma unroll
                for (int j = 0; j < 8; ++j) a[mi][j] = f2bf(af[mi][j]);
        }
        #pragma unroll
        for (int nt = 0; nt < NT; ++nt) {
            bf16x8 b = *reinterpret_cast<const bf16x8*>(bp + (size_t)nt * 16 * K + k0);
            acc[0][nt] = __builtin_amdgcn_mfma_f32_16x16x32_bf16(a[0], b, acc[0][nt], 0, 0, 0);
            acc[1][nt] = __builtin_amdgcn_mfma_f32_16x16x32_bf16(a[1], b, acc[1][nt], 0, 0, 0);
        }
    }
    #pragma unroll
    for (int mi = 0; mi < 2; ++mi) {
        int rowb = m_base + mi * 16 + kg * 4;
        if (MODE == 0) {
            #pragma unroll
            for (int nt = 0; nt < NT - 1; ++nt) {
                int col = nt * 16 + lm;
                #pragma unroll
                for (int r = 0; r < 4; ++r) {
                    int row = rowb + r;
                    if (row < M) hsb[(size_t)row * HC + col] = (ushort)f2bf(acc[mi][nt][r]);
                }
            }
            #pragma unroll
            for (int r = 0; r < 4; ++r) {
                int row = rowb + r;
                if (row < M) {
                    float v = acc[mi][NT - 1][r];
                    if (lm < 4) atts[(size_t)row * 4 + lm] = v;
                    else if (lm < 8) attd[(size_t)row * 4 + (lm - 4)] = v;
                }
            }
        } else {
            #pragma unroll
            for (int nt = 0; nt < NT; ++nt) {
                int col = nt * 16 + lm;
                float bv = bias[col];
                #pragma unroll
                for (int r = 0; r < 4; ++r) {
                    int row = rowb + r;
                    if (row < M) C[(size_t)row * ldc + col] = acc[mi][nt][r] + bv;
                }
            }
        }
    }
}

// ---------------- CSR build (dual edge-type, src-windowed) ------------------
// Counters indexed [w][dst]; rank[e] = within-(w,dst) slot (hist return val).
__global__ void hist_dual_k(const int* __restrict__ s0, const int* __restrict__ d0,
                            int* __restrict__ c0, int E0, int nsrc0, int n0,
                            const int* __restrict__ s1, const int* __restrict__ d1,
                            int* __restrict__ c1, int E1, int nsrc1, int n1,
                            int* __restrict__ rank) {
    int e = blockIdx.x * 256 + threadIdx.x;
    if (e < E0) {
        int w = (int)((long)s0[e] * NWM / nsrc0);
        rank[e] = atomicAdd(&c0[w * n0 + d0[e]], 1);
    } else if (e - E0 < E1) {
        int e1 = e - E0;
        int w = (int)((long)s1[e1] * NWU / nsrc1);
        rank[e] = atomicAdd(&c1[w * n1 + d1[e1]], 1);
    }
}

__device__ __forceinline__ void scan_block_body(
    const int* deg, int n, int len, int* out, int* partial, int b) {
    __shared__ int s[256];
    int i = b * 256 + threadIdx.x;
    int v = (i < n) ? deg[i] : 0;
    s[threadIdx.x] = v;
    __syncthreads();
    for (int off = 1; off < 256; off <<= 1) {
        int t = (threadIdx.x >= off) ? s[threadIdx.x - off] : 0;
        __syncthreads();
        s[threadIdx.x] += t;
        __syncthreads();
    }
    if (i < len) out[i] = s[threadIdx.x] - v;
    if (threadIdx.x == 255) partial[b] = s[255];
}

__global__ void scan_block_dual_k(const int* dM, int nM, int* rsM, int* pM, int nbM,
                                  const int* dU, int nU, int* rsU, int* pU) {
    if ((int)blockIdx.x < nbM)
        scan_block_body(dM, nM, nM + 1, rsM, pM, blockIdx.x);
    else
        scan_block_body(dU, nU, nU + 1, rsU, pU, blockIdx.x - nbM);
}

// 1024-thread partial scan (windowed rs arrays need up to ~800 blocks).
__global__ void scan_partial_dual_k(int* pM, int nbM, int* pU, int nbU) {
    __shared__ int s[1024];
    int t = threadIdx.x;
    for (int seg = 0; seg < 2; ++seg) {
        int* p = seg ? pU : pM;
        int nb = seg ? nbU : nbM;
        int v = (t < nb) ? p[t] : 0;
        s[t] = v;
        __syncthreads();
        for (int off = 1; off < 1024; off <<= 1) {
            int x = (t >= off) ? s[t - off] : 0;
            __syncthreads();
            s[t] += x;
            __syncthreads();
        }
        if (t < nb) p[t] = s[t] - v;
        __syncthreads();
    }
}

__global__ void add_off_dual_k(int* __restrict__ oM, const int* __restrict__ pM,
                               int lenM, int nbM,
                               int* __restrict__ oU, const int* __restrict__ pU,
                               int lenU) {
    int b = blockIdx.x;
    if (b < nbM) {
        int i = b * 256 + threadIdx.x;
        if (i < lenM) oM[i] += pM[b];
    } else {
        b -= nbM;
        int i = b * 256 + threadIdx.x;
        if (i < lenU) oU[i] += pU[b];
    }
}

// atomic-free scatter; blockIdx.y windows DST range (write-region coalescing).
__global__ void fill_dual_k(const int* __restrict__ s0, const int* __restrict__ d0,
                            const int* __restrict__ rs0, int* __restrict__ csr0,
                            int E0, int nsrc0, int n0,
                            const int* __restrict__ s1, const int* __restrict__ d1,
                            const int* __restrict__ rs1, int* __restrict__ csr1,
                            int E1, int nsrc1, int n1,
                            const int* __restrict__ rank) {
    int e = blockIdx.x * 256 + threadIdx.x;
    int y = blockIdx.y;
    if (e < E0) {
        int d = d0[e];
        int lo = (int)((long)y * n0 / NWIN), hi = (int)((long)(y + 1) * n0 / NWIN);
        if (d >= lo && d < hi) {
            int w = (int)((long)s0[e] * NWM / nsrc0);
            csr0[rs0[w * n0 + d] + rank[e]] = s0[e];
        }
    } else if (e - E0 < E1) {
        int e1 = e - E0;
        int d = d1[e1];
        int lo = (int)((long)y * n1 / NWIN), hi = (int)((long)(y + 1) * n1 / NWIN);
        if (d >= lo && d < hi) {
            int w = (int)((long)s1[e1] * NWU / nsrc1);
            csr1[rs1[w * n1 + d] + rank[e]] = s1[e1];
        }
    }
}

// ---------------- per-dst aggregation: 16 lanes/node, ushort8 loads ---------
// Lane c in [0,16): channels 8c..8c+7 (16B load); head h = c>>2. Each node's
// edges live in NW window-segments [rs[w*n+node], rs[w*n+node+1]); walking
// them in order keeps the active gather slice L2-resident.
template <bool WF32, bool WBF>
__global__ __launch_bounds__(256) void agg16_dual_k(
    const int* __restrict__ rs0, const int* __restrict__ csr0,
    const ushort* __restrict__ hsb0, const float* __restrict__ atts0,
    const float* __restrict__ attd0, const float* __restrict__ bias0,
    float* __restrict__ out0, ushort* __restrict__ outb0, int n0,
    const int* __restrict__ rs1, const int* __restrict__ csr1,
    const ushort* __restrict__ hsb1, const float* __restrict__ atts1,
    const float* __restrict__ attd1, const float* __restrict__ bias1,
    float* __restrict__ out1, ushort* __restrict__ outb1, int n1) {
    int g = (int)((blockIdx.x * 256u + threadIdx.x) >> 4);   // 16 nodes/block
    const int* rs; const int* csr; const ushort* hsb; const float* atts;
    const float* attd; const float* bias; float* out; ushort* outb;
    int node, nn, nw;
    if (g < n0) {
        rs = rs0; csr = csr0; hsb = hsb0; atts = atts0; attd = attd0;
        bias = bias0; out = out0; outb = outb0; node = g; nn = n0; nw = NWM;
    } else {
        node = g - n0;
        if (node >= n1) return;
        rs = rs1; csr = csr1; hsb = hsb1; atts = atts1; attd = attd1;
        bias = bias1; out = out1; outb = outb1; nn = n1; nw = NWU;
    }
    int c = threadIdx.x & 15;    // channels 8c..8c+7
    int h = c >> 2;              // head (32 ch per head, 4 lanes per head)
    float ad = attd[node * 4 + h];
    float acc[8] = {};
    float wsum = 0.f;
    for (int w = 0; w < nw; ++w) {
        int s0 = rs[w * nn + node], s1 = rs[w * nn + node + 1];
        int i = s0;
        for (; i + 4 <= s1; i += 4) {            // 4 edge-rows in flight
            int sx[4];
            #pragma unroll
            for (int j = 0; j < 4; ++j) sx[j] = csr[i + j];
            bf16x8 hv[4]; float el[4];
            #pragma unroll
            for (int j = 0; j < 4; ++j) {
                hv[j] = *reinterpret_cast<const bf16x8*>(hsb + (size_t)sx[j] * HC + 8 * c);
                el[j] = atts[(size_t)sx[j] * 4 + h];
            }
            #pragma unroll
            for (int j = 0; j < 4; ++j) {
                float e = el[j] + ad;
                e = e > 0.f ? e : 0.2f * e;
                float wt = __expf(e);
                wsum += wt;
                #pragma unroll
                for (int k = 0; k < 8; ++k)
                    acc[k] = fmaf(wt, bf2f((ushort)hv[j][k]), acc[k]);
            }
        }
        if (i + 2 <= s1) {                       // 2-deep rung (short segments)
            int sa = csr[i], sb = csr[i + 1];
            bf16x8 ha = *reinterpret_cast<const bf16x8*>(hsb + (size_t)sa * HC + 8 * c);
            bf16x8 hb = *reinterpret_cast<const bf16x8*>(hsb + (size_t)sb * HC + 8 * c);
            float ea = atts[(size_t)sa * 4 + h] + ad;
            float eb = atts[(size_t)sb * 4 + h] + ad;
            ea = ea > 0.f ? ea : 0.2f * ea;
            eb = eb > 0.f ? eb : 0.2f * eb;
            float wa = __expf(ea), wb = __expf(eb);
            wsum += wa + wb;
            #pragma unroll
            for (int k = 0; k < 8; ++k)
                acc[k] = fmaf(wa, bf2f((ushort)ha[k]),
                              fmaf(wb, bf2f((ushort)hb[k]), acc[k]));
            i += 2;
        }
        if (i < s1) {
            int src = csr[i];
            bf16x8 hv = *reinterpret_cast<const bf16x8*>(hsb + (size_t)src * HC + 8 * c);
            float e = atts[(size_t)src * 4 + h] + ad;
            e = e > 0.f ? e : 0.2f * e;
            float wt = __expf(e);
            wsum += wt;
            #pragma unroll
            for (int k = 0; k < 8; ++k)
                acc[k] = fmaf(wt, bf2f((ushort)hv[k]), acc[k]);
        }
    }
    float inv = 1.f / (wsum + 1e-16f);
    float v[8];
    #pragma unroll
    for (int k = 0; k < 8; ++k) {
        v[k] = fmaf(acc[k], inv, bias[8 * c + k]);
        v[k] = v[k] > 0.f ? v[k] : 0.01f * v[k];
    }
    if (WF32) {
        float4 o0 = make_float4(v[0], v[1], v[2], v[3]);
        float4 o1 = make_float4(v[4], v[5], v[6], v[7]);
        reinterpret_cast<float4*>(out + (size_t)node * HC + 8 * c)[0] = o0;
        reinterpret_cast<float4*>(out + (size_t)node * HC + 8 * c)[1] = o1;
    }
    if (WBF) {
        bf16x8 u;
        #pragma unroll
        for (int k = 0; k < 8; ++k) u[k] = f2bf(v[k]);
        *reinterpret_cast<bf16x8*>(outb + (size_t)node * HC + 8 * c) = u;
    }
}

// ---------------------------------------------------------------------------
extern "C" void kernel_launch(void* const* d_in, const int* in_sizes, int n_in,
                              void* d_out, int out_size, void* d_ws, size_t ws_size,
                              hipStream_t stream) {
    const int Nu = in_sizes[0];
    const int Nm = in_sizes[1];
    const int E1 = in_sizes[2];   // um edges
    const int E2 = in_sizes[4];   // mu edges
    const int D  = in_sizes[6] / Nu;   // 64
    const int O  = in_sizes[27];       // 64

    const int*   user_ids  = (const int*)d_in[0];
    const int*   movie_ids = (const int*)d_in[1];
    const int*   um_src    = (const int*)d_in[2];
    const int*   um_dst    = (const int*)d_in[3];
    const int*   mu_src    = (const int*)d_in[4];
    const int*   mu_dst    = (const int*)d_in[5];
    const float* user_emb  = (const float*)d_in[6];
    const float* movie_emb = (const float*)d_in[7];
    const float* l1_um_Wsrc = (const float*)d_in[8];
    const float* l1_um_Wdst = (const float*)d_in[9];
    const float* l1_um_asrc = (const float*)d_in[10];
    const float* l1_um_adst = (const float*)d_in[11];
    const float* l1_um_b    = (const float*)d_in[12];
    const float* l1_mu_Wsrc = (const float*)d_in[13];
    const float* l1_mu_Wdst = (const float*)d_in[14];
    const float* l1_mu_asrc = (const float*)d_in[15];
    const float* l1_mu_adst = (const float*)d_in[16];
    const float* l1_mu_b    = (const float*)d_in[17];
    const float* l2_um_W    = (const float*)d_in[18];
    const float* l2_um_asrc = (const float*)d_in[19];
    const float* l2_um_adst = (const float*)d_in[20];
    const float* l2_um_b    = (const float*)d_in[21];
    const float* l2_mu_W    = (const float*)d_in[22];
    const float* l2_mu_asrc = (const float*)d_in[23];
    const float* l2_mu_adst = (const float*)d_in[24];
    const float* l2_mu_b    = (const float*)d_in[25];
    const float* Wo         = (const float*)d_in[26];
    const float* bo         = (const float*)d_in[27];

    // ---- workspace carve ----
    char* p = (char*)d_ws;
    auto alloc = [&](size_t bytes) { void* r = p; p += (bytes + 255) & ~(size_t)255; return r; };
    ushort* hs_u = (ushort*)alloc((size_t)Nu * HC * 2);
    ushort* hs_m = (ushort*)alloc((size_t)Nm * HC * 2);
    ushort* XUb  = (ushort*)alloc((size_t)Nu * HC * 2);
    ushort* XMb  = (ushort*)alloc((size_t)Nm * HC * 2);
    float* atts_u = (float*)alloc((size_t)Nu * 4 * 4);
    float* attd_u = (float*)alloc((size_t)Nu * 4 * 4);
    float* atts_m = (float*)alloc((size_t)Nm * 4 * 4);
    float* attd_m = (float*)alloc((size_t)Nm * 4 * 4);
    float* V_u1  = (float*)alloc((size_t)HC * 8 * 4);
    float* V_m1  = (float*)alloc((size_t)HC * 8 * 4);
    float* V_u2  = (float*)alloc((size_t)HC * 8 * 4);
    float* V_m2  = (float*)alloc((size_t)HC * 8 * 4);
    ushort* Wb_u1 = (ushort*)alloc((size_t)144 * D * 2);
    ushort* Wb_m1 = (ushort*)alloc((size_t)144 * D * 2);
    ushort* Wb_u2 = (ushort*)alloc((size_t)144 * HC * 2);
    ushort* Wb_m2 = (ushort*)alloc((size_t)144 * HC * 2);
    ushort* Wb_o  = (ushort*)alloc((size_t)64 * HC * 2);
    int lenM = NWM * Nm + 1, lenU = NWU * Nu + 1;
    int* um_rs  = (int*)alloc((size_t)lenM * 4);
    int* mu_rs  = (int*)alloc((size_t)lenU * 4);
    int* cnts   = (int*)alloc((size_t)(NWM * Nm + NWU * Nu) * 4);
    int* um_cnt = cnts;
    int* mu_cnt = cnts + NWM * Nm;
    int* um_csr = (int*)alloc((size_t)E1 * 4);
    int* mu_csr = (int*)alloc((size_t)E2 * 4);
    int* rank   = (int*)alloc((size_t)(E1 + E2) * 4);
    int* partM  = (int*)alloc(1024 * 4);
    int* partU  = (int*)alloc(1024 * 4);

    auto cdiv = [](int a, int b) { return (a + b - 1) / b; };

    // ---- fold attention + pack weights (x-independent) ----
    {
        VT vt;
        const float* Ws[8] = {l1_um_Wsrc, l1_mu_Wdst, l1_mu_Wsrc, l1_um_Wdst,
                              l2_um_W, l2_mu_W, l2_mu_W, l2_um_W};
        const float* as[8] = {l1_um_asrc, l1_mu_adst, l1_mu_asrc, l1_um_adst,
                              l2_um_asrc, l2_mu_adst, l2_mu_asrc, l2_um_adst};
        float* vs[8] = {V_u1, V_u1, V_m1, V_m1, V_u2, V_u2, V_m2, V_m2};
        for (int i = 0; i < 8; ++i) { vt.W[i] = Ws[i]; vt.a[i] = as[i]; vt.v[i] = vs[i]; }
        make_v_all_k<<<12, 256, 0, stream>>>(vt);

        PT pt;
        const float* pW[5] = {l1_um_Wsrc, l1_mu_Wsrc, l2_um_W, l2_mu_W, Wo};
        const float* pV[5] = {V_u1, V_m1, V_u2, V_m2, nullptr};
        ushort* pB[5] = {Wb_u1, Wb_m1, Wb_u2, Wb_m2, Wb_o};
        int pK[5] = {D, D, HC, HC, HC};
        int pN[5] = {HC, HC, HC, HC, 64};
        int cum = 0;
        for (int i = 0; i < 5; ++i) {
            pt.W[i] = pW[i]; pt.V[i] = pV[i]; pt.Wb[i] = pB[i];
            pt.K[i] = pK[i]; pt.Nw[i] = pN[i];
            pt.start[i] = cum;
            cum += (i < 4 ? 144 : 64) * pK[i];
        }
        pt.start[5] = cum;
        pack_all_k<<<cdiv(cum, 256), 256, 0, stream>>>(pt);
    }

    // ---- src-windowed CSR build (both edge types, reused by both layers) ----
    int nbM = cdiv(lenM, 256), nbU = cdiv(lenU, 256);
    hipMemsetAsync(cnts, 0, (size_t)(NWM * Nm + NWU * Nu) * 4, stream);
    hist_dual_k<<<cdiv(E1 + E2, 256), 256, 0, stream>>>(
        um_src, um_dst, um_cnt, E1, Nu, Nm,
        mu_src, mu_dst, mu_cnt, E2, Nm, Nu, rank);
    scan_block_dual_k<<<nbM + nbU, 256, 0, stream>>>(
        um_cnt, NWM * Nm, um_rs, partM, nbM,
        mu_cnt, NWU * Nu, mu_rs, partU);
    scan_partial_dual_k<<<1, 1024, 0, stream>>>(partM, nbM, partU, nbU);
    add_off_dual_k<<<nbM + nbU, 256, 0, stream>>>(um_rs, partM, lenM, nbM,
                                                  mu_rs, partU, lenU);
    {
        dim3 g(cdiv(E1 + E2, 256), NWIN);
        fill_dual_k<<<g, 256, 0, stream>>>(
            um_src, um_dst, um_rs, um_csr, E1, Nu, Nm,
            mu_src, mu_dst, mu_rs, mu_csr, E2, Nm, Nu, rank);
    }

    // output slots: [out_user | out_movie | xu | xm]
    float* OU = (float*)d_out;
    float* OM = OU + (size_t)Nu * O;
    float* XU = OM + (size_t)Nm * O;
    float* XM = XU + (size_t)Nu * HC;

    int gbU = cdiv(Nu, 128), gbM = cdiv(Nm, 128);
    int aggBlocks = cdiv((Nm + Nu) * 16, 256);

    // ---- layer 1: A = fp32 embeddings (gathered), K = D ----
    gemm_dual_k<9, 0, false><<<gbU + gbM, 256, 0, stream>>>(
        user_emb, user_ids, Wb_u1, hs_u, atts_u, attd_u, nullptr, nullptr, Nu, gbU,
        movie_emb, movie_ids, Wb_m1, hs_m, atts_m, attd_m, nullptr, nullptr, Nm,
        D, 0);
    // layer-1 agg: bf16 activations only (fp32 slot would be overwritten by L2)
    agg16_dual_k<false, true><<<aggBlocks, 256, 0, stream>>>(
        um_rs, um_csr, hs_u, atts_u, attd_m, l1_um_b, nullptr, XMb, Nm,
        mu_rs, mu_csr, hs_m, atts_m, attd_u, l1_mu_b, nullptr, XUb, Nu);

    // ---- layer 2: A = bf16 activations, K = HC ----
    gemm_dual_k<9, 0, true><<<gbU + gbM, 256, 0, stream>>>(
        XUb, nullptr, Wb_u2, hs_u, atts_u, attd_u, nullptr, nullptr, Nu, gbU,
        XMb, nullptr, Wb_m2, hs_m, atts_m, attd_m, nullptr, nullptr, Nm,
        HC, 0);
    // layer-2 agg: fp32 only (xu/xm are outputs; proj reads fp32)
    agg16_dual_k<true, false><<<aggBlocks, 256, 0, stream>>>(
        um_rs, um_csr, hs_u, atts_u, attd_m, l2_um_b, XM, nullptr, Nm,
        mu_rs, mu_csr, hs_m, atts_m, attd_u, l2_mu_b, XU, nullptr, Nu);

    // ---- final projection: out = x @ Wo + bo (fp32 A) ----
    gemm_dual_k<4, 1, false><<<gbU + gbM, 256, 0, stream>>>(
        XU, nullptr, Wb_o, nullptr, nullptr, nullptr, OU, bo, Nu, gbU,
        XM, nullptr, Wb_o, nullptr, nullptr, nullptr, OM, bo, Nm,
        HC, O);
}

// Round 12
// 248.233 us; speedup vs baseline: 4.0901x; 1.0191x over previous
//
#include <hip/hip_runtime.h>
#include <hip/hip_bf16.h>
#include <cstdint>

// ---------------------------------------------------------------------------
// HGAT: 2-layer hetero GAT (user<->movie), H=4 heads, C=32, HC=128.
// GEMMs on bf16 MFMA 16x16x32, fp32 accumulate; folded attention matrix V
// appended to packed weights so hs+att come out of one GEMM (MODE 0).
// Edge aggregation: CSR by dst, 16 lanes/node, ushort8 (16B) loads; src
// attention logits stored bf16 (8B/node, 0.8MB table -> L2-resident gather).
// CSR build: rank-from-hist (atomic-free fill), dst-windowed scatter (NWIN=2).
// REVERTED experiments (measured net-negative):
//   - degree-sorted node perm (r9/r10): perm indirection de-coalesced writes.
//   - src-windowed CSR (r11): reuse/window/XCD = 25/8/8 < 1 -> no L2 gain,
//     fragmented segments killed the 4-deep unroll (253us vs 247.8us).
// Softmax max-subtraction skipped (logits bounded; shift-invariant; validated).
// ---------------------------------------------------------------------------

#define HC 128
#define HH 4
#define NWIN 2   // fill scatter windows (over dst)

typedef __attribute__((ext_vector_type(8))) short bf16x8;
typedef __attribute__((ext_vector_type(4))) float f32x4;

__device__ __forceinline__ short f2bf(float f) {
    return __builtin_bit_cast(short, __float2bfloat16(f));
}
__device__ __forceinline__ float bf2f(ushort u) {
    return __builtin_bit_cast(float, ((unsigned)u) << 16);
}

// ---------------- fold attention: v[k, coff+h] = sum_c W[k,h*32+c]*a[h,c] ---
struct VT { const float* W[8]; const float* a[8]; float* v[8]; };
__global__ void make_v_all_k(VT t) {
    int gid = blockIdx.x * 256 + threadIdx.x;
    int task, base;
    if (gid < 1024) { task = gid >> 8; base = gid & 255; }
    else if (gid < 3072) { int g = gid - 1024; task = 4 + (g >> 9); base = g & 511; }
    else return;
    int k = base >> 2, h = base & 3;
    int coff = (task & 1) * 4;
    const float* wr = t.W[task] + (size_t)k * HC + h * 32;
    const float* ar = t.a[task] + h * 32;
    float s = 0.f;
    #pragma unroll
    for (int c = 0; c < 32; ++c) s = fmaf(wr[c], ar[c], s);
    t.v[task][k * 8 + coff + h] = s;
}

// ---------------- pack Wb[n][k] = bf16(W[k][n]); rows Nw..Nw+7 = V ----------
struct PT { const float* W[5]; const float* V[5]; ushort* Wb[5];
            int K[5]; int Nw[5]; int start[6]; };
__global__ void pack_all_k(PT t) {
    int gid = blockIdx.x * 256 + threadIdx.x;
    if (gid >= t.start[5]) return;
    int task = 0;
    while (gid >= t.start[task + 1]) ++task;
    int loc = gid - t.start[task];
    int K = t.K[task], Nw = t.Nw[task];
    int n = loc / K, k = loc % K;
    float v = 0.f;
    if (n < Nw) v = t.W[task][(size_t)k * Nw + n];
    else if (t.V[task] != nullptr && n < Nw + 8) v = t.V[task][k * 8 + (n - Nw)];
    t.Wb[task][loc] = (ushort)f2bf(v);
}

// ---------------- dual-segment bf16 MFMA GEMM -------------------------------
// MODE 0: hs out (bf16 [M,128]) + atts bf16 [M,4] + attd fp32 [M,4].
// MODE 1: fp32 C[M,ldc] + bias. ABF: A dense bf16 (ushort), else fp32 (+idx).
template <int NT, int MODE, bool ABF>
__global__ __launch_bounds__(256) void gemm_dual_k(
    const void* A0, const int* idx0, const ushort* Wb0, ushort* hsb0,
    ushort* atts0, float* attd0, float* C0, const float* bias0, int M0, int nb0,
    const void* A1, const int* idx1, const ushort* Wb1, ushort* hsb1,
    ushort* atts1, float* attd1, float* C1, const float* bias1, int M1,
    int K, int ldc) {
    const void* A; const int* aidx; const ushort* Wb; ushort* hsb;
    ushort* atts; float* attd; float* C; const float* bias; int M, bid;
    if ((int)blockIdx.x < nb0) {
        A = A0; aidx = idx0; Wb = Wb0; hsb = hsb0; atts = atts0; attd = attd0;
        C = C0; bias = bias0; M = M0; bid = blockIdx.x;
    } else {
        A = A1; aidx = idx1; Wb = Wb1; hsb = hsb1; atts = atts1; attd = attd1;
        C = C1; bias = bias1; M = M1; bid = blockIdx.x - nb0;
    }
    int lane = threadIdx.x & 63;
    int wave = threadIdx.x >> 6;
    int m_base = bid * 128 + wave * 32;
    int lm = lane & 15;      // A row-in-tile / C col-in-tile
    int kg = lane >> 4;      // k-group (8 consecutive k)

    int r0 = m_base + lm, r1 = r0 + 16;
    int cr0 = r0 < M ? r0 : M - 1;
    int cr1 = r1 < M ? r1 : M - 1;
    int row0 = aidx ? aidx[cr0] : cr0;
    int row1 = aidx ? aidx[cr1] : cr1;
    const ushort* bp = Wb + (size_t)lm * K + kg * 8;

    f32x4 acc[2][NT] = {};
    for (int k0 = 0; k0 < K; k0 += 32) {
        bf16x8 a[2];
        if (ABF) {
            const ushort* a0p = (const ushort*)A + (size_t)row0 * K + kg * 8;
            const ushort* a1p = (const ushort*)A + (size_t)row1 * K + kg * 8;
            a[0] = *reinterpret_cast<const bf16x8*>(a0p + k0);
            a[1] = *reinterpret_cast<const bf16x8*>(a1p + k0);
        } else {
            const float* a0p = (const float*)A + (size_t)row0 * K + kg * 8;
            const float* a1p = (const float*)A + (size_t)row1 * K + kg * 8;
            float af[2][8];
            *reinterpret_cast<float4*>(&af[0][0]) = *reinterpret_cast<const float4*>(a0p + k0);
            *reinterpret_cast<float4*>(&af[0][4]) = *reinterpret_cast<const float4*>(a0p + k0 + 4);
            *reinterpret_cast<float4*>(&af[1][0]) = *reinterpret_cast<const float4*>(a1p + k0);
            *reinterpret_cast<float4*>(&af[1][4]) = *reinterpret_cast<const float4*>(a1p + k0 + 4);
            #pragma unroll
            for (int mi = 0; mi < 2; ++mi)
                #pragma unroll
                for (int j = 0; j < 8; ++j) a[mi][j] = f2bf(af[mi][j]);
        }
        #pragma unroll
        for (int nt = 0; nt < NT; ++nt) {
            bf16x8 b = *reinterpret_cast<const bf16x8*>(bp + (size_t)nt * 16 * K + k0);
            acc[0][nt] = __builtin_amdgcn_mfma_f32_16x16x32_bf16(a[0], b, acc[0][nt], 0, 0, 0);
            acc[1][nt] = __builtin_amdgcn_mfma_f32_16x16x32_bf16(a[1], b, acc[1][nt], 0, 0, 0);
        }
    }
    #pragma unroll
    for (int mi = 0; mi < 2; ++mi) {
        int rowb = m_base + mi * 16 + kg * 4;
        if (MODE == 0) {
            #pragma unroll
            for (int nt = 0; nt < NT - 1; ++nt) {
                int col = nt * 16 + lm;
                #pragma unroll
                for (int r = 0; r < 4; ++r) {
                    int row = rowb + r;
                    if (row < M) hsb[(size_t)row * HC + col] = (ushort)f2bf(acc[mi][nt][r]);
                }
            }
            // last tile: cols 0-3 = src logits (bf16), 4-7 = dst logits (fp32)
            #pragma unroll
            for (int r = 0; r < 4; ++r) {
                int row = rowb + r;
                if (row < M) {
                    float v = acc[mi][NT - 1][r];
                    if (lm < 4) atts[(size_t)row * 4 + lm] = (ushort)f2bf(v);
                    else if (lm < 8) attd[(size_t)row * 4 + (lm - 4)] = v;
                }
            }
        } else {
            #pragma unroll
            for (int nt = 0; nt < NT; ++nt) {
                int col = nt * 16 + lm;
                float bv = bias[col];
                #pragma unroll
                for (int r = 0; r < 4; ++r) {
                    int row = rowb + r;
                    if (row < M) C[(size_t)row * ldc + col] = acc[mi][nt][r] + bv;
                }
            }
        }
    }
}

// ---------------- CSR build (dual edge-type) --------------------------------
// hist also emits rank[e] = old count = edge's within-dst slot (coalesced).
__global__ void hist_dual_k(const int* __restrict__ d0, int* __restrict__ c0, int E0,
                            const int* __restrict__ d1, int* __restrict__ c1, int E1,
                            int* __restrict__ rank) {
    int e = blockIdx.x * 256 + threadIdx.x;
    if (e < E0) rank[e] = atomicAdd(&c0[d0[e]], 1);
    else if (e - E0 < E1) rank[e] = atomicAdd(&c1[d1[e - E0]], 1);
}

__device__ __forceinline__ void scan_block_body(
    const int* deg, int n, int len, int* out, int* partial, int b) {
    __shared__ int s[256];
    int i = b * 256 + threadIdx.x;
    int v = (i < n) ? deg[i] : 0;
    s[threadIdx.x] = v;
    __syncthreads();
    for (int off = 1; off < 256; off <<= 1) {
        int t = (threadIdx.x >= off) ? s[threadIdx.x - off] : 0;
        __syncthreads();
        s[threadIdx.x] += t;
        __syncthreads();
    }
    if (i < len) out[i] = s[threadIdx.x] - v;
    if (threadIdx.x == 255) partial[b] = s[255];
}

__global__ void scan_block_dual_k(const int* dM, int nM, int* rsM, int* pM, int nbM,
                                  const int* dU, int nU, int* rsU, int* pU) {
    if ((int)blockIdx.x < nbM)
        scan_block_body(dM, nM, nM + 1, rsM, pM, blockIdx.x);
    else
        scan_block_body(dU, nU, nU + 1, rsU, pU, blockIdx.x - nbM);
}

__global__ void scan_partial_dual_k(int* pM, int nbM, int* pU, int nbU) {
    __shared__ int s[512];
    int t = threadIdx.x;
    for (int seg = 0; seg < 2; ++seg) {
        int* p = seg ? pU : pM;
        int nb = seg ? nbU : nbM;
        int v = (t < nb) ? p[t] : 0;
        s[t] = v;
        __syncthreads();
        for (int off = 1; off < 512; off <<= 1) {
            int x = (t >= off) ? s[t - off] : 0;
            __syncthreads();
            s[t] += x;
            __syncthreads();
        }
        if (t < nb) p[t] = s[t] - v;
        __syncthreads();
    }
}

__global__ void add_off_dual_k(int* __restrict__ oM, const int* __restrict__ pM,
                               int lenM, int nbM,
                               int* __restrict__ oU, const int* __restrict__ pU,
                               int lenU) {
    int b = blockIdx.x;
    if (b < nbM) {
        int i = b * 256 + threadIdx.x;
        if (i < lenM) oM[i] += pM[b];
    } else {
        b -= nbM;
        int i = b * 256 + threadIdx.x;
        if (i < lenU) oU[i] += pU[b];
    }
}

// atomic-free, dst-windowed scatter: window w handles dst in [w*n/NWIN, ...).
__global__ void fill_dual_k(const int* __restrict__ s0, const int* __restrict__ d0,
                            const int* __restrict__ rs0, int* __restrict__ csr0,
                            int E0, int n0,
                            const int* __restrict__ s1, const int* __restrict__ d1,
                            const int* __restrict__ rs1, int* __restrict__ csr1,
                            int E1, int n1,
                            const int* __restrict__ rank) {
    int e = blockIdx.x * 256 + threadIdx.x;
    int w = blockIdx.y;
    if (e < E0) {
        int d = d0[e];
        int lo = (int)((long)w * n0 / NWIN), hi = (int)((long)(w + 1) * n0 / NWIN);
        if (d >= lo && d < hi) csr0[rs0[d] + rank[e]] = s0[e];
    } else if (e - E0 < E1) {
        int e1 = e - E0;
        int d = d1[e1];
        int lo = (int)((long)w * n1 / NWIN), hi = (int)((long)(w + 1) * n1 / NWIN);
        if (d >= lo && d < hi) csr1[rs1[d] + rank[e]] = s1[e1];
    }
}

// ---------------- per-dst aggregation: 16 lanes/node, ushort8 loads ---------
// Lane c in [0,16): channels 8c..8c+7 (16B load); head h = c>>2.
// src logits read from bf16 [N,4] table (0.8MB user-side -> L2-resident).
template <bool WF32, bool WBF>
__global__ __launch_bounds__(256) void agg16_dual_k(
    const int* __restrict__ rs0, const int* __restrict__ csr0,
    const ushort* __restrict__ hsb0, const ushort* __restrict__ atts0,
    const float* __restrict__ attd0, const float* __restrict__ bias0,
    float* __restrict__ out0, ushort* __restrict__ outb0, int n0,
    const int* __restrict__ rs1, const int* __restrict__ csr1,
    const ushort* __restrict__ hsb1, const ushort* __restrict__ atts1,
    const float* __restrict__ attd1, const float* __restrict__ bias1,
    float* __restrict__ out1, ushort* __restrict__ outb1, int n1) {
    int g = (int)((blockIdx.x * 256u + threadIdx.x) >> 4);   // 16 nodes/block
    const int* rs; const int* csr; const ushort* hsb; const ushort* atts;
    const float* attd; const float* bias; float* out; ushort* outb; int node;
    if (g < n0) {
        rs = rs0; csr = csr0; hsb = hsb0; atts = atts0; attd = attd0;
        bias = bias0; out = out0; outb = outb0; node = g;
    } else {
        node = g - n0;
        if (node >= n1) return;
        rs = rs1; csr = csr1; hsb = hsb1; atts = atts1; attd = attd1;
        bias = bias1; out = out1; outb = outb1;
    }
    int c = threadIdx.x & 15;    // channels 8c..8c+7
    int h = c >> 2;              // head (32 ch per head, 4 lanes per head)
    float ad = attd[node * 4 + h];
    int s0 = rs[node], s1 = rs[node + 1];
    float acc[8] = {};
    float wsum = 0.f;
    int i = s0;
    for (; i + 4 <= s1; i += 4) {            // 4 edge-rows in flight
        int sx[4];
        #pragma unroll
        for (int j = 0; j < 4; ++j) sx[j] = csr[i + j];
        bf16x8 hv[4]; float el[4];
        #pragma unroll
        for (int j = 0; j < 4; ++j) {
            hv[j] = *reinterpret_cast<const bf16x8*>(hsb + (size_t)sx[j] * HC + 8 * c);
            el[j] = bf2f(atts[(size_t)sx[j] * 4 + h]);
        }
        #pragma unroll
        for (int j = 0; j < 4; ++j) {
            float e = el[j] + ad;
            e = e > 0.f ? e : 0.2f * e;
            float w = __expf(e);
            wsum += w;
            #pragma unroll
            for (int k = 0; k < 8; ++k)
                acc[k] = fmaf(w, bf2f((ushort)hv[j][k]), acc[k]);
        }
    }
    for (; i < s1; ++i) {
        int src = csr[i];
        bf16x8 hv = *reinterpret_cast<const bf16x8*>(hsb + (size_t)src * HC + 8 * c);
        float e = bf2f(atts[(size_t)src * 4 + h]) + ad;
        e = e > 0.f ? e : 0.2f * e;
        float w = __expf(e);
        wsum += w;
        #pragma unroll
        for (int k = 0; k < 8; ++k)
            acc[k] = fmaf(w, bf2f((ushort)hv[k]), acc[k]);
    }
    float inv = 1.f / (wsum + 1e-16f);
    float v[8];
    #pragma unroll
    for (int k = 0; k < 8; ++k) {
        v[k] = fmaf(acc[k], inv, bias[8 * c + k]);
        v[k] = v[k] > 0.f ? v[k] : 0.01f * v[k];
    }
    if (WF32) {
        float4 o0 = make_float4(v[0], v[1], v[2], v[3]);
        float4 o1 = make_float4(v[4], v[5], v[6], v[7]);
        reinterpret_cast<float4*>(out + (size_t)node * HC + 8 * c)[0] = o0;
        reinterpret_cast<float4*>(out + (size_t)node * HC + 8 * c)[1] = o1;
    }
    if (WBF) {
        bf16x8 u;
        #pragma unroll
        for (int k = 0; k < 8; ++k) u[k] = f2bf(v[k]);
        *reinterpret_cast<bf16x8*>(outb + (size_t)node * HC + 8 * c) = u;
    }
}

// ---------------------------------------------------------------------------
extern "C" void kernel_launch(void* const* d_in, const int* in_sizes, int n_in,
                              void* d_out, int out_size, void* d_ws, size_t ws_size,
                              hipStream_t stream) {
    const int Nu = in_sizes[0];
    const int Nm = in_sizes[1];
    const int E1 = in_sizes[2];   // um edges
    const int E2 = in_sizes[4];   // mu edges
    const int D  = in_sizes[6] / Nu;   // 64
    const int O  = in_sizes[27];       // 64

    const int*   user_ids  = (const int*)d_in[0];
    const int*   movie_ids = (const int*)d_in[1];
    const int*   um_src    = (const int*)d_in[2];
    const int*   um_dst    = (const int*)d_in[3];
    const int*   mu_src    = (const int*)d_in[4];
    const int*   mu_dst    = (const int*)d_in[5];
    const float* user_emb  = (const float*)d_in[6];
    const float* movie_emb = (const float*)d_in[7];
    const float* l1_um_Wsrc = (const float*)d_in[8];
    const float* l1_um_Wdst = (const float*)d_in[9];
    const float* l1_um_asrc = (const float*)d_in[10];
    const float* l1_um_adst = (const float*)d_in[11];
    const float* l1_um_b    = (const float*)d_in[12];
    const float* l1_mu_Wsrc = (const float*)d_in[13];
    const float* l1_mu_Wdst = (const float*)d_in[14];
    const float* l1_mu_asrc = (const float*)d_in[15];
    const float* l1_mu_adst = (const float*)d_in[16];
    const float* l1_mu_b    = (const float*)d_in[17];
    const float* l2_um_W    = (const float*)d_in[18];
    const float* l2_um_asrc = (const float*)d_in[19];
    const float* l2_um_adst = (const float*)d_in[20];
    const float* l2_um_b    = (const float*)d_in[21];
    const float* l2_mu_W    = (const float*)d_in[22];
    const float* l2_mu_asrc = (const float*)d_in[23];
    const float* l2_mu_adst = (const float*)d_in[24];
    const float* l2_mu_b    = (const float*)d_in[25];
    const float* Wo         = (const float*)d_in[26];
    const float* bo         = (const float*)d_in[27];

    // ---- workspace carve ----
    char* p = (char*)d_ws;
    auto alloc = [&](size_t bytes) { void* r = p; p += (bytes + 255) & ~(size_t)255; return r; };
    ushort* hs_u = (ushort*)alloc((size_t)Nu * HC * 2);
    ushort* hs_m = (ushort*)alloc((size_t)Nm * HC * 2);
    ushort* XUb  = (ushort*)alloc((size_t)Nu * HC * 2);
    ushort* XMb  = (ushort*)alloc((size_t)Nm * HC * 2);
    ushort* atts_u = (ushort*)alloc((size_t)Nu * 4 * 2);   // bf16 src logits
    ushort* atts_m = (ushort*)alloc((size_t)Nm * 4 * 2);
    float* attd_u = (float*)alloc((size_t)Nu * 4 * 4);
    float* attd_m = (float*)alloc((size_t)Nm * 4 * 4);
    float* V_u1  = (float*)alloc((size_t)HC * 8 * 4);
    float* V_m1  = (float*)alloc((size_t)HC * 8 * 4);
    float* V_u2  = (float*)alloc((size_t)HC * 8 * 4);
    float* V_m2  = (float*)alloc((size_t)HC * 8 * 4);
    ushort* Wb_u1 = (ushort*)alloc((size_t)144 * D * 2);
    ushort* Wb_m1 = (ushort*)alloc((size_t)144 * D * 2);
    ushort* Wb_u2 = (ushort*)alloc((size_t)144 * HC * 2);
    ushort* Wb_m2 = (ushort*)alloc((size_t)144 * HC * 2);
    ushort* Wb_o  = (ushort*)alloc((size_t)64 * HC * 2);
    int* um_rs  = (int*)alloc((size_t)(Nm + 1) * 4);
    int* mu_rs  = (int*)alloc((size_t)(Nu + 1) * 4);
    int* cnts   = (int*)alloc((size_t)(Nm + Nu) * 4);   // um_cnt | mu_cnt
    int* um_cnt = cnts;
    int* mu_cnt = cnts + Nm;
    int* um_csr = (int*)alloc((size_t)E1 * 4);
    int* mu_csr = (int*)alloc((size_t)E2 * 4);
    int* rank   = (int*)alloc((size_t)(E1 + E2) * 4);
    int* partM  = (int*)alloc(512 * 4);
    int* partU  = (int*)alloc(512 * 4);

    auto cdiv = [](int a, int b) { return (a + b - 1) / b; };

    // ---- fold attention + pack weights (x-independent) ----
    {
        VT vt;
        const float* Ws[8] = {l1_um_Wsrc, l1_mu_Wdst, l1_mu_Wsrc, l1_um_Wdst,
                              l2_um_W, l2_mu_W, l2_mu_W, l2_um_W};
        const float* as[8] = {l1_um_asrc, l1_mu_adst, l1_mu_asrc, l1_um_adst,
                              l2_um_asrc, l2_mu_adst, l2_mu_asrc, l2_um_adst};
        float* vs[8] = {V_u1, V_u1, V_m1, V_m1, V_u2, V_u2, V_m2, V_m2};
        for (int i = 0; i < 8; ++i) { vt.W[i] = Ws[i]; vt.a[i] = as[i]; vt.v[i] = vs[i]; }
        make_v_all_k<<<12, 256, 0, stream>>>(vt);

        PT pt;
        const float* pW[5] = {l1_um_Wsrc, l1_mu_Wsrc, l2_um_W, l2_mu_W, Wo};
        const float* pV[5] = {V_u1, V_m1, V_u2, V_m2, nullptr};
        ushort* pB[5] = {Wb_u1, Wb_m1, Wb_u2, Wb_m2, Wb_o};
        int pK[5] = {D, D, HC, HC, HC};
        int pN[5] = {HC, HC, HC, HC, 64};
        int cum = 0;
        for (int i = 0; i < 5; ++i) {
            pt.W[i] = pW[i]; pt.V[i] = pV[i]; pt.Wb[i] = pB[i];
            pt.K[i] = pK[i]; pt.Nw[i] = pN[i];
            pt.start[i] = cum;
            cum += (i < 4 ? 144 : 64) * pK[i];
        }
        pt.start[5] = cum;
        pack_all_k<<<cdiv(cum, 256), 256, 0, stream>>>(pt);
    }

    // ---- CSR build (both edge types, reused by both layers) ----
    int nbM = cdiv(Nm + 1, 256), nbU = cdiv(Nu + 1, 256);
    hipMemsetAsync(cnts, 0, (size_t)(Nm + Nu) * 4, stream);
    hist_dual_k<<<cdiv(E1 + E2, 256), 256, 0, stream>>>(
        um_dst, um_cnt, E1, mu_dst, mu_cnt, E2, rank);
    scan_block_dual_k<<<nbM + nbU, 256, 0, stream>>>(um_cnt, Nm, um_rs, partM, nbM,
                                                     mu_cnt, Nu, mu_rs, partU);
    scan_partial_dual_k<<<1, 512, 0, stream>>>(partM, nbM, partU, nbU);
    add_off_dual_k<<<nbM + nbU, 256, 0, stream>>>(um_rs, partM, Nm + 1, nbM,
                                                  mu_rs, partU, Nu + 1);
    {
        dim3 g(cdiv(E1 + E2, 256), NWIN);
        fill_dual_k<<<g, 256, 0, stream>>>(
            um_src, um_dst, um_rs, um_csr, E1, Nm,
            mu_src, mu_dst, mu_rs, mu_csr, E2, Nu, rank);
    }

    // output slots: [out_user | out_movie | xu | xm]
    float* OU = (float*)d_out;
    float* OM = OU + (size_t)Nu * O;
    float* XU = OM + (size_t)Nm * O;
    float* XM = XU + (size_t)Nu * HC;

    int gbU = cdiv(Nu, 128), gbM = cdiv(Nm, 128);
    int aggBlocks = cdiv((Nm + Nu) * 16, 256);

    // ---- layer 1: A = fp32 embeddings (gathered), K = D ----
    gemm_dual_k<9, 0, false><<<gbU + gbM, 256, 0, stream>>>(
        user_emb, user_ids, Wb_u1, hs_u, atts_u, attd_u, nullptr, nullptr, Nu, gbU,
        movie_emb, movie_ids, Wb_m1, hs_m, atts_m, attd_m, nullptr, nullptr, Nm,
        D, 0);
    // layer-1 agg: bf16 activations only (fp32 slot would be overwritten by L2)
    agg16_dual_k<false, true><<<aggBlocks, 256, 0, stream>>>(
        um_rs, um_csr, hs_u, atts_u, attd_m, l1_um_b, nullptr, XMb, Nm,
        mu_rs, mu_csr, hs_m, atts_m, attd_u, l1_mu_b, nullptr, XUb, Nu);

    // ---- layer 2: A = bf16 activations, K = HC ----
    gemm_dual_k<9, 0, true><<<gbU + gbM, 256, 0, stream>>>(
        XUb, nullptr, Wb_u2, hs_u, atts_u, attd_u, nullptr, nullptr, Nu, gbU,
        XMb, nullptr, Wb_m2, hs_m, atts_m, attd_m, nullptr, nullptr, Nm,
        HC, 0);
    // layer-2 agg: fp32 only (xu/xm are outputs; proj reads fp32)
    agg16_dual_k<true, false><<<aggBlocks, 256, 0, stream>>>(
        um_rs, um_csr, hs_u, atts_u, attd_m, l2_um_b, XM, nullptr, Nm,
        mu_rs, mu_csr, hs_m, atts_m, attd_u, l2_mu_b, XU, nullptr, Nu);

    // ---- final projection: out = x @ Wo + bo (fp32 A) ----
    gemm_dual_k<4, 1, false><<<gbU + gbM, 256, 0, stream>>>(
        XU, nullptr, Wb_o, nullptr, nullptr, nullptr, OU, bo, Nu, gbU,
        XM, nullptr, Wb_o, nullptr, nullptr, nullptr, OM, bo, Nm,
        HC, O);
}

// Round 13
// 245.065 us; speedup vs baseline: 4.1430x; 1.0129x over previous
//
#include <hip/hip_runtime.h>
#include <hip/hip_bf16.h>
#include <cstdint>

// ---------------------------------------------------------------------------
// HGAT: 2-layer hetero GAT (user<->movie), H=4 heads, C=32, HC=128.
// GEMMs on bf16 MFMA 16x16x32, fp32 accumulate; folded attention matrix V
// appended to packed weights so hs+att come out of one GEMM (MODE 0).
// SCHEDULE FUSION: the CSR hist pass (1M returning device-scope atomics,
// 54us of pure latency at 0.4% VALUBusy) is data-independent of layer-1's
// GEMM -> its blocks are APPENDED to the GEMM1 dispatch so the atomic
// latency hides under MFMA compute (r12 showed them serialized: 25+54us).
// hist does 4 edges/thread for 4x atomic memory-level parallelism.
// Edge aggregation: CSR by dst, 16 lanes/node, ushort8 (16B) loads; src
// attention logits stored bf16 (0.8MB table -> L2-resident gather).
// CSR build: rank-from-hist (atomic-free fill), dst-windowed scatter (NWIN=2).
// REVERTED experiments (measured net-negative): degree-sort perm (r9/r10),
// src-windowed CSR (r11: reuse/window/XCD < 1 -> no L2 gain).
// Softmax max-subtraction skipped (logits bounded; shift-invariant; validated).
// ---------------------------------------------------------------------------

#define HC 128
#define HH 4
#define NWIN 2   // fill scatter windows (over dst)

typedef __attribute__((ext_vector_type(8))) short bf16x8;
typedef __attribute__((ext_vector_type(4))) float f32x4;

__device__ __forceinline__ short f2bf(float f) {
    return __builtin_bit_cast(short, __float2bfloat16(f));
}
__device__ __forceinline__ float bf2f(ushort u) {
    return __builtin_bit_cast(float, ((unsigned)u) << 16);
}

// ---------------- fold attention: v[k, coff+h] = sum_c W[k,h*32+c]*a[h,c] ---
struct VT { const float* W[8]; const float* a[8]; float* v[8]; };
__global__ void make_v_all_k(VT t) {
    int gid = blockIdx.x * 256 + threadIdx.x;
    int task, base;
    if (gid < 1024) { task = gid >> 8; base = gid & 255; }
    else if (gid < 3072) { int g = gid - 1024; task = 4 + (g >> 9); base = g & 511; }
    else return;
    int k = base >> 2, h = base & 3;
    int coff = (task & 1) * 4;
    const float* wr = t.W[task] + (size_t)k * HC + h * 32;
    const float* ar = t.a[task] + h * 32;
    float s = 0.f;
    #pragma unroll
    for (int c = 0; c < 32; ++c) s = fmaf(wr[c], ar[c], s);
    t.v[task][k * 8 + coff + h] = s;
}

// ---------------- pack Wb[n][k] = bf16(W[k][n]); rows Nw..Nw+7 = V ----------
struct PT { const float* W[5]; const float* V[5]; ushort* Wb[5];
            int K[5]; int Nw[5]; int start[6]; };
__global__ void pack_all_k(PT t) {
    int gid = blockIdx.x * 256 + threadIdx.x;
    if (gid >= t.start[5]) return;
    int task = 0;
    while (gid >= t.start[task + 1]) ++task;
    int loc = gid - t.start[task];
    int K = t.K[task], Nw = t.Nw[task];
    int n = loc / K, k = loc % K;
    float v = 0.f;
    if (n < Nw) v = t.W[task][(size_t)k * Nw + n];
    else if (t.V[task] != nullptr && n < Nw + 8) v = t.V[task][k * 8 + (n - Nw)];
    t.Wb[task][loc] = (ushort)f2bf(v);
}

// ---------------- dual-segment bf16 MFMA GEMM (+ optional fused hist) -------
// MODE 0: hs out (bf16 [M,128]) + atts bf16 [M,4] + attd fp32 [M,4].
// MODE 1: fp32 C[M,ldc] + bias. ABF: A dense bf16 (ushort), else fp32 (+idx).
// HIST: blocks beyond nb0+nb1 run the CSR hist pass (rank[e] = old count of
// dst[e]); 4 edges/thread for atomic MLP. Latency hides under GEMM compute.
template <int NT, int MODE, bool ABF, bool HIST>
__global__ __launch_bounds__(256) void gemm_dual_k(
    const void* A0, const int* idx0, const ushort* Wb0, ushort* hsb0,
    ushort* atts0, float* attd0, float* C0, const float* bias0, int M0, int nb0,
    const void* A1, const int* idx1, const ushort* Wb1, ushort* hsb1,
    ushort* atts1, float* attd1, float* C1, const float* bias1, int M1, int nb1,
    int K, int ldc,
    const int* hd0, int* hc0, int Eh0,
    const int* hd1, int* hc1, int Eh1, int* hrank) {
    const void* A; const int* aidx; const ushort* Wb; ushort* hsb;
    ushort* atts; float* attd; float* C; const float* bias; int M, bid;
    int nbg = nb0 + nb1;
    if (HIST && (int)blockIdx.x >= nbg) {
        int base = ((int)blockIdx.x - nbg) * 1024 + threadIdx.x;
        #pragma unroll
        for (int j = 0; j < 4; ++j) {
            int e = base + j * 256;
            if (e < Eh0) hrank[e] = atomicAdd(&hc0[hd0[e]], 1);
            else if (e - Eh0 < Eh1) hrank[e] = atomicAdd(&hc1[hd1[e - Eh0]], 1);
        }
        return;
    }
    if ((int)blockIdx.x < nb0) {
        A = A0; aidx = idx0; Wb = Wb0; hsb = hsb0; atts = atts0; attd = attd0;
        C = C0; bias = bias0; M = M0; bid = blockIdx.x;
    } else {
        A = A1; aidx = idx1; Wb = Wb1; hsb = hsb1; atts = atts1; attd = attd1;
        C = C1; bias = bias1; M = M1; bid = blockIdx.x - nb0;
    }
    int lane = threadIdx.x & 63;
    int wave = threadIdx.x >> 6;
    int m_base = bid * 128 + wave * 32;
    int lm = lane & 15;      // A row-in-tile / C col-in-tile
    int kg = lane >> 4;      // k-group (8 consecutive k)

    int r0 = m_base + lm, r1 = r0 + 16;
    int cr0 = r0 < M ? r0 : M - 1;
    int cr1 = r1 < M ? r1 : M - 1;
    int row0 = aidx ? aidx[cr0] : cr0;
    int row1 = aidx ? aidx[cr1] : cr1;
    const ushort* bp = Wb + (size_t)lm * K + kg * 8;

    f32x4 acc[2][NT] = {};
    for (int k0 = 0; k0 < K; k0 += 32) {
        bf16x8 a[2];
        if (ABF) {
            const ushort* a0p = (const ushort*)A + (size_t)row0 * K + kg * 8;
            const ushort* a1p = (const ushort*)A + (size_t)row1 * K + kg * 8;
            a[0] = *reinterpret_cast<const bf16x8*>(a0p + k0);
            a[1] = *reinterpret_cast<const bf16x8*>(a1p + k0);
        } else {
            const float* a0p = (const float*)A + (size_t)row0 * K + kg * 8;
            const float* a1p = (const float*)A + (size_t)row1 * K + kg * 8;
            float af[2][8];
            *reinterpret_cast<float4*>(&af[0][0]) = *reinterpret_cast<const float4*>(a0p + k0);
            *reinterpret_cast<float4*>(&af[0][4]) = *reinterpret_cast<const float4*>(a0p + k0 + 4);
            *reinterpret_cast<float4*>(&af[1][0]) = *reinterpret_cast<const float4*>(a1p + k0);
            *reinterpret_cast<float4*>(&af[1][4]) = *reinterpret_cast<const float4*>(a1p + k0 + 4);
            #pragma unroll
            for (int mi = 0; mi < 2; ++mi)
                #pragma unroll
                for (int j = 0; j < 8; ++j) a[mi][j] = f2bf(af[mi][j]);
        }
        #pragma unroll
        for (int nt = 0; nt < NT; ++nt) {
            bf16x8 b = *reinterpret_cast<const bf16x8*>(bp + (size_t)nt * 16 * K + k0);
            acc[0][nt] = __builtin_amdgcn_mfma_f32_16x16x32_bf16(a[0], b, acc[0][nt], 0, 0, 0);
            acc[1][nt] = __builtin_amdgcn_mfma_f32_16x16x32_bf16(a[1], b, acc[1][nt], 0, 0, 0);
        }
    }
    #pragma unroll
    for (int mi = 0; mi < 2; ++mi) {
        int rowb = m_base + mi * 16 + kg * 4;
        if (MODE == 0) {
            #pragma unroll
            for (int nt = 0; nt < NT - 1; ++nt) {
                int col = nt * 16 + lm;
                #pragma unroll
                for (int r = 0; r < 4; ++r) {
                    int row = rowb + r;
                    if (row < M) hsb[(size_t)row * HC + col] = (ushort)f2bf(acc[mi][nt][r]);
                }
            }
            // last tile: cols 0-3 = src logits (bf16), 4-7 = dst logits (fp32)
            #pragma unroll
            for (int r = 0; r < 4; ++r) {
                int row = rowb + r;
                if (row < M) {
                    float v = acc[mi][NT - 1][r];
                    if (lm < 4) atts[(size_t)row * 4 + lm] = (ushort)f2bf(v);
                    else if (lm < 8) attd[(size_t)row * 4 + (lm - 4)] = v;
                }
            }
        } else {
            #pragma unroll
            for (int nt = 0; nt < NT; ++nt) {
                int col = nt * 16 + lm;
                float bv = bias[col];
                #pragma unroll
                for (int r = 0; r < 4; ++r) {
                    int row = rowb + r;
                    if (row < M) C[(size_t)row * ldc + col] = acc[mi][nt][r] + bv;
                }
            }
        }
    }
}

// ---------------- CSR build helpers ------------------------------------------
__device__ __forceinline__ void scan_block_body(
    const int* deg, int n, int len, int* out, int* partial, int b) {
    __shared__ int s[256];
    int i = b * 256 + threadIdx.x;
    int v = (i < n) ? deg[i] : 0;
    s[threadIdx.x] = v;
    __syncthreads();
    for (int off = 1; off < 256; off <<= 1) {
        int t = (threadIdx.x >= off) ? s[threadIdx.x - off] : 0;
        __syncthreads();
        s[threadIdx.x] += t;
        __syncthreads();
    }
    if (i < len) out[i] = s[threadIdx.x] - v;
    if (threadIdx.x == 255) partial[b] = s[255];
}

__global__ void scan_block_dual_k(const int* dM, int nM, int* rsM, int* pM, int nbM,
                                  const int* dU, int nU, int* rsU, int* pU) {
    if ((int)blockIdx.x < nbM)
        scan_block_body(dM, nM, nM + 1, rsM, pM, blockIdx.x);
    else
        scan_block_body(dU, nU, nU + 1, rsU, pU, blockIdx.x - nbM);
}

__global__ void scan_partial_dual_k(int* pM, int nbM, int* pU, int nbU) {
    __shared__ int s[512];
    int t = threadIdx.x;
    for (int seg = 0; seg < 2; ++seg) {
        int* p = seg ? pU : pM;
        int nb = seg ? nbU : nbM;
        int v = (t < nb) ? p[t] : 0;
        s[t] = v;
        __syncthreads();
        for (int off = 1; off < 512; off <<= 1) {
            int x = (t >= off) ? s[t - off] : 0;
            __syncthreads();
            s[t] += x;
            __syncthreads();
        }
        if (t < nb) p[t] = s[t] - v;
        __syncthreads();
    }
}

__global__ void add_off_dual_k(int* __restrict__ oM, const int* __restrict__ pM,
                               int lenM, int nbM,
                               int* __restrict__ oU, const int* __restrict__ pU,
                               int lenU) {
    int b = blockIdx.x;
    if (b < nbM) {
        int i = b * 256 + threadIdx.x;
        if (i < lenM) oM[i] += pM[b];
    } else {
        b -= nbM;
        int i = b * 256 + threadIdx.x;
        if (i < lenU) oU[i] += pU[b];
    }
}

// atomic-free, dst-windowed scatter: window w handles dst in [w*n/NWIN, ...).
__global__ void fill_dual_k(const int* __restrict__ s0, const int* __restrict__ d0,
                            const int* __restrict__ rs0, int* __restrict__ csr0,
                            int E0, int n0,
                            const int* __restrict__ s1, const int* __restrict__ d1,
                            const int* __restrict__ rs1, int* __restrict__ csr1,
                            int E1, int n1,
                            const int* __restrict__ rank) {
    int e = blockIdx.x * 256 + threadIdx.x;
    int w = blockIdx.y;
    if (e < E0) {
        int d = d0[e];
        int lo = (int)((long)w * n0 / NWIN), hi = (int)((long)(w + 1) * n0 / NWIN);
        if (d >= lo && d < hi) csr0[rs0[d] + rank[e]] = s0[e];
    } else if (e - E0 < E1) {
        int e1 = e - E0;
        int d = d1[e1];
        int lo = (int)((long)w * n1 / NWIN), hi = (int)((long)(w + 1) * n1 / NWIN);
        if (d >= lo && d < hi) csr1[rs1[d] + rank[e]] = s1[e1];
    }
}

// ---------------- per-dst aggregation: 16 lanes/node, ushort8 loads ---------
// Lane c in [0,16): channels 8c..8c+7 (16B load); head h = c>>2.
// src logits read from bf16 [N,4] table (0.8MB user-side -> L2-resident).
template <bool WF32, bool WBF>
__global__ __launch_bounds__(256) void agg16_dual_k(
    const int* __restrict__ rs0, const int* __restrict__ csr0,
    const ushort* __restrict__ hsb0, const ushort* __restrict__ atts0,
    const float* __restrict__ attd0, const float* __restrict__ bias0,
    float* __restrict__ out0, ushort* __restrict__ outb0, int n0,
    const int* __restrict__ rs1, const int* __restrict__ csr1,
    const ushort* __restrict__ hsb1, const ushort* __restrict__ atts1,
    const float* __restrict__ attd1, const float* __restrict__ bias1,
    float* __restrict__ out1, ushort* __restrict__ outb1, int n1) {
    int g = (int)((blockIdx.x * 256u + threadIdx.x) >> 4);   // 16 nodes/block
    const int* rs; const int* csr; const ushort* hsb; const ushort* atts;
    const float* attd; const float* bias; float* out; ushort* outb; int node;
    if (g < n0) {
        rs = rs0; csr = csr0; hsb = hsb0; atts = atts0; attd = attd0;
        bias = bias0; out = out0; outb = outb0; node = g;
    } else {
        node = g - n0;
        if (node >= n1) return;
        rs = rs1; csr = csr1; hsb = hsb1; atts = atts1; attd = attd1;
        bias = bias1; out = out1; outb = outb1;
    }
    int c = threadIdx.x & 15;    // channels 8c..8c+7
    int h = c >> 2;              // head (32 ch per head, 4 lanes per head)
    float ad = attd[node * 4 + h];
    int s0 = rs[node], s1 = rs[node + 1];
    float acc[8] = {};
    float wsum = 0.f;
    int i = s0;
    for (; i + 4 <= s1; i += 4) {            // 4 edge-rows in flight
        int sx[4];
        #pragma unroll
        for (int j = 0; j < 4; ++j) sx[j] = csr[i + j];
        bf16x8 hv[4]; float el[4];
        #pragma unroll
        for (int j = 0; j < 4; ++j) {
            hv[j] = *reinterpret_cast<const bf16x8*>(hsb + (size_t)sx[j] * HC + 8 * c);
            el[j] = bf2f(atts[(size_t)sx[j] * 4 + h]);
        }
        #pragma unroll
        for (int j = 0; j < 4; ++j) {
            float e = el[j] + ad;
            e = e > 0.f ? e : 0.2f * e;
            float w = __expf(e);
            wsum += w;
            #pragma unroll
            for (int k = 0; k < 8; ++k)
                acc[k] = fmaf(w, bf2f((ushort)hv[j][k]), acc[k]);
        }
    }
    for (; i < s1; ++i) {
        int src = csr[i];
        bf16x8 hv = *reinterpret_cast<const bf16x8*>(hsb + (size_t)src * HC + 8 * c);
        float e = bf2f(atts[(size_t)src * 4 + h]) + ad;
        e = e > 0.f ? e : 0.2f * e;
        float w = __expf(e);
        wsum += w;
        #pragma unroll
        for (int k = 0; k < 8; ++k)
            acc[k] = fmaf(w, bf2f((ushort)hv[k]), acc[k]);
    }
    float inv = 1.f / (wsum + 1e-16f);
    float v[8];
    #pragma unroll
    for (int k = 0; k < 8; ++k) {
        v[k] = fmaf(acc[k], inv, bias[8 * c + k]);
        v[k] = v[k] > 0.f ? v[k] : 0.01f * v[k];
    }
    if (WF32) {
        float4 o0 = make_float4(v[0], v[1], v[2], v[3]);
        float4 o1 = make_float4(v[4], v[5], v[6], v[7]);
        reinterpret_cast<float4*>(out + (size_t)node * HC + 8 * c)[0] = o0;
        reinterpret_cast<float4*>(out + (size_t)node * HC + 8 * c)[1] = o1;
    }
    if (WBF) {
        bf16x8 u;
        #pragma unroll
        for (int k = 0; k < 8; ++k) u[k] = f2bf(v[k]);
        *reinterpret_cast<bf16x8*>(outb + (size_t)node * HC + 8 * c) = u;
    }
}

// ---------------------------------------------------------------------------
extern "C" void kernel_launch(void* const* d_in, const int* in_sizes, int n_in,
                              void* d_out, int out_size, void* d_ws, size_t ws_size,
                              hipStream_t stream) {
    const int Nu = in_sizes[0];
    const int Nm = in_sizes[1];
    const int E1 = in_sizes[2];   // um edges
    const int E2 = in_sizes[4];   // mu edges
    const int D  = in_sizes[6] / Nu;   // 64
    const int O  = in_sizes[27];       // 64

    const int*   user_ids  = (const int*)d_in[0];
    const int*   movie_ids = (const int*)d_in[1];
    const int*   um_src    = (const int*)d_in[2];
    const int*   um_dst    = (const int*)d_in[3];
    const int*   mu_src    = (const int*)d_in[4];
    const int*   mu_dst    = (const int*)d_in[5];
    const float* user_emb  = (const float*)d_in[6];
    const float* movie_emb = (const float*)d_in[7];
    const float* l1_um_Wsrc = (const float*)d_in[8];
    const float* l1_um_Wdst = (const float*)d_in[9];
    const float* l1_um_asrc = (const float*)d_in[10];
    const float* l1_um_adst = (const float*)d_in[11];
    const float* l1_um_b    = (const float*)d_in[12];
    const float* l1_mu_Wsrc = (const float*)d_in[13];
    const float* l1_mu_Wdst = (const float*)d_in[14];
    const float* l1_mu_asrc = (const float*)d_in[15];
    const float* l1_mu_adst = (const float*)d_in[16];
    const float* l1_mu_b    = (const float*)d_in[17];
    const float* l2_um_W    = (const float*)d_in[18];
    const float* l2_um_asrc = (const float*)d_in[19];
    const float* l2_um_adst = (const float*)d_in[20];
    const float* l2_um_b    = (const float*)d_in[21];
    const float* l2_mu_W    = (const float*)d_in[22];
    const float* l2_mu_asrc = (const float*)d_in[23];
    const float* l2_mu_adst = (const float*)d_in[24];
    const float* l2_mu_b    = (const float*)d_in[25];
    const float* Wo         = (const float*)d_in[26];
    const float* bo         = (const float*)d_in[27];

    // ---- workspace carve ----
    char* p = (char*)d_ws;
    auto alloc = [&](size_t bytes) { void* r = p; p += (bytes + 255) & ~(size_t)255; return r; };
    ushort* hs_u = (ushort*)alloc((size_t)Nu * HC * 2);
    ushort* hs_m = (ushort*)alloc((size_t)Nm * HC * 2);
    ushort* XUb  = (ushort*)alloc((size_t)Nu * HC * 2);
    ushort* XMb  = (ushort*)alloc((size_t)Nm * HC * 2);
    ushort* atts_u = (ushort*)alloc((size_t)Nu * 4 * 2);   // bf16 src logits
    ushort* atts_m = (ushort*)alloc((size_t)Nm * 4 * 2);
    float* attd_u = (float*)alloc((size_t)Nu * 4 * 4);
    float* attd_m = (float*)alloc((size_t)Nm * 4 * 4);
    float* V_u1  = (float*)alloc((size_t)HC * 8 * 4);
    float* V_m1  = (float*)alloc((size_t)HC * 8 * 4);
    float* V_u2  = (float*)alloc((size_t)HC * 8 * 4);
    float* V_m2  = (float*)alloc((size_t)HC * 8 * 4);
    ushort* Wb_u1 = (ushort*)alloc((size_t)144 * D * 2);
    ushort* Wb_m1 = (ushort*)alloc((size_t)144 * D * 2);
    ushort* Wb_u2 = (ushort*)alloc((size_t)144 * HC * 2);
    ushort* Wb_m2 = (ushort*)alloc((size_t)144 * HC * 2);
    ushort* Wb_o  = (ushort*)alloc((size_t)64 * HC * 2);
    int* um_rs  = (int*)alloc((size_t)(Nm + 1) * 4);
    int* mu_rs  = (int*)alloc((size_t)(Nu + 1) * 4);
    int* cnts   = (int*)alloc((size_t)(Nm + Nu) * 4);   // um_cnt | mu_cnt
    int* um_cnt = cnts;
    int* mu_cnt = cnts + Nm;
    int* um_csr = (int*)alloc((size_t)E1 * 4);
    int* mu_csr = (int*)alloc((size_t)E2 * 4);
    int* rank   = (int*)alloc((size_t)(E1 + E2) * 4);
    int* partM  = (int*)alloc(512 * 4);
    int* partU  = (int*)alloc(512 * 4);

    auto cdiv = [](int a, int b) { return (a + b - 1) / b; };

    // ---- fold attention + pack weights (x-independent) ----
    {
        VT vt;
        const float* Ws[8] = {l1_um_Wsrc, l1_mu_Wdst, l1_mu_Wsrc, l1_um_Wdst,
                              l2_um_W, l2_mu_W, l2_mu_W, l2_um_W};
        const float* as[8] = {l1_um_asrc, l1_mu_adst, l1_mu_asrc, l1_um_adst,
                              l2_um_asrc, l2_mu_adst, l2_mu_asrc, l2_um_adst};
        float* vs[8] = {V_u1, V_u1, V_m1, V_m1, V_u2, V_u2, V_m2, V_m2};
        for (int i = 0; i < 8; ++i) { vt.W[i] = Ws[i]; vt.a[i] = as[i]; vt.v[i] = vs[i]; }
        make_v_all_k<<<12, 256, 0, stream>>>(vt);

        PT pt;
        const float* pW[5] = {l1_um_Wsrc, l1_mu_Wsrc, l2_um_W, l2_mu_W, Wo};
        const float* pV[5] = {V_u1, V_m1, V_u2, V_m2, nullptr};
        ushort* pB[5] = {Wb_u1, Wb_m1, Wb_u2, Wb_m2, Wb_o};
        int pK[5] = {D, D, HC, HC, HC};
        int pN[5] = {HC, HC, HC, HC, 64};
        int cum = 0;
        for (int i = 0; i < 5; ++i) {
            pt.W[i] = pW[i]; pt.V[i] = pV[i]; pt.Wb[i] = pB[i];
            pt.K[i] = pK[i]; pt.Nw[i] = pN[i];
            pt.start[i] = cum;
            cum += (i < 4 ? 144 : 64) * pK[i];
        }
        pt.start[5] = cum;
        pack_all_k<<<cdiv(cum, 256), 256, 0, stream>>>(pt);
    }

    hipMemsetAsync(cnts, 0, (size_t)(Nm + Nu) * 4, stream);

    // output slots: [out_user | out_movie | xu | xm]
    float* OU = (float*)d_out;
    float* OM = OU + (size_t)Nu * O;
    float* XU = OM + (size_t)Nm * O;
    float* XM = XU + (size_t)Nu * HC;

    int gbU = cdiv(Nu, 128), gbM = cdiv(Nm, 128);
    int aggBlocks = cdiv((Nm + Nu) * 16, 256);
    int histBlocks = cdiv(E1 + E2, 1024);

    // ---- layer-1 GEMM (fp32 emb gathered, K=D) FUSED with CSR hist ----
    gemm_dual_k<9, 0, false, true><<<gbU + gbM + histBlocks, 256, 0, stream>>>(
        user_emb, user_ids, Wb_u1, hs_u, atts_u, attd_u, nullptr, nullptr, Nu, gbU,
        movie_emb, movie_ids, Wb_m1, hs_m, atts_m, attd_m, nullptr, nullptr, Nm, gbM,
        D, 0,
        um_dst, um_cnt, E1, mu_dst, mu_cnt, E2, rank);

    // ---- CSR scan + fill (needs hist; reused by both layers) ----
    int nbM = cdiv(Nm + 1, 256), nbU = cdiv(Nu + 1, 256);
    scan_block_dual_k<<<nbM + nbU, 256, 0, stream>>>(um_cnt, Nm, um_rs, partM, nbM,
                                                     mu_cnt, Nu, mu_rs, partU);
    scan_partial_dual_k<<<1, 512, 0, stream>>>(partM, nbM, partU, nbU);
    add_off_dual_k<<<nbM + nbU, 256, 0, stream>>>(um_rs, partM, Nm + 1, nbM,
                                                  mu_rs, partU, Nu + 1);
    {
        dim3 g(cdiv(E1 + E2, 256), NWIN);
        fill_dual_k<<<g, 256, 0, stream>>>(
            um_src, um_dst, um_rs, um_csr, E1, Nm,
            mu_src, mu_dst, mu_rs, mu_csr, E2, Nu, rank);
    }

    // layer-1 agg: bf16 activations only (fp32 slot would be overwritten by L2)
    agg16_dual_k<false, true><<<aggBlocks, 256, 0, stream>>>(
        um_rs, um_csr, hs_u, atts_u, attd_m, l1_um_b, nullptr, XMb, Nm,
        mu_rs, mu_csr, hs_m, atts_m, attd_u, l1_mu_b, nullptr, XUb, Nu);

    // ---- layer 2: A = bf16 activations, K = HC ----
    gemm_dual_k<9, 0, true, false><<<gbU + gbM, 256, 0, stream>>>(
        XUb, nullptr, Wb_u2, hs_u, atts_u, attd_u, nullptr, nullptr, Nu, gbU,
        XMb, nullptr, Wb_m2, hs_m, atts_m, attd_m, nullptr, nullptr, Nm, gbM,
        HC, 0,
        nullptr, nullptr, 0, nullptr, nullptr, 0, nullptr);
    // layer-2 agg: fp32 only (xu/xm are outputs; proj reads fp32)
    agg16_dual_k<true, false><<<aggBlocks, 256, 0, stream>>>(
        um_rs, um_csr, hs_u, atts_u, attd_m, l2_um_b, XM, nullptr, Nm,
        mu_rs, mu_csr, hs_m, atts_m, attd_u, l2_mu_b, XU, nullptr, Nu);

    // ---- final projection: out = x @ Wo + bo (fp32 A) ----
    gemm_dual_k<4, 1, false, false><<<gbU + gbM, 256, 0, stream>>>(
        XU, nullptr, Wb_o, nullptr, nullptr, nullptr, OU, bo, Nu, gbU,
        XM, nullptr, Wb_o, nullptr, nullptr, nullptr, OM, bo, Nm, gbM,
        HC, O,
        nullptr, nullptr, 0, nullptr, nullptr, 0, nullptr);
}

// Round 14
// 236.715 us; speedup vs baseline: 4.2891x; 1.0353x over previous
//
#include <hip/hip_runtime.h>
#include <hip/hip_bf16.h>
#include <cstdint>

// ---------------------------------------------------------------------------
// HGAT: 2-layer hetero GAT (user<->movie), H=4 heads, C=32, HC=128.
// GEMMs on bf16 MFMA 16x16x32, fp32 accumulate; folded attention matrix V
// appended to packed weights so hs+att come out of one GEMM (MODE 0).
// CSR hist (1M returning device-scope atomics) is fused INSTRUCTION-LEVEL
// into layer-1 GEMM: every block's prologue processes ~1100 edges, then runs
// its GEMM tile -- all 939 blocks co-resident, so the TCC atomic backlog
// drains under MFMA compute (r13 showed block-level appending serializes:
// 85us = 25+54). Hist counters PADDED one per 64B line (stride 16): kills
// same-line serialization at the memory-side atomic unit (16 counters/line
// x ~25 hits/counter = ~400 serialized ops/line explained the 54us).
// Edge aggregation: CSR by dst, 16 lanes/node, ushort8 (16B) loads; src
// attention logits bf16 (0.8MB table, L2-resident).
// CSR fill: rank-from-hist (atomic-free), dst-windowed scatter (NWIN=2).
// REVERTED (net-negative): degree-sort perm (r9/10), src-windowed CSR (r11).
// Softmax max-subtraction skipped (logits bounded; shift-invariant; validated).
// ---------------------------------------------------------------------------

#define HC 128
#define HH 4
#define NWIN 2   // fill scatter windows (over dst)
#define CPAD 16  // hist counter stride (ints): one counter per 64B line

typedef __attribute__((ext_vector_type(8))) short bf16x8;
typedef __attribute__((ext_vector_type(4))) float f32x4;

__device__ __forceinline__ short f2bf(float f) {
    return __builtin_bit_cast(short, __float2bfloat16(f));
}
__device__ __forceinline__ float bf2f(ushort u) {
    return __builtin_bit_cast(float, ((unsigned)u) << 16);
}

// ---------------- fold attention: v[k, coff+h] = sum_c W[k,h*32+c]*a[h,c] ---
struct VT { const float* W[8]; const float* a[8]; float* v[8]; };
__global__ void make_v_all_k(VT t) {
    int gid = blockIdx.x * 256 + threadIdx.x;
    int task, base;
    if (gid < 1024) { task = gid >> 8; base = gid & 255; }
    else if (gid < 3072) { int g = gid - 1024; task = 4 + (g >> 9); base = g & 511; }
    else return;
    int k = base >> 2, h = base & 3;
    int coff = (task & 1) * 4;
    const float* wr = t.W[task] + (size_t)k * HC + h * 32;
    const float* ar = t.a[task] + h * 32;
    float s = 0.f;
    #pragma unroll
    for (int c = 0; c < 32; ++c) s = fmaf(wr[c], ar[c], s);
    t.v[task][k * 8 + coff + h] = s;
}

// ---------------- pack Wb[n][k] = bf16(W[k][n]); rows Nw..Nw+7 = V ----------
struct PT { const float* W[5]; const float* V[5]; ushort* Wb[5];
            int K[5]; int Nw[5]; int start[6]; };
__global__ void pack_all_k(PT t) {
    int gid = blockIdx.x * 256 + threadIdx.x;
    if (gid >= t.start[5]) return;
    int task = 0;
    while (gid >= t.start[task + 1]) ++task;
    int loc = gid - t.start[task];
    int K = t.K[task], Nw = t.Nw[task];
    int n = loc / K, k = loc % K;
    float v = 0.f;
    if (n < Nw) v = t.W[task][(size_t)k * Nw + n];
    else if (t.V[task] != nullptr && n < Nw + 8) v = t.V[task][k * 8 + (n - Nw)];
    t.Wb[task][loc] = (ushort)f2bf(v);
}

// ---------------- dual-segment bf16 MFMA GEMM (+ fused hist prologue) -------
// MODE 0: hs out (bf16 [M,128]) + atts bf16 [M,4] + attd fp32 [M,4].
// MODE 1: fp32 C[M,ldc] + bias. ABF: A dense bf16 (ushort), else fp32 (+idx).
// HIST: every block's prologue handles its slice of edges (returning atomic
// rank into padded counters); the atomic latency hides under the K-loop.
template <int NT, int MODE, bool ABF, bool HIST>
__global__ __launch_bounds__(256) void gemm_dual_k(
    const void* A0, const int* idx0, const ushort* Wb0, ushort* hsb0,
    ushort* atts0, float* attd0, float* C0, const float* bias0, int M0, int nb0,
    const void* A1, const int* idx1, const ushort* Wb1, ushort* hsb1,
    ushort* atts1, float* attd1, float* C1, const float* bias1, int M1, int nb1,
    int K, int ldc,
    const int* hd0, int* hc0, int Eh0,
    const int* hd1, int* hc1, int Eh1, int* hrank) {
    if (HIST) {
        int nbg = nb0 + nb1;
        int totE = Eh0 + Eh1;
        int epb = (totE + nbg - 1) / nbg;
        int e0 = (int)blockIdx.x * epb;
        int e1 = min(e0 + epb, totE);
        for (int e = e0 + (int)threadIdx.x; e < e1; e += 256) {
            int r;
            if (e < Eh0) r = atomicAdd(&hc0[(size_t)hd0[e] * CPAD], 1);
            else r = atomicAdd(&hc1[(size_t)hd1[e - Eh0] * CPAD], 1);
            hrank[e] = r;
        }
    }
    const void* A; const int* aidx; const ushort* Wb; ushort* hsb;
    ushort* atts; float* attd; float* C; const float* bias; int M, bid;
    if ((int)blockIdx.x < nb0) {
        A = A0; aidx = idx0; Wb = Wb0; hsb = hsb0; atts = atts0; attd = attd0;
        C = C0; bias = bias0; M = M0; bid = blockIdx.x;
    } else {
        A = A1; aidx = idx1; Wb = Wb1; hsb = hsb1; atts = atts1; attd = attd1;
        C = C1; bias = bias1; M = M1; bid = blockIdx.x - nb0;
    }
    int lane = threadIdx.x & 63;
    int wave = threadIdx.x >> 6;
    int m_base = bid * 128 + wave * 32;
    int lm = lane & 15;      // A row-in-tile / C col-in-tile
    int kg = lane >> 4;      // k-group (8 consecutive k)

    int r0 = m_base + lm, r1 = r0 + 16;
    int cr0 = r0 < M ? r0 : M - 1;
    int cr1 = r1 < M ? r1 : M - 1;
    int row0 = aidx ? aidx[cr0] : cr0;
    int row1 = aidx ? aidx[cr1] : cr1;
    const ushort* bp = Wb + (size_t)lm * K + kg * 8;

    f32x4 acc[2][NT] = {};
    for (int k0 = 0; k0 < K; k0 += 32) {
        bf16x8 a[2];
        if (ABF) {
            const ushort* a0p = (const ushort*)A + (size_t)row0 * K + kg * 8;
            const ushort* a1p = (const ushort*)A + (size_t)row1 * K + kg * 8;
            a[0] = *reinterpret_cast<const bf16x8*>(a0p + k0);
            a[1] = *reinterpret_cast<const bf16x8*>(a1p + k0);
        } else {
            const float* a0p = (const float*)A + (size_t)row0 * K + kg * 8;
            const float* a1p = (const float*)A + (size_t)row1 * K + kg * 8;
            float af[2][8];
            *reinterpret_cast<float4*>(&af[0][0]) = *reinterpret_cast<const float4*>(a0p + k0);
            *reinterpret_cast<float4*>(&af[0][4]) = *reinterpret_cast<const float4*>(a0p + k0 + 4);
            *reinterpret_cast<float4*>(&af[1][0]) = *reinterpret_cast<const float4*>(a1p + k0);
            *reinterpret_cast<float4*>(&af[1][4]) = *reinterpret_cast<const float4*>(a1p + k0 + 4);
            #pragma unroll
            for (int mi = 0; mi < 2; ++mi)
                #pragma unroll
                for (int j = 0; j < 8; ++j) a[mi][j] = f2bf(af[mi][j]);
        }
        #pragma unroll
        for (int nt = 0; nt < NT; ++nt) {
            bf16x8 b = *reinterpret_cast<const bf16x8*>(bp + (size_t)nt * 16 * K + k0);
            acc[0][nt] = __builtin_amdgcn_mfma_f32_16x16x32_bf16(a[0], b, acc[0][nt], 0, 0, 0);
            acc[1][nt] = __builtin_amdgcn_mfma_f32_16x16x32_bf16(a[1], b, acc[1][nt], 0, 0, 0);
        }
    }
    #pragma unroll
    for (int mi = 0; mi < 2; ++mi) {
        int rowb = m_base + mi * 16 + kg * 4;
        if (MODE == 0) {
            #pragma unroll
            for (int nt = 0; nt < NT - 1; ++nt) {
                int col = nt * 16 + lm;
                #pragma unroll
                for (int r = 0; r < 4; ++r) {
                    int row = rowb + r;
                    if (row < M) hsb[(size_t)row * HC + col] = (ushort)f2bf(acc[mi][nt][r]);
                }
            }
            // last tile: cols 0-3 = src logits (bf16), 4-7 = dst logits (fp32)
            #pragma unroll
            for (int r = 0; r < 4; ++r) {
                int row = rowb + r;
                if (row < M) {
                    float v = acc[mi][NT - 1][r];
                    if (lm < 4) atts[(size_t)row * 4 + lm] = (ushort)f2bf(v);
                    else if (lm < 8) attd[(size_t)row * 4 + (lm - 4)] = v;
                }
            }
        } else {
            #pragma unroll
            for (int nt = 0; nt < NT; ++nt) {
                int col = nt * 16 + lm;
                float bv = bias[col];
                #pragma unroll
                for (int r = 0; r < 4; ++r) {
                    int row = rowb + r;
                    if (row < M) C[(size_t)row * ldc + col] = acc[mi][nt][r] + bv;
                }
            }
        }
    }
}

// ---------------- CSR build helpers (padded counters) ------------------------
__device__ __forceinline__ void scan_block_body(
    const int* deg, int n, int len, int* out, int* partial, int b) {
    __shared__ int s[256];
    int i = b * 256 + threadIdx.x;
    int v = (i < n) ? deg[(size_t)i * CPAD] : 0;
    s[threadIdx.x] = v;
    __syncthreads();
    for (int off = 1; off < 256; off <<= 1) {
        int t = (threadIdx.x >= off) ? s[threadIdx.x - off] : 0;
        __syncthreads();
        s[threadIdx.x] += t;
        __syncthreads();
    }
    if (i < len) out[i] = s[threadIdx.x] - v;
    if (threadIdx.x == 255) partial[b] = s[255];
}

__global__ void scan_block_dual_k(const int* dM, int nM, int* rsM, int* pM, int nbM,
                                  const int* dU, int nU, int* rsU, int* pU) {
    if ((int)blockIdx.x < nbM)
        scan_block_body(dM, nM, nM + 1, rsM, pM, blockIdx.x);
    else
        scan_block_body(dU, nU, nU + 1, rsU, pU, blockIdx.x - nbM);
}

__global__ void scan_partial_dual_k(int* pM, int nbM, int* pU, int nbU) {
    __shared__ int s[512];
    int t = threadIdx.x;
    for (int seg = 0; seg < 2; ++seg) {
        int* p = seg ? pU : pM;
        int nb = seg ? nbU : nbM;
        int v = (t < nb) ? p[t] : 0;
        s[t] = v;
        __syncthreads();
        for (int off = 1; off < 512; off <<= 1) {
            int x = (t >= off) ? s[t - off] : 0;
            __syncthreads();
            s[t] += x;
            __syncthreads();
        }
        if (t < nb) p[t] = s[t] - v;
        __syncthreads();
    }
}

__global__ void add_off_dual_k(int* __restrict__ oM, const int* __restrict__ pM,
                               int lenM, int nbM,
                               int* __restrict__ oU, const int* __restrict__ pU,
                               int lenU) {
    int b = blockIdx.x;
    if (b < nbM) {
        int i = b * 256 + threadIdx.x;
        if (i < lenM) oM[i] += pM[b];
    } else {
        b -= nbM;
        int i = b * 256 + threadIdx.x;
        if (i < lenU) oU[i] += pU[b];
    }
}

// atomic-free, dst-windowed scatter: window w handles dst in [w*n/NWIN, ...).
__global__ void fill_dual_k(const int* __restrict__ s0, const int* __restrict__ d0,
                            const int* __restrict__ rs0, int* __restrict__ csr0,
                            int E0, int n0,
                            const int* __restrict__ s1, const int* __restrict__ d1,
                            const int* __restrict__ rs1, int* __restrict__ csr1,
                            int E1, int n1,
                            const int* __restrict__ rank) {
    int e = blockIdx.x * 256 + threadIdx.x;
    int w = blockIdx.y;
    if (e < E0) {
        int d = d0[e];
        int lo = (int)((long)w * n0 / NWIN), hi = (int)((long)(w + 1) * n0 / NWIN);
        if (d >= lo && d < hi) csr0[rs0[d] + rank[e]] = s0[e];
    } else if (e - E0 < E1) {
        int e1 = e - E0;
        int d = d1[e1];
        int lo = (int)((long)w * n1 / NWIN), hi = (int)((long)(w + 1) * n1 / NWIN);
        if (d >= lo && d < hi) csr1[rs1[d] + rank[e]] = s1[e1];
    }
}

// ---------------- per-dst aggregation: 16 lanes/node, ushort8 loads ---------
// Lane c in [0,16): channels 8c..8c+7 (16B load); head h = c>>2.
// src logits read from bf16 [N,4] table (0.8MB user-side -> L2-resident).
template <bool WF32, bool WBF>
__global__ __launch_bounds__(256) void agg16_dual_k(
    const int* __restrict__ rs0, const int* __restrict__ csr0,
    const ushort* __restrict__ hsb0, const ushort* __restrict__ atts0,
    const float* __restrict__ attd0, const float* __restrict__ bias0,
    float* __restrict__ out0, ushort* __restrict__ outb0, int n0,
    const int* __restrict__ rs1, const int* __restrict__ csr1,
    const ushort* __restrict__ hsb1, const ushort* __restrict__ atts1,
    const float* __restrict__ attd1, const float* __restrict__ bias1,
    float* __restrict__ out1, ushort* __restrict__ outb1, int n1) {
    int g = (int)((blockIdx.x * 256u + threadIdx.x) >> 4);   // 16 nodes/block
    const int* rs; const int* csr; const ushort* hsb; const ushort* atts;
    const float* attd; const float* bias; float* out; ushort* outb; int node;
    if (g < n0) {
        rs = rs0; csr = csr0; hsb = hsb0; atts = atts0; attd = attd0;
        bias = bias0; out = out0; outb = outb0; node = g;
    } else {
        node = g - n0;
        if (node >= n1) return;
        rs = rs1; csr = csr1; hsb = hsb1; atts = atts1; attd = attd1;
        bias = bias1; out = out1; outb = outb1;
    }
    int c = threadIdx.x & 15;    // channels 8c..8c+7
    int h = c >> 2;              // head (32 ch per head, 4 lanes per head)
    float ad = attd[node * 4 + h];
    int s0 = rs[node], s1 = rs[node + 1];
    float acc[8] = {};
    float wsum = 0.f;
    int i = s0;
    for (; i + 4 <= s1; i += 4) {            // 4 edge-rows in flight
        int sx[4];
        #pragma unroll
        for (int j = 0; j < 4; ++j) sx[j] = csr[i + j];
        bf16x8 hv[4]; float el[4];
        #pragma unroll
        for (int j = 0; j < 4; ++j) {
            hv[j] = *reinterpret_cast<const bf16x8*>(hsb + (size_t)sx[j] * HC + 8 * c);
            el[j] = bf2f(atts[(size_t)sx[j] * 4 + h]);
        }
        #pragma unroll
        for (int j = 0; j < 4; ++j) {
            float e = el[j] + ad;
            e = e > 0.f ? e : 0.2f * e;
            float w = __expf(e);
            wsum += w;
            #pragma unroll
            for (int k = 0; k < 8; ++k)
                acc[k] = fmaf(w, bf2f((ushort)hv[j][k]), acc[k]);
        }
    }
    for (; i < s1; ++i) {
        int src = csr[i];
        bf16x8 hv = *reinterpret_cast<const bf16x8*>(hsb + (size_t)src * HC + 8 * c);
        float e = bf2f(atts[(size_t)src * 4 + h]) + ad;
        e = e > 0.f ? e : 0.2f * e;
        float w = __expf(e);
        wsum += w;
        #pragma unroll
        for (int k = 0; k < 8; ++k)
            acc[k] = fmaf(w, bf2f((ushort)hv[k]), acc[k]);
    }
    float inv = 1.f / (wsum + 1e-16f);
    float v[8];
    #pragma unroll
    for (int k = 0; k < 8; ++k) {
        v[k] = fmaf(acc[k], inv, bias[8 * c + k]);
        v[k] = v[k] > 0.f ? v[k] : 0.01f * v[k];
    }
    if (WF32) {
        float4 o0 = make_float4(v[0], v[1], v[2], v[3]);
        float4 o1 = make_float4(v[4], v[5], v[6], v[7]);
        reinterpret_cast<float4*>(out + (size_t)node * HC + 8 * c)[0] = o0;
        reinterpret_cast<float4*>(out + (size_t)node * HC + 8 * c)[1] = o1;
    }
    if (WBF) {
        bf16x8 u;
        #pragma unroll
        for (int k = 0; k < 8; ++k) u[k] = f2bf(v[k]);
        *reinterpret_cast<bf16x8*>(outb + (size_t)node * HC + 8 * c) = u;
    }
}

// ---------------------------------------------------------------------------
extern "C" void kernel_launch(void* const* d_in, const int* in_sizes, int n_in,
                              void* d_out, int out_size, void* d_ws, size_t ws_size,
                              hipStream_t stream) {
    const int Nu = in_sizes[0];
    const int Nm = in_sizes[1];
    const int E1 = in_sizes[2];   // um edges
    const int E2 = in_sizes[4];   // mu edges
    const int D  = in_sizes[6] / Nu;   // 64
    const int O  = in_sizes[27];       // 64

    const int*   user_ids  = (const int*)d_in[0];
    const int*   movie_ids = (const int*)d_in[1];
    const int*   um_src    = (const int*)d_in[2];
    const int*   um_dst    = (const int*)d_in[3];
    const int*   mu_src    = (const int*)d_in[4];
    const int*   mu_dst    = (const int*)d_in[5];
    const float* user_emb  = (const float*)d_in[6];
    const float* movie_emb = (const float*)d_in[7];
    const float* l1_um_Wsrc = (const float*)d_in[8];
    const float* l1_um_Wdst = (const float*)d_in[9];
    const float* l1_um_asrc = (const float*)d_in[10];
    const float* l1_um_adst = (const float*)d_in[11];
    const float* l1_um_b    = (const float*)d_in[12];
    const float* l1_mu_Wsrc = (const float*)d_in[13];
    const float* l1_mu_Wdst = (const float*)d_in[14];
    const float* l1_mu_asrc = (const float*)d_in[15];
    const float* l1_mu_adst = (const float*)d_in[16];
    const float* l1_mu_b    = (const float*)d_in[17];
    const float* l2_um_W    = (const float*)d_in[18];
    const float* l2_um_asrc = (const float*)d_in[19];
    const float* l2_um_adst = (const float*)d_in[20];
    const float* l2_um_b    = (const float*)d_in[21];
    const float* l2_mu_W    = (const float*)d_in[22];
    const float* l2_mu_asrc = (const float*)d_in[23];
    const float* l2_mu_adst = (const float*)d_in[24];
    const float* l2_mu_b    = (const float*)d_in[25];
    const float* Wo         = (const float*)d_in[26];
    const float* bo         = (const float*)d_in[27];

    // ---- workspace carve ----
    char* p = (char*)d_ws;
    auto alloc = [&](size_t bytes) { void* r = p; p += (bytes + 255) & ~(size_t)255; return r; };
    ushort* hs_u = (ushort*)alloc((size_t)Nu * HC * 2);
    ushort* hs_m = (ushort*)alloc((size_t)Nm * HC * 2);
    ushort* XUb  = (ushort*)alloc((size_t)Nu * HC * 2);
    ushort* XMb  = (ushort*)alloc((size_t)Nm * HC * 2);
    ushort* atts_u = (ushort*)alloc((size_t)Nu * 4 * 2);   // bf16 src logits
    ushort* atts_m = (ushort*)alloc((size_t)Nm * 4 * 2);
    float* attd_u = (float*)alloc((size_t)Nu * 4 * 4);
    float* attd_m = (float*)alloc((size_t)Nm * 4 * 4);
    float* V_u1  = (float*)alloc((size_t)HC * 8 * 4);
    float* V_m1  = (float*)alloc((size_t)HC * 8 * 4);
    float* V_u2  = (float*)alloc((size_t)HC * 8 * 4);
    float* V_m2  = (float*)alloc((size_t)HC * 8 * 4);
    ushort* Wb_u1 = (ushort*)alloc((size_t)144 * D * 2);
    ushort* Wb_m1 = (ushort*)alloc((size_t)144 * D * 2);
    ushort* Wb_u2 = (ushort*)alloc((size_t)144 * HC * 2);
    ushort* Wb_m2 = (ushort*)alloc((size_t)144 * HC * 2);
    ushort* Wb_o  = (ushort*)alloc((size_t)64 * HC * 2);
    int* um_rs  = (int*)alloc((size_t)(Nm + 1) * 4);
    int* mu_rs  = (int*)alloc((size_t)(Nu + 1) * 4);
    int* cnts   = (int*)alloc((size_t)(Nm + Nu) * CPAD * 4);  // padded counters
    int* um_cnt = cnts;
    int* mu_cnt = cnts + (size_t)Nm * CPAD;
    int* um_csr = (int*)alloc((size_t)E1 * 4);
    int* mu_csr = (int*)alloc((size_t)E2 * 4);
    int* rank   = (int*)alloc((size_t)(E1 + E2) * 4);
    int* partM  = (int*)alloc(512 * 4);
    int* partU  = (int*)alloc(512 * 4);

    auto cdiv = [](int a, int b) { return (a + b - 1) / b; };

    // ---- fold attention + pack weights (x-independent) ----
    {
        VT vt;
        const float* Ws[8] = {l1_um_Wsrc, l1_mu_Wdst, l1_mu_Wsrc, l1_um_Wdst,
                              l2_um_W, l2_mu_W, l2_mu_W, l2_um_W};
        const float* as[8] = {l1_um_asrc, l1_mu_adst, l1_mu_asrc, l1_um_adst,
                              l2_um_asrc, l2_mu_adst, l2_mu_asrc, l2_um_adst};
        float* vs[8] = {V_u1, V_u1, V_m1, V_m1, V_u2, V_u2, V_m2, V_m2};
        for (int i = 0; i < 8; ++i) { vt.W[i] = Ws[i]; vt.a[i] = as[i]; vt.v[i] = vs[i]; }
        make_v_all_k<<<12, 256, 0, stream>>>(vt);

        PT pt;
        const float* pW[5] = {l1_um_Wsrc, l1_mu_Wsrc, l2_um_W, l2_mu_W, Wo};
        const float* pV[5] = {V_u1, V_m1, V_u2, V_m2, nullptr};
        ushort* pB[5] = {Wb_u1, Wb_m1, Wb_u2, Wb_m2, Wb_o};
        int pK[5] = {D, D, HC, HC, HC};
        int pN[5] = {HC, HC, HC, HC, 64};
        int cum = 0;
        for (int i = 0; i < 5; ++i) {
            pt.W[i] = pW[i]; pt.V[i] = pV[i]; pt.Wb[i] = pB[i];
            pt.K[i] = pK[i]; pt.Nw[i] = pN[i];
            pt.start[i] = cum;
            cum += (i < 4 ? 144 : 64) * pK[i];
        }
        pt.start[5] = cum;
        pack_all_k<<<cdiv(cum, 256), 256, 0, stream>>>(pt);
    }

    hipMemsetAsync(cnts, 0, (size_t)(Nm + Nu) * CPAD * 4, stream);

    // output slots: [out_user | out_movie | xu | xm]
    float* OU = (float*)d_out;
    float* OM = OU + (size_t)Nu * O;
    float* XU = OM + (size_t)Nm * O;
    float* XM = XU + (size_t)Nu * HC;

    int gbU = cdiv(Nu, 128), gbM = cdiv(Nm, 128);
    int aggBlocks = cdiv((Nm + Nu) * 16, 256);

    // ---- layer-1 GEMM (fp32 emb gathered, K=D) with fused hist prologue ----
    gemm_dual_k<9, 0, false, true><<<gbU + gbM, 256, 0, stream>>>(
        user_emb, user_ids, Wb_u1, hs_u, atts_u, attd_u, nullptr, nullptr, Nu, gbU,
        movie_emb, movie_ids, Wb_m1, hs_m, atts_m, attd_m, nullptr, nullptr, Nm, gbM,
        D, 0,
        um_dst, um_cnt, E1, mu_dst, mu_cnt, E2, rank);

    // ---- CSR scan + fill (needs hist; reused by both layers) ----
    int nbM = cdiv(Nm + 1, 256), nbU = cdiv(Nu + 1, 256);
    scan_block_dual_k<<<nbM + nbU, 256, 0, stream>>>(um_cnt, Nm, um_rs, partM, nbM,
                                                     mu_cnt, Nu, mu_rs, partU);
    scan_partial_dual_k<<<1, 512, 0, stream>>>(partM, nbM, partU, nbU);
    add_off_dual_k<<<nbM + nbU, 256, 0, stream>>>(um_rs, partM, Nm + 1, nbM,
                                                  mu_rs, partU, Nu + 1);
    {
        dim3 g(cdiv(E1 + E2, 256), NWIN);
        fill_dual_k<<<g, 256, 0, stream>>>(
            um_src, um_dst, um_rs, um_csr, E1, Nm,
            mu_src, mu_dst, mu_rs, mu_csr, E2, Nu, rank);
    }

    // layer-1 agg: bf16 activations only (fp32 slot would be overwritten by L2)
    agg16_dual_k<false, true><<<aggBlocks, 256, 0, stream>>>(
        um_rs, um_csr, hs_u, atts_u, attd_m, l1_um_b, nullptr, XMb, Nm,
        mu_rs, mu_csr, hs_m, atts_m, attd_u, l1_mu_b, nullptr, XUb, Nu);

    // ---- layer 2: A = bf16 activations, K = HC ----
    gemm_dual_k<9, 0, true, false><<<gbU + gbM, 256, 0, stream>>>(
        XUb, nullptr, Wb_u2, hs_u, atts_u, attd_u, nullptr, nullptr, Nu, gbU,
        XMb, nullptr, Wb_m2, hs_m, atts_m, attd_m, nullptr, nullptr, Nm, gbM,
        HC, 0,
        nullptr, nullptr, 0, nullptr, nullptr, 0, nullptr);
    // layer-2 agg: fp32 only (xu/xm are outputs; proj reads fp32)
    agg16_dual_k<true, false><<<aggBlocks, 256, 0, stream>>>(
        um_rs, um_csr, hs_u, atts_u, attd_m, l2_um_b, XM, nullptr, Nm,
        mu_rs, mu_csr, hs_m, atts_m, attd_u, l2_mu_b, XU, nullptr, Nu);

    // ---- final projection: out = x @ Wo + bo (fp32 A) ----
    gemm_dual_k<4, 1, false, false><<<gbU + gbM, 256, 0, stream>>>(
        XU, nullptr, Wb_o, nullptr, nullptr, nullptr, OU, bo, Nu, gbU,
        XM, nullptr, Wb_o, nullptr, nullptr, nullptr, OM, bo, Nm, gbM,
        HC, O,
        nullptr, nullptr, 0, nullptr, nullptr, 0, nullptr);
}

// Round 15
// 213.640 us; speedup vs baseline: 4.7524x; 1.1080x over previous
//
#include <hip/hip_runtime.h>
#include <hip/hip_bf16.h>
#include <cstdint>

// ---------------------------------------------------------------------------
// HGAT: 2-layer hetero GAT (user<->movie), H=4 heads, C=32, HC=128.
// GEMMs on bf16 MFMA 16x16x32, fp32 accumulate; folded attention matrix V
// appended to packed weights so hs+att come out of one GEMM (MODE 0).
// CSR BUILD WITH ZERO GLOBAL ATOMICS (r12-14 established that 1M returning
// device-scope atomics have a hard ~50us floor at the memory-side atomic
// unit, ~19G/s, immune to padding/fusion): LDS counting sort instead.
//   P1a: per-block 256-bin LDS hist over key-windows (key = dst | Nm+dst,
//        window = key>>9) -> (window,block) count matrix, plain writes.
//   scan: 125k-entry exclusive scan (3 kernels, reused machinery).
//   P1b: re-read edges, returning LDS atomic -> local rank -> scatter
//        (src,key) pairs into window-partitioned buffer.
//   P2:  one block per window (512 keys span, 2KB LDS): count -> LDS scan
//        -> write rs directly -> returning LDS atomic -> write csr.
// rs/csr are combined over both edge types (movie keys 0..Nm-1, user keys
// Nm..Nm+Nu-1) and reused by both layers.
// Edge aggregation: CSR by dst, 16 lanes/node, ushort8 (16B) loads; src
// attention logits bf16 (0.8MB table, L2-resident).
// REVERTED (net-negative): degree-sort perm (r9/10), src-windowed CSR (r11),
// hist-GEMM fusion (r13/14: atomic floor can't be hidden).
// Softmax max-subtraction skipped (logits bounded; shift-invariant; validated).
// ---------------------------------------------------------------------------

#define HC 128
#define HH 4
#define WPART 256       // key windows (key>>9, covers keys < 131072)
#define EPB 2048        // edges per partition block

typedef __attribute__((ext_vector_type(8))) short bf16x8;
typedef __attribute__((ext_vector_type(4))) float f32x4;

__device__ __forceinline__ short f2bf(float f) {
    return __builtin_bit_cast(short, __float2bfloat16(f));
}
__device__ __forceinline__ float bf2f(ushort u) {
    return __builtin_bit_cast(float, ((unsigned)u) << 16);
}

// ---------------- fold attention: v[k, coff+h] = sum_c W[k,h*32+c]*a[h,c] ---
struct VT { const float* W[8]; const float* a[8]; float* v[8]; };
__global__ void make_v_all_k(VT t) {
    int gid = blockIdx.x * 256 + threadIdx.x;
    int task, base;
    if (gid < 1024) { task = gid >> 8; base = gid & 255; }
    else if (gid < 3072) { int g = gid - 1024; task = 4 + (g >> 9); base = g & 511; }
    else return;
    int k = base >> 2, h = base & 3;
    int coff = (task & 1) * 4;
    const float* wr = t.W[task] + (size_t)k * HC + h * 32;
    const float* ar = t.a[task] + h * 32;
    float s = 0.f;
    #pragma unroll
    for (int c = 0; c < 32; ++c) s = fmaf(wr[c], ar[c], s);
    t.v[task][k * 8 + coff + h] = s;
}

// ---------------- pack Wb[n][k] = bf16(W[k][n]); rows Nw..Nw+7 = V ----------
struct PT { const float* W[5]; const float* V[5]; ushort* Wb[5];
            int K[5]; int Nw[5]; int start[6]; };
__global__ void pack_all_k(PT t) {
    int gid = blockIdx.x * 256 + threadIdx.x;
    if (gid >= t.start[5]) return;
    int task = 0;
    while (gid >= t.start[task + 1]) ++task;
    int loc = gid - t.start[task];
    int K = t.K[task], Nw = t.Nw[task];
    int n = loc / K, k = loc % K;
    float v = 0.f;
    if (n < Nw) v = t.W[task][(size_t)k * Nw + n];
    else if (t.V[task] != nullptr && n < Nw + 8) v = t.V[task][k * 8 + (n - Nw)];
    t.Wb[task][loc] = (ushort)f2bf(v);
}

// ---------------- dual-segment bf16 MFMA GEMM -------------------------------
// MODE 0: hs out (bf16 [M,128]) + atts bf16 [M,4] + attd fp32 [M,4].
// MODE 1: fp32 C[M,ldc] + bias. ABF: A dense bf16 (ushort), else fp32 (+idx).
template <int NT, int MODE, bool ABF>
__global__ __launch_bounds__(256) void gemm_dual_k(
    const void* A0, const int* idx0, const ushort* Wb0, ushort* hsb0,
    ushort* atts0, float* attd0, float* C0, const float* bias0, int M0, int nb0,
    const void* A1, const int* idx1, const ushort* Wb1, ushort* hsb1,
    ushort* atts1, float* attd1, float* C1, const float* bias1, int M1,
    int K, int ldc) {
    const void* A; const int* aidx; const ushort* Wb; ushort* hsb;
    ushort* atts; float* attd; float* C; const float* bias; int M, bid;
    if ((int)blockIdx.x < nb0) {
        A = A0; aidx = idx0; Wb = Wb0; hsb = hsb0; atts = atts0; attd = attd0;
        C = C0; bias = bias0; M = M0; bid = blockIdx.x;
    } else {
        A = A1; aidx = idx1; Wb = Wb1; hsb = hsb1; atts = atts1; attd = attd1;
        C = C1; bias = bias1; M = M1; bid = blockIdx.x - nb0;
    }
    int lane = threadIdx.x & 63;
    int wave = threadIdx.x >> 6;
    int m_base = bid * 128 + wave * 32;
    int lm = lane & 15;      // A row-in-tile / C col-in-tile
    int kg = lane >> 4;      // k-group (8 consecutive k)

    int r0 = m_base + lm, r1 = r0 + 16;
    int cr0 = r0 < M ? r0 : M - 1;
    int cr1 = r1 < M ? r1 : M - 1;
    int row0 = aidx ? aidx[cr0] : cr0;
    int row1 = aidx ? aidx[cr1] : cr1;
    const ushort* bp = Wb + (size_t)lm * K + kg * 8;

    f32x4 acc[2][NT] = {};
    for (int k0 = 0; k0 < K; k0 += 32) {
        bf16x8 a[2];
        if (ABF) {
            const ushort* a0p = (const ushort*)A + (size_t)row0 * K + kg * 8;
            const ushort* a1p = (const ushort*)A + (size_t)row1 * K + kg * 8;
            a[0] = *reinterpret_cast<const bf16x8*>(a0p + k0);
            a[1] = *reinterpret_cast<const bf16x8*>(a1p + k0);
        } else {
            const float* a0p = (const float*)A + (size_t)row0 * K + kg * 8;
            const float* a1p = (const float*)A + (size_t)row1 * K + kg * 8;
            float af[2][8];
            *reinterpret_cast<float4*>(&af[0][0]) = *reinterpret_cast<const float4*>(a0p + k0);
            *reinterpret_cast<float4*>(&af[0][4]) = *reinterpret_cast<const float4*>(a0p + k0 + 4);
            *reinterpret_cast<float4*>(&af[1][0]) = *reinterpret_cast<const float4*>(a1p + k0);
            *reinterpret_cast<float4*>(&af[1][4]) = *reinterpret_cast<const float4*>(a1p + k0 + 4);
            #pragma unroll
            for (int mi = 0; mi < 2; ++mi)
                #pragma unroll
                for (int j = 0; j < 8; ++j) a[mi][j] = f2bf(af[mi][j]);
        }
        #pragma unroll
        for (int nt = 0; nt < NT; ++nt) {
            bf16x8 b = *reinterpret_cast<const bf16x8*>(bp + (size_t)nt * 16 * K + k0);
            acc[0][nt] = __builtin_amdgcn_mfma_f32_16x16x32_bf16(a[0], b, acc[0][nt], 0, 0, 0);
            acc[1][nt] = __builtin_amdgcn_mfma_f32_16x16x32_bf16(a[1], b, acc[1][nt], 0, 0, 0);
        }
    }
    #pragma unroll
    for (int mi = 0; mi < 2; ++mi) {
        int rowb = m_base + mi * 16 + kg * 4;
        if (MODE == 0) {
            #pragma unroll
            for (int nt = 0; nt < NT - 1; ++nt) {
                int col = nt * 16 + lm;
                #pragma unroll
                for (int r = 0; r < 4; ++r) {
                    int row = rowb + r;
                    if (row < M) hsb[(size_t)row * HC + col] = (ushort)f2bf(acc[mi][nt][r]);
                }
            }
            // last tile: cols 0-3 = src logits (bf16), 4-7 = dst logits (fp32)
            #pragma unroll
            for (int r = 0; r < 4; ++r) {
                int row = rowb + r;
                if (row < M) {
                    float v = acc[mi][NT - 1][r];
                    if (lm < 4) atts[(size_t)row * 4 + lm] = (ushort)f2bf(v);
                    else if (lm < 8) attd[(size_t)row * 4 + (lm - 4)] = v;
                }
            }
        } else {
            #pragma unroll
            for (int nt = 0; nt < NT; ++nt) {
                int col = nt * 16 + lm;
                float bv = bias[col];
                #pragma unroll
                for (int r = 0; r < 4; ++r) {
                    int row = rowb + r;
                    if (row < M) C[(size_t)row * ldc + col] = acc[mi][nt][r] + bv;
                }
            }
        }
    }
}

// ---------------- P1a: per-block window histogram (LDS, no global atomics) --
__global__ __launch_bounds__(256) void part_count_k(
    const int* __restrict__ d0, int E0,
    const int* __restrict__ d1, int E1, int Nm,
    int* __restrict__ cntmat, int NB1) {
    __shared__ int lh[WPART];
    int t = threadIdx.x;
    lh[t] = 0;
    __syncthreads();
    int base = blockIdx.x * EPB + t;
    #pragma unroll
    for (int j = 0; j < EPB / 256; ++j) {
        int e = base + j * 256;
        int key = -1;
        if (e < E0) key = d0[e];
        else if (e - E0 < E1) key = Nm + d1[e - E0];
        if (key >= 0) atomicAdd(&lh[key >> 9], 1);
    }
    __syncthreads();
    cntmat[(size_t)t * NB1 + blockIdx.x] = lh[t];
}

// ---------------- P1b: scatter (src,key) into window partitions -------------
__global__ __launch_bounds__(256) void part_scatter_k(
    const int* __restrict__ s0, const int* __restrict__ d0, int E0,
    const int* __restrict__ s1, const int* __restrict__ d1, int E1, int Nm,
    const int* __restrict__ scanned, int NB1, int2* __restrict__ buf) {
    __shared__ int lb[WPART];
    __shared__ int lc[WPART];
    int t = threadIdx.x;
    lb[t] = scanned[(size_t)t * NB1 + blockIdx.x];
    lc[t] = 0;
    __syncthreads();
    int base = blockIdx.x * EPB + t;
    #pragma unroll
    for (int j = 0; j < EPB / 256; ++j) {
        int e = base + j * 256;
        int key = -1, src = 0;
        if (e < E0) { key = d0[e]; src = s0[e]; }
        else if (e - E0 < E1) { key = Nm + d1[e - E0]; src = s1[e - E0]; }
        if (key >= 0) {
            int w = key >> 9;
            int r = atomicAdd(&lc[w], 1);
            buf[lb[w] + r] = make_int2(src, key);
        }
    }
}

// ---------------- P2: per-window counting sort -> rs + csr ------------------
__global__ __launch_bounds__(512) void csort_k(
    const int2* __restrict__ buf, const int* __restrict__ scanned, int NB1,
    int E, int NK, int* __restrict__ rs, int* __restrict__ csr) {
    __shared__ int c1[512];
    __shared__ int ls[512];
    int b = blockIdx.x;
    int t = threadIdx.x;
    int lo = scanned[(size_t)b * NB1];
    int hi = (b + 1 < WPART) ? scanned[(size_t)(b + 1) * NB1] : E;
    int keylo = b << 9;
    c1[t] = 0;
    __syncthreads();
    for (int i = lo + t; i < hi; i += 512)
        atomicAdd(&c1[buf[i].y - keylo], 1);
    __syncthreads();
    // exclusive scan of c1 -> ls
    int v = c1[t];
    ls[t] = v;
    __syncthreads();
    for (int off = 1; off < 512; off <<= 1) {
        int x = (t >= off) ? ls[t - off] : 0;
        __syncthreads();
        ls[t] += x;
        __syncthreads();
    }
    ls[t] -= v;            // exclusive
    int gk = keylo + t;
    if (gk <= NK) rs[gk] = lo + ls[t];
    c1[t] = 0;             // reuse as slot counters
    __syncthreads();
    for (int i = lo + t; i < hi; i += 512) {
        int2 p = buf[i];
        int k = p.y - keylo;
        int r = atomicAdd(&c1[k], 1);
        csr[lo + ls[k] + r] = p.x;
    }
}

// ---------------- scan helpers (exclusive, 3-kernel) -------------------------
__global__ void scan_block_k(const int* __restrict__ deg, int n,
                             int* __restrict__ out, int* __restrict__ partial) {
    __shared__ int s[256];
    int i = blockIdx.x * 256 + threadIdx.x;
    int v = (i < n) ? deg[i] : 0;
    s[threadIdx.x] = v;
    __syncthreads();
    for (int off = 1; off < 256; off <<= 1) {
        int x = (threadIdx.x >= off) ? s[threadIdx.x - off] : 0;
        __syncthreads();
        s[threadIdx.x] += x;
        __syncthreads();
    }
    if (i < n) out[i] = s[threadIdx.x] - v;
    if (threadIdx.x == 255) partial[blockIdx.x] = s[255];
}

__global__ void scan_partial_k(int* __restrict__ partial, int nb) {
    __shared__ int s[512];
    int t = threadIdx.x;
    int v = (t < nb) ? partial[t] : 0;
    s[t] = v;
    __syncthreads();
    for (int off = 1; off < 512; off <<= 1) {
        int x = (t >= off) ? s[t - off] : 0;
        __syncthreads();
        s[t] += x;
        __syncthreads();
    }
    if (t < nb) partial[t] = s[t] - v;
}

__global__ void add_off_k(int* __restrict__ out, const int* __restrict__ partial, int n) {
    int i = blockIdx.x * 256 + threadIdx.x;
    if (i < n) out[i] += partial[blockIdx.x];
}

// ---------------- per-dst aggregation: 16 lanes/node, ushort8 loads ---------
// Lane c in [0,16): channels 8c..8c+7 (16B load); head h = c>>2.
template <bool WF32, bool WBF>
__global__ __launch_bounds__(256) void agg16_dual_k(
    const int* __restrict__ rs0, const int* __restrict__ csr0,
    const ushort* __restrict__ hsb0, const ushort* __restrict__ atts0,
    const float* __restrict__ attd0, const float* __restrict__ bias0,
    float* __restrict__ out0, ushort* __restrict__ outb0, int n0,
    const int* __restrict__ rs1, const int* __restrict__ csr1,
    const ushort* __restrict__ hsb1, const ushort* __restrict__ atts1,
    const float* __restrict__ attd1, const float* __restrict__ bias1,
    float* __restrict__ out1, ushort* __restrict__ outb1, int n1) {
    int g = (int)((blockIdx.x * 256u + threadIdx.x) >> 4);   // 16 nodes/block
    const int* rs; const int* csr; const ushort* hsb; const ushort* atts;
    const float* attd; const float* bias; float* out; ushort* outb; int node;
    if (g < n0) {
        rs = rs0; csr = csr0; hsb = hsb0; atts = atts0; attd = attd0;
        bias = bias0; out = out0; outb = outb0; node = g;
    } else {
        node = g - n0;
        if (node >= n1) return;
        rs = rs1; csr = csr1; hsb = hsb1; atts = atts1; attd = attd1;
        bias = bias1; out = out1; outb = outb1;
    }
    int c = threadIdx.x & 15;    // channels 8c..8c+7
    int h = c >> 2;              // head (32 ch per head, 4 lanes per head)
    float ad = attd[node * 4 + h];
    int s0 = rs[node], s1 = rs[node + 1];
    float acc[8] = {};
    float wsum = 0.f;
    int i = s0;
    for (; i + 4 <= s1; i += 4) {            // 4 edge-rows in flight
        int sx[4];
        #pragma unroll
        for (int j = 0; j < 4; ++j) sx[j] = csr[i + j];
        bf16x8 hv[4]; float el[4];
        #pragma unroll
        for (int j = 0; j < 4; ++j) {
            hv[j] = *reinterpret_cast<const bf16x8*>(hsb + (size_t)sx[j] * HC + 8 * c);
            el[j] = bf2f(atts[(size_t)sx[j] * 4 + h]);
        }
        #pragma unroll
        for (int j = 0; j < 4; ++j) {
            float e = el[j] + ad;
            e = e > 0.f ? e : 0.2f * e;
            float w = __expf(e);
            wsum += w;
            #pragma unroll
            for (int k = 0; k < 8; ++k)
                acc[k] = fmaf(w, bf2f((ushort)hv[j][k]), acc[k]);
        }
    }
    for (; i < s1; ++i) {
        int src = csr[i];
        bf16x8 hv = *reinterpret_cast<const bf16x8*>(hsb + (size_t)src * HC + 8 * c);
        float e = bf2f(atts[(size_t)src * 4 + h]) + ad;
        e = e > 0.f ? e : 0.2f * e;
        float w = __expf(e);
        wsum += w;
        #pragma unroll
        for (int k = 0; k < 8; ++k)
            acc[k] = fmaf(w, bf2f((ushort)hv[k]), acc[k]);
    }
    float inv = 1.f / (wsum + 1e-16f);
    float v[8];
    #pragma unroll
    for (int k = 0; k < 8; ++k) {
        v[k] = fmaf(acc[k], inv, bias[8 * c + k]);
        v[k] = v[k] > 0.f ? v[k] : 0.01f * v[k];
    }
    if (WF32) {
        float4 o0 = make_float4(v[0], v[1], v[2], v[3]);
        float4 o1 = make_float4(v[4], v[5], v[6], v[7]);
        reinterpret_cast<float4*>(out + (size_t)node * HC + 8 * c)[0] = o0;
        reinterpret_cast<float4*>(out + (size_t)node * HC + 8 * c)[1] = o1;
    }
    if (WBF) {
        bf16x8 u;
        #pragma unroll
        for (int k = 0; k < 8; ++k) u[k] = f2bf(v[k]);
        *reinterpret_cast<bf16x8*>(outb + (size_t)node * HC + 8 * c) = u;
    }
}

// ---------------------------------------------------------------------------
extern "C" void kernel_launch(void* const* d_in, const int* in_sizes, int n_in,
                              void* d_out, int out_size, void* d_ws, size_t ws_size,
                              hipStream_t stream) {
    const int Nu = in_sizes[0];
    const int Nm = in_sizes[1];
    const int E1 = in_sizes[2];   // um edges
    const int E2 = in_sizes[4];   // mu edges
    const int D  = in_sizes[6] / Nu;   // 64
    const int O  = in_sizes[27];       // 64
    const int E  = E1 + E2;
    const int NK = Nm + Nu;       // combined key range

    const int*   user_ids  = (const int*)d_in[0];
    const int*   movie_ids = (const int*)d_in[1];
    const int*   um_src    = (const int*)d_in[2];
    const int*   um_dst    = (const int*)d_in[3];
    const int*   mu_src    = (const int*)d_in[4];
    const int*   mu_dst    = (const int*)d_in[5];
    const float* user_emb  = (const float*)d_in[6];
    const float* movie_emb = (const float*)d_in[7];
    const float* l1_um_Wsrc = (const float*)d_in[8];
    const float* l1_um_Wdst = (const float*)d_in[9];
    const float* l1_um_asrc = (const float*)d_in[10];
    const float* l1_um_adst = (const float*)d_in[11];
    const float* l1_um_b    = (const float*)d_in[12];
    const float* l1_mu_Wsrc = (const float*)d_in[13];
    const float* l1_mu_Wdst = (const float*)d_in[14];
    const float* l1_mu_asrc = (const float*)d_in[15];
    const float* l1_mu_adst = (const float*)d_in[16];
    const float* l1_mu_b    = (const float*)d_in[17];
    const float* l2_um_W    = (const float*)d_in[18];
    const float* l2_um_asrc = (const float*)d_in[19];
    const float* l2_um_adst = (const float*)d_in[20];
    const float* l2_um_b    = (const float*)d_in[21];
    const float* l2_mu_W    = (const float*)d_in[22];
    const float* l2_mu_asrc = (const float*)d_in[23];
    const float* l2_mu_adst = (const float*)d_in[24];
    const float* l2_mu_b    = (const float*)d_in[25];
    const float* Wo         = (const float*)d_in[26];
    const float* bo         = (const float*)d_in[27];

    auto cdiv = [](int a, int b) { return (a + b - 1) / b; };
    const int NB1 = cdiv(E, EPB);            // partition blocks
    const int CM  = WPART * NB1;             // count matrix size

    // ---- workspace carve ----
    char* p = (char*)d_ws;
    auto alloc = [&](size_t bytes) { void* r = p; p += (bytes + 255) & ~(size_t)255; return r; };
    ushort* hs_u = (ushort*)alloc((size_t)Nu * HC * 2);
    ushort* hs_m = (ushort*)alloc((size_t)Nm * HC * 2);
    ushort* XUb  = (ushort*)alloc((size_t)Nu * HC * 2);
    ushort* XMb  = (ushort*)alloc((size_t)Nm * HC * 2);
    ushort* atts_u = (ushort*)alloc((size_t)Nu * 4 * 2);   // bf16 src logits
    ushort* atts_m = (ushort*)alloc((size_t)Nm * 4 * 2);
    float* attd_u = (float*)alloc((size_t)Nu * 4 * 4);
    float* attd_m = (float*)alloc((size_t)Nm * 4 * 4);
    float* V_u1  = (float*)alloc((size_t)HC * 8 * 4);
    float* V_m1  = (float*)alloc((size_t)HC * 8 * 4);
    float* V_u2  = (float*)alloc((size_t)HC * 8 * 4);
    float* V_m2  = (float*)alloc((size_t)HC * 8 * 4);
    ushort* Wb_u1 = (ushort*)alloc((size_t)144 * D * 2);
    ushort* Wb_m1 = (ushort*)alloc((size_t)144 * D * 2);
    ushort* Wb_u2 = (ushort*)alloc((size_t)144 * HC * 2);
    ushort* Wb_m2 = (ushort*)alloc((size_t)144 * HC * 2);
    ushort* Wb_o  = (ushort*)alloc((size_t)64 * HC * 2);
    int* rs      = (int*)alloc((size_t)(NK + 2) * 4);      // combined row starts
    int* cntmat  = (int*)alloc((size_t)(CM + 256) * 4);
    int* scanned = (int*)alloc((size_t)(CM + 256) * 4);
    int2* buf    = (int2*)alloc((size_t)E * 8);            // (src,key) pairs
    int* csr     = (int*)alloc((size_t)E * 4);             // combined csr
    int* part    = (int*)alloc(1024 * 4);

    // ---- fold attention + pack weights (x-independent) ----
    {
        VT vt;
        const float* Ws[8] = {l1_um_Wsrc, l1_mu_Wdst, l1_mu_Wsrc, l1_um_Wdst,
                              l2_um_W, l2_mu_W, l2_mu_W, l2_um_W};
        const float* as[8] = {l1_um_asrc, l1_mu_adst, l1_mu_asrc, l1_um_adst,
                              l2_um_asrc, l2_mu_adst, l2_mu_asrc, l2_um_adst};
        float* vs[8] = {V_u1, V_u1, V_m1, V_m1, V_u2, V_u2, V_m2, V_m2};
        for (int i = 0; i < 8; ++i) { vt.W[i] = Ws[i]; vt.a[i] = as[i]; vt.v[i] = vs[i]; }
        make_v_all_k<<<12, 256, 0, stream>>>(vt);

        PT pt;
        const float* pW[5] = {l1_um_Wsrc, l1_mu_Wsrc, l2_um_W, l2_mu_W, Wo};
        const float* pV[5] = {V_u1, V_m1, V_u2, V_m2, nullptr};
        ushort* pB[5] = {Wb_u1, Wb_m1, Wb_u2, Wb_m2, Wb_o};
        int pK[5] = {D, D, HC, HC, HC};
        int pN[5] = {HC, HC, HC, HC, 64};
        int cum = 0;
        for (int i = 0; i < 5; ++i) {
            pt.W[i] = pW[i]; pt.V[i] = pV[i]; pt.Wb[i] = pB[i];
            pt.K[i] = pK[i]; pt.Nw[i] = pN[i];
            pt.start[i] = cum;
            cum += (i < 4 ? 144 : 64) * pK[i];
        }
        pt.start[5] = cum;
        pack_all_k<<<cdiv(cum, 256), 256, 0, stream>>>(pt);
    }

    // ---- CSR build via LDS counting sort (zero global atomics) ----
    part_count_k<<<NB1, 256, 0, stream>>>(um_dst, E1, mu_dst, E2, Nm, cntmat, NB1);
    {
        int nb = cdiv(CM, 256);
        scan_block_k<<<nb, 256, 0, stream>>>(cntmat, CM, scanned, part);
        scan_partial_k<<<1, 512, 0, stream>>>(part, nb);
        add_off_k<<<nb, 256, 0, stream>>>(scanned, part, CM);
    }
    part_scatter_k<<<NB1, 256, 0, stream>>>(um_src, um_dst, E1, mu_src, mu_dst, E2,
                                            Nm, scanned, NB1, buf);
    csort_k<<<WPART, 512, 0, stream>>>(buf, scanned, NB1, E, NK, rs, csr);

    // output slots: [out_user | out_movie | xu | xm]
    float* OU = (float*)d_out;
    float* OM = OU + (size_t)Nu * O;
    float* XU = OM + (size_t)Nm * O;
    float* XM = XU + (size_t)Nu * HC;

    int gbU = cdiv(Nu, 128), gbM = cdiv(Nm, 128);
    int aggBlocks = cdiv((Nm + Nu) * 16, 256);

    // ---- layer 1: A = fp32 embeddings (gathered), K = D ----
    gemm_dual_k<9, 0, false><<<gbU + gbM, 256, 0, stream>>>(
        user_emb, user_ids, Wb_u1, hs_u, atts_u, attd_u, nullptr, nullptr, Nu, gbU,
        movie_emb, movie_ids, Wb_m1, hs_m, atts_m, attd_m, nullptr, nullptr, Nm,
        D, 0);
    // layer-1 agg: bf16 activations only (fp32 slot would be overwritten by L2)
    agg16_dual_k<false, true><<<aggBlocks, 256, 0, stream>>>(
        rs, csr, hs_u, atts_u, attd_m, l1_um_b, nullptr, XMb, Nm,
        rs + Nm, csr, hs_m, atts_m, attd_u, l1_mu_b, nullptr, XUb, Nu);

    // ---- layer 2: A = bf16 activations, K = HC ----
    gemm_dual_k<9, 0, true><<<gbU + gbM, 256, 0, stream>>>(
        XUb, nullptr, Wb_u2, hs_u, atts_u, attd_u, nullptr, nullptr, Nu, gbU,
        XMb, nullptr, Wb_m2, hs_m, atts_m, attd_m, nullptr, nullptr, Nm,
        HC, 0);
    // layer-2 agg: fp32 only (xu/xm are outputs; proj reads fp32)
    agg16_dual_k<true, false><<<aggBlocks, 256, 0, stream>>>(
        rs, csr, hs_u, atts_u, attd_m, l2_um_b, XM, nullptr, Nm,
        rs + Nm, csr, hs_m, atts_m, attd_u, l2_mu_b, XU, nullptr, Nu);

    // ---- final projection: out = x @ Wo + bo (fp32 A) ----
    gemm_dual_k<4, 1, false><<<gbU + gbM, 256, 0, stream>>>(
        XU, nullptr, Wb_o, nullptr, nullptr, nullptr, OU, bo, Nu, gbU,
        XM, nullptr, Wb_o, nullptr, nullptr, nullptr, OM, bo, Nm,
        HC, O);
}

// Round 16
// 209.020 us; speedup vs baseline: 4.8574x; 1.0221x over previous
//
#include <hip/hip_runtime.h>
#include <hip/hip_bf16.h>
#include <cstdint>

// ---------------------------------------------------------------------------
// HGAT: 2-layer hetero GAT (user<->movie), H=4 heads, C=32, HC=128.
// GEMMs on bf16 MFMA 16x16x32, fp32 accumulate; folded attention matrix V
// appended to packed weights so hs+att come out of one GEMM (MODE 0).
// CSR build: zero-global-atomic LDS counting sort (r15; the 1M returning
// device-scope atomics of hist had a hard ~50us floor at the memory-side
// atomic unit, r12-14). Combined key space: movie dst = 0..Nm-1, user dst =
// Nm..Nm+Nu-1; rs/csr shared by both layers.
// Edge aggregation: CSR by dst, 16 lanes/node, ushort8 (16B) loads; src
// attention logits bf16 (0.8MB table, L2-resident). agg1 FETCH matches the
// analytic random-gather L2 model (~105MB) -> near random-access BW bound.
// PROJ FUSION (this round): the final projection re-read XU/XM (61MB) that
// agg2 had just computed. agg2 now deposits each node row into a padded LDS
// tile ([16][136] bf16, 2-way bank alias = free), barriers once, and its 4
// waves MFMA the 16x64x128 proj against L2-hot Wb_o, writing OU/OM directly.
// REVERTED (net-negative): degree-sort perm (r9/10), src-windowed CSR (r11),
// hist-GEMM fusion (r13/14).
// Softmax max-subtraction skipped (logits bounded; shift-invariant; validated).
// ---------------------------------------------------------------------------

#define HC 128
#define HH 4
#define WPART 256       // key windows (key>>9, covers keys < 131072)
#define EPB 2048        // edges per partition block

typedef __attribute__((ext_vector_type(8))) short bf16x8;
typedef __attribute__((ext_vector_type(4))) float f32x4;

__device__ __forceinline__ short f2bf(float f) {
    return __builtin_bit_cast(short, __float2bfloat16(f));
}
__device__ __forceinline__ float bf2f(ushort u) {
    return __builtin_bit_cast(float, ((unsigned)u) << 16);
}

// ---------------- fold attention: v[k, coff+h] = sum_c W[k,h*32+c]*a[h,c] ---
struct VT { const float* W[8]; const float* a[8]; float* v[8]; };
__global__ void make_v_all_k(VT t) {
    int gid = blockIdx.x * 256 + threadIdx.x;
    int task, base;
    if (gid < 1024) { task = gid >> 8; base = gid & 255; }
    else if (gid < 3072) { int g = gid - 1024; task = 4 + (g >> 9); base = g & 511; }
    else return;
    int k = base >> 2, h = base & 3;
    int coff = (task & 1) * 4;
    const float* wr = t.W[task] + (size_t)k * HC + h * 32;
    const float* ar = t.a[task] + h * 32;
    float s = 0.f;
    #pragma unroll
    for (int c = 0; c < 32; ++c) s = fmaf(wr[c], ar[c], s);
    t.v[task][k * 8 + coff + h] = s;
}

// ---------------- pack Wb[n][k] = bf16(W[k][n]); rows Nw..Nw+7 = V ----------
struct PT { const float* W[5]; const float* V[5]; ushort* Wb[5];
            int K[5]; int Nw[5]; int start[6]; };
__global__ void pack_all_k(PT t) {
    int gid = blockIdx.x * 256 + threadIdx.x;
    if (gid >= t.start[5]) return;
    int task = 0;
    while (gid >= t.start[task + 1]) ++task;
    int loc = gid - t.start[task];
    int K = t.K[task], Nw = t.Nw[task];
    int n = loc / K, k = loc % K;
    float v = 0.f;
    if (n < Nw) v = t.W[task][(size_t)k * Nw + n];
    else if (t.V[task] != nullptr && n < Nw + 8) v = t.V[task][k * 8 + (n - Nw)];
    t.Wb[task][loc] = (ushort)f2bf(v);
}

// ---------------- dual-segment bf16 MFMA GEMM -------------------------------
// MODE 0: hs out (bf16 [M,128]) + atts bf16 [M,4] + attd fp32 [M,4].
// MODE 1: fp32 C[M,ldc] + bias. ABF: A dense bf16 (ushort), else fp32 (+idx).
template <int NT, int MODE, bool ABF>
__global__ __launch_bounds__(256) void gemm_dual_k(
    const void* A0, const int* idx0, const ushort* Wb0, ushort* hsb0,
    ushort* atts0, float* attd0, float* C0, const float* bias0, int M0, int nb0,
    const void* A1, const int* idx1, const ushort* Wb1, ushort* hsb1,
    ushort* atts1, float* attd1, float* C1, const float* bias1, int M1,
    int K, int ldc) {
    const void* A; const int* aidx; const ushort* Wb; ushort* hsb;
    ushort* atts; float* attd; float* C; const float* bias; int M, bid;
    if ((int)blockIdx.x < nb0) {
        A = A0; aidx = idx0; Wb = Wb0; hsb = hsb0; atts = atts0; attd = attd0;
        C = C0; bias = bias0; M = M0; bid = blockIdx.x;
    } else {
        A = A1; aidx = idx1; Wb = Wb1; hsb = hsb1; atts = atts1; attd = attd1;
        C = C1; bias = bias1; M = M1; bid = blockIdx.x - nb0;
    }
    int lane = threadIdx.x & 63;
    int wave = threadIdx.x >> 6;
    int m_base = bid * 128 + wave * 32;
    int lm = lane & 15;      // A row-in-tile / C col-in-tile
    int kg = lane >> 4;      // k-group (8 consecutive k)

    int r0 = m_base + lm, r1 = r0 + 16;
    int cr0 = r0 < M ? r0 : M - 1;
    int cr1 = r1 < M ? r1 : M - 1;
    int row0 = aidx ? aidx[cr0] : cr0;
    int row1 = aidx ? aidx[cr1] : cr1;
    const ushort* bp = Wb + (size_t)lm * K + kg * 8;

    f32x4 acc[2][NT] = {};
    for (int k0 = 0; k0 < K; k0 += 32) {
        bf16x8 a[2];
        if (ABF) {
            const ushort* a0p = (const ushort*)A + (size_t)row0 * K + kg * 8;
            const ushort* a1p = (const ushort*)A + (size_t)row1 * K + kg * 8;
            a[0] = *reinterpret_cast<const bf16x8*>(a0p + k0);
            a[1] = *reinterpret_cast<const bf16x8*>(a1p + k0);
        } else {
            const float* a0p = (const float*)A + (size_t)row0 * K + kg * 8;
            const float* a1p = (const float*)A + (size_t)row1 * K + kg * 8;
            float af[2][8];
            *reinterpret_cast<float4*>(&af[0][0]) = *reinterpret_cast<const float4*>(a0p + k0);
            *reinterpret_cast<float4*>(&af[0][4]) = *reinterpret_cast<const float4*>(a0p + k0 + 4);
            *reinterpret_cast<float4*>(&af[1][0]) = *reinterpret_cast<const float4*>(a1p + k0);
            *reinterpret_cast<float4*>(&af[1][4]) = *reinterpret_cast<const float4*>(a1p + k0 + 4);
            #pragma unroll
            for (int mi = 0; mi < 2; ++mi)
                #pragma unroll
                for (int j = 0; j < 8; ++j) a[mi][j] = f2bf(af[mi][j]);
        }
        #pragma unroll
        for (int nt = 0; nt < NT; ++nt) {
            bf16x8 b = *reinterpret_cast<const bf16x8*>(bp + (size_t)nt * 16 * K + k0);
            acc[0][nt] = __builtin_amdgcn_mfma_f32_16x16x32_bf16(a[0], b, acc[0][nt], 0, 0, 0);
            acc[1][nt] = __builtin_amdgcn_mfma_f32_16x16x32_bf16(a[1], b, acc[1][nt], 0, 0, 0);
        }
    }
    #pragma unroll
    for (int mi = 0; mi < 2; ++mi) {
        int rowb = m_base + mi * 16 + kg * 4;
        if (MODE == 0) {
            #pragma unroll
            for (int nt = 0; nt < NT - 1; ++nt) {
                int col = nt * 16 + lm;
                #pragma unroll
                for (int r = 0; r < 4; ++r) {
                    int row = rowb + r;
                    if (row < M) hsb[(size_t)row * HC + col] = (ushort)f2bf(acc[mi][nt][r]);
                }
            }
            // last tile: cols 0-3 = src logits (bf16), 4-7 = dst logits (fp32)
            #pragma unroll
            for (int r = 0; r < 4; ++r) {
                int row = rowb + r;
                if (row < M) {
                    float v = acc[mi][NT - 1][r];
                    if (lm < 4) atts[(size_t)row * 4 + lm] = (ushort)f2bf(v);
                    else if (lm < 8) attd[(size_t)row * 4 + (lm - 4)] = v;
                }
            }
        } else {
            #pragma unroll
            for (int nt = 0; nt < NT; ++nt) {
                int col = nt * 16 + lm;
                float bv = bias[col];
                #pragma unroll
                for (int r = 0; r < 4; ++r) {
                    int row = rowb + r;
                    if (row < M) C[(size_t)row * ldc + col] = acc[mi][nt][r] + bv;
                }
            }
        }
    }
}

// ---------------- P1a: per-block window histogram (LDS, no global atomics) --
__global__ __launch_bounds__(256) void part_count_k(
    const int* __restrict__ d0, int E0,
    const int* __restrict__ d1, int E1, int Nm,
    int* __restrict__ cntmat, int NB1) {
    __shared__ int lh[WPART];
    int t = threadIdx.x;
    lh[t] = 0;
    __syncthreads();
    int base = blockIdx.x * EPB + t;
    #pragma unroll
    for (int j = 0; j < EPB / 256; ++j) {
        int e = base + j * 256;
        int key = -1;
        if (e < E0) key = d0[e];
        else if (e - E0 < E1) key = Nm + d1[e - E0];
        if (key >= 0) atomicAdd(&lh[key >> 9], 1);
    }
    __syncthreads();
    cntmat[(size_t)t * NB1 + blockIdx.x] = lh[t];
}

// ---------------- P1b: scatter (src,key) into window partitions -------------
__global__ __launch_bounds__(256) void part_scatter_k(
    const int* __restrict__ s0, const int* __restrict__ d0, int E0,
    const int* __restrict__ s1, const int* __restrict__ d1, int E1, int Nm,
    const int* __restrict__ scanned, int NB1, int2* __restrict__ buf) {
    __shared__ int lb[WPART];
    __shared__ int lc[WPART];
    int t = threadIdx.x;
    lb[t] = scanned[(size_t)t * NB1 + blockIdx.x];
    lc[t] = 0;
    __syncthreads();
    int base = blockIdx.x * EPB + t;
    #pragma unroll
    for (int j = 0; j < EPB / 256; ++j) {
        int e = base + j * 256;
        int key = -1, src = 0;
        if (e < E0) { key = d0[e]; src = s0[e]; }
        else if (e - E0 < E1) { key = Nm + d1[e - E0]; src = s1[e - E0]; }
        if (key >= 0) {
            int w = key >> 9;
            int r = atomicAdd(&lc[w], 1);
            buf[lb[w] + r] = make_int2(src, key);
        }
    }
}

// ---------------- P2: per-window counting sort -> rs + csr ------------------
__global__ __launch_bounds__(512) void csort_k(
    const int2* __restrict__ buf, const int* __restrict__ scanned, int NB1,
    int E, int NK, int* __restrict__ rs, int* __restrict__ csr) {
    __shared__ int c1[512];
    __shared__ int ls[512];
    int b = blockIdx.x;
    int t = threadIdx.x;
    int lo = scanned[(size_t)b * NB1];
    int hi = (b + 1 < WPART) ? scanned[(size_t)(b + 1) * NB1] : E;
    int keylo = b << 9;
    c1[t] = 0;
    __syncthreads();
    for (int i = lo + t; i < hi; i += 512)
        atomicAdd(&c1[buf[i].y - keylo], 1);
    __syncthreads();
    // exclusive scan of c1 -> ls
    int v = c1[t];
    ls[t] = v;
    __syncthreads();
    for (int off = 1; off < 512; off <<= 1) {
        int x = (t >= off) ? ls[t - off] : 0;
        __syncthreads();
        ls[t] += x;
        __syncthreads();
    }
    ls[t] -= v;            // exclusive
    int gk = keylo + t;
    if (gk <= NK) rs[gk] = lo + ls[t];
    c1[t] = 0;             // reuse as slot counters
    __syncthreads();
    for (int i = lo + t; i < hi; i += 512) {
        int2 p = buf[i];
        int k = p.y - keylo;
        int r = atomicAdd(&c1[k], 1);
        csr[lo + ls[k] + r] = p.x;
    }
}

// ---------------- scan helpers (exclusive, 3-kernel) -------------------------
__global__ void scan_block_k(const int* __restrict__ deg, int n,
                             int* __restrict__ out, int* __restrict__ partial) {
    __shared__ int s[256];
    int i = blockIdx.x * 256 + threadIdx.x;
    int v = (i < n) ? deg[i] : 0;
    s[threadIdx.x] = v;
    __syncthreads();
    for (int off = 1; off < 256; off <<= 1) {
        int x = (threadIdx.x >= off) ? s[threadIdx.x - off] : 0;
        __syncthreads();
        s[threadIdx.x] += x;
        __syncthreads();
    }
    if (i < n) out[i] = s[threadIdx.x] - v;
    if (threadIdx.x == 255) partial[blockIdx.x] = s[255];
}

__global__ void scan_partial_k(int* __restrict__ partial, int nb) {
    __shared__ int s[512];
    int t = threadIdx.x;
    int v = (t < nb) ? partial[t] : 0;
    s[t] = v;
    __syncthreads();
    for (int off = 1; off < 512; off <<= 1) {
        int x = (t >= off) ? s[t - off] : 0;
        __syncthreads();
        s[t] += x;
        __syncthreads();
    }
    if (t < nb) partial[t] = s[t] - v;
}

__global__ void add_off_k(int* __restrict__ out, const int* __restrict__ partial, int n) {
    int i = blockIdx.x * 256 + threadIdx.x;
    if (i < n) out[i] += partial[blockIdx.x];
}

// ---------------- per-dst aggregation: 16 lanes/node, ushort8 loads ---------
// Lane c in [0,16): channels 8c..8c+7 (16B load); head h = c>>2.
// PROJ: block deposits its 16 node-rows (bf16) into padded LDS [16][136],
// barriers once, then 4 waves MFMA 16x64x128 against Wbo and write OU/OM.
template <bool WF32, bool WBF, bool PROJ>
__global__ __launch_bounds__(256) void agg16_dual_k(
    const int* __restrict__ rs0, const int* __restrict__ csr0,
    const ushort* __restrict__ hsb0, const ushort* __restrict__ atts0,
    const float* __restrict__ attd0, const float* __restrict__ bias0,
    float* __restrict__ out0, ushort* __restrict__ outb0, int n0,
    const int* __restrict__ rs1, const int* __restrict__ csr1,
    const ushort* __restrict__ hsb1, const ushort* __restrict__ atts1,
    const float* __restrict__ attd1, const float* __restrict__ bias1,
    float* __restrict__ out1, ushort* __restrict__ outb1, int n1,
    const ushort* __restrict__ Wbo, const float* __restrict__ bo,
    float* __restrict__ pj0, float* __restrict__ pj1) {
    int g = (int)((blockIdx.x * 256u + threadIdx.x) >> 4);   // 16 nodes/block
    int gl = (threadIdx.x >> 4) & 15;                        // slot in block
    const int* rs; const int* csr; const ushort* hsb; const ushort* atts;
    const float* attd; const float* bias; float* out; ushort* outb;
    int node; bool active = true;
    if (g < n0) {
        rs = rs0; csr = csr0; hsb = hsb0; atts = atts0; attd = attd0;
        bias = bias0; out = out0; outb = outb0; node = g;
    } else {
        node = g - n0;
        if (node >= n1) { active = false; node = 0; }
        rs = rs1; csr = csr1; hsb = hsb1; atts = atts1; attd = attd1;
        bias = bias1; out = out1; outb = outb1;
    }
    int c = threadIdx.x & 15;    // channels 8c..8c+7
    int h = c >> 2;              // head (32 ch per head, 4 lanes per head)
    float ad = attd[node * 4 + h];
    int s0 = 0, s1 = 0;
    if (active) { s0 = rs[node]; s1 = rs[node + 1]; }
    float acc[8] = {};
    float wsum = 0.f;
    int i = s0;
    for (; i + 4 <= s1; i += 4) {            // 4 edge-rows in flight
        int sx[4];
        #pragma unroll
        for (int j = 0; j < 4; ++j) sx[j] = csr[i + j];
        bf16x8 hv[4]; float el[4];
        #pragma unroll
        for (int j = 0; j < 4; ++j) {
            hv[j] = *reinterpret_cast<const bf16x8*>(hsb + (size_t)sx[j] * HC + 8 * c);
            el[j] = bf2f(atts[(size_t)sx[j] * 4 + h]);
        }
        #pragma unroll
        for (int j = 0; j < 4; ++j) {
            float e = el[j] + ad;
            e = e > 0.f ? e : 0.2f * e;
            float w = __expf(e);
            wsum += w;
            #pragma unroll
            for (int k = 0; k < 8; ++k)
                acc[k] = fmaf(w, bf2f((ushort)hv[j][k]), acc[k]);
        }
    }
    for (; i < s1; ++i) {
        int src = csr[i];
        bf16x8 hv = *reinterpret_cast<const bf16x8*>(hsb + (size_t)src * HC + 8 * c);
        float e = bf2f(atts[(size_t)src * 4 + h]) + ad;
        e = e > 0.f ? e : 0.2f * e;
        float w = __expf(e);
        wsum += w;
        #pragma unroll
        for (int k = 0; k < 8; ++k)
            acc[k] = fmaf(w, bf2f((ushort)hv[k]), acc[k]);
    }
    float inv = 1.f / (wsum + 1e-16f);
    float v[8];
    #pragma unroll
    for (int k = 0; k < 8; ++k) {
        v[k] = fmaf(acc[k], inv, bias[8 * c + k]);
        v[k] = v[k] > 0.f ? v[k] : 0.01f * v[k];
    }
    if (active && WF32) {
        float4 o0 = make_float4(v[0], v[1], v[2], v[3]);
        float4 o1 = make_float4(v[4], v[5], v[6], v[7]);
        reinterpret_cast<float4*>(out + (size_t)node * HC + 8 * c)[0] = o0;
        reinterpret_cast<float4*>(out + (size_t)node * HC + 8 * c)[1] = o1;
    }
    if (active && WBF) {
        bf16x8 u;
        #pragma unroll
        for (int k = 0; k < 8; ++k) u[k] = f2bf(v[k]);
        *reinterpret_cast<bf16x8*>(outb + (size_t)node * HC + 8 * c) = u;
    }
    if constexpr (PROJ) {
        __shared__ ushort As[16][136];   // +8 pad: 2-way bank alias (free)
        bf16x8 u;
        #pragma unroll
        for (int k = 0; k < 8; ++k) u[k] = active ? f2bf(v[k]) : (short)0;
        *reinterpret_cast<bf16x8*>(&As[gl][8 * c]) = u;
        __syncthreads();
        int lane = threadIdx.x & 63;
        int wv = threadIdx.x >> 6;       // wave -> output col tile (0..3)
        int lm = lane & 15;              // B row (output col in tile)
        int kg = lane >> 4;              // k-group
        int col = wv * 16 + lm;
        const ushort* bp = Wbo + (size_t)col * HC + kg * 8;
        f32x4 pacc = {};
        #pragma unroll
        for (int k0 = 0; k0 < HC; k0 += 32) {
            bf16x8 a = *reinterpret_cast<const bf16x8*>(&As[lm][k0 + kg * 8]);
            bf16x8 b = *reinterpret_cast<const bf16x8*>(bp + k0);
            pacc = __builtin_amdgcn_mfma_f32_16x16x32_bf16(a, b, pacc, 0, 0, 0);
        }
        float bv = bo[col];
        int blockBase = blockIdx.x * 16;
        #pragma unroll
        for (int r = 0; r < 4; ++r) {
            int slot = kg * 4 + r;
            int ng = blockBase + slot;
            if (ng < n0) pj0[(size_t)ng * 64 + col] = pacc[r] + bv;
            else if (ng - n0 < n1) pj1[(size_t)(ng - n0) * 64 + col] = pacc[r] + bv;
        }
    }
}

// ---------------------------------------------------------------------------
extern "C" void kernel_launch(void* const* d_in, const int* in_sizes, int n_in,
                              void* d_out, int out_size, void* d_ws, size_t ws_size,
                              hipStream_t stream) {
    const int Nu = in_sizes[0];
    const int Nm = in_sizes[1];
    const int E1 = in_sizes[2];   // um edges
    const int E2 = in_sizes[4];   // mu edges
    const int D  = in_sizes[6] / Nu;   // 64
    const int O  = in_sizes[27];       // 64
    const int E  = E1 + E2;
    const int NK = Nm + Nu;       // combined key range

    const int*   user_ids  = (const int*)d_in[0];
    const int*   movie_ids = (const int*)d_in[1];
    const int*   um_src    = (const int*)d_in[2];
    const int*   um_dst    = (const int*)d_in[3];
    const int*   mu_src    = (const int*)d_in[4];
    const int*   mu_dst    = (const int*)d_in[5];
    const float* user_emb  = (const float*)d_in[6];
    const float* movie_emb = (const float*)d_in[7];
    const float* l1_um_Wsrc = (const float*)d_in[8];
    const float* l1_um_Wdst = (const float*)d_in[9];
    const float* l1_um_asrc = (const float*)d_in[10];
    const float* l1_um_adst = (const float*)d_in[11];
    const float* l1_um_b    = (const float*)d_in[12];
    const float* l1_mu_Wsrc = (const float*)d_in[13];
    const float* l1_mu_Wdst = (const float*)d_in[14];
    const float* l1_mu_asrc = (const float*)d_in[15];
    const float* l1_mu_adst = (const float*)d_in[16];
    const float* l1_mu_b    = (const float*)d_in[17];
    const float* l2_um_W    = (const float*)d_in[18];
    const float* l2_um_asrc = (const float*)d_in[19];
    const float* l2_um_adst = (const float*)d_in[20];
    const float* l2_um_b    = (const float*)d_in[21];
    const float* l2_mu_W    = (const float*)d_in[22];
    const float* l2_mu_asrc = (const float*)d_in[23];
    const float* l2_mu_adst = (const float*)d_in[24];
    const float* l2_mu_b    = (const float*)d_in[25];
    const float* Wo         = (const float*)d_in[26];
    const float* bo         = (const float*)d_in[27];

    auto cdiv = [](int a, int b) { return (a + b - 1) / b; };
    const int NB1 = cdiv(E, EPB);            // partition blocks
    const int CM  = WPART * NB1;             // count matrix size

    // ---- workspace carve ----
    char* p = (char*)d_ws;
    auto alloc = [&](size_t bytes) { void* r = p; p += (bytes + 255) & ~(size_t)255; return r; };
    ushort* hs_u = (ushort*)alloc((size_t)Nu * HC * 2);
    ushort* hs_m = (ushort*)alloc((size_t)Nm * HC * 2);
    ushort* XUb  = (ushort*)alloc((size_t)Nu * HC * 2);
    ushort* XMb  = (ushort*)alloc((size_t)Nm * HC * 2);
    ushort* atts_u = (ushort*)alloc((size_t)Nu * 4 * 2);   // bf16 src logits
    ushort* atts_m = (ushort*)alloc((size_t)Nm * 4 * 2);
    float* attd_u = (float*)alloc((size_t)Nu * 4 * 4);
    float* attd_m = (float*)alloc((size_t)Nm * 4 * 4);
    float* V_u1  = (float*)alloc((size_t)HC * 8 * 4);
    float* V_m1  = (float*)alloc((size_t)HC * 8 * 4);
    float* V_u2  = (float*)alloc((size_t)HC * 8 * 4);
    float* V_m2  = (float*)alloc((size_t)HC * 8 * 4);
    ushort* Wb_u1 = (ushort*)alloc((size_t)144 * D * 2);
    ushort* Wb_m1 = (ushort*)alloc((size_t)144 * D * 2);
    ushort* Wb_u2 = (ushort*)alloc((size_t)144 * HC * 2);
    ushort* Wb_m2 = (ushort*)alloc((size_t)144 * HC * 2);
    ushort* Wb_o  = (ushort*)alloc((size_t)64 * HC * 2);
    int* rs      = (int*)alloc((size_t)(NK + 2) * 4);      // combined row starts
    int* cntmat  = (int*)alloc((size_t)(CM + 256) * 4);
    int* scanned = (int*)alloc((size_t)(CM + 256) * 4);
    int2* buf    = (int2*)alloc((size_t)E * 8);            // (src,key) pairs
    int* csr     = (int*)alloc((size_t)E * 4);             // combined csr
    int* part    = (int*)alloc(1024 * 4);

    // ---- fold attention + pack weights (x-independent) ----
    {
        VT vt;
        const float* Ws[8] = {l1_um_Wsrc, l1_mu_Wdst, l1_mu_Wsrc, l1_um_Wdst,
                              l2_um_W, l2_mu_W, l2_mu_W, l2_um_W};
        const float* as[8] = {l1_um_asrc, l1_mu_adst, l1_mu_asrc, l1_um_adst,
                              l2_um_asrc, l2_mu_adst, l2_mu_asrc, l2_um_adst};
        float* vs[8] = {V_u1, V_u1, V_m1, V_m1, V_u2, V_u2, V_m2, V_m2};
        for (int i = 0; i < 8; ++i) { vt.W[i] = Ws[i]; vt.a[i] = as[i]; vt.v[i] = vs[i]; }
        make_v_all_k<<<12, 256, 0, stream>>>(vt);

        PT pt;
        const float* pW[5] = {l1_um_Wsrc, l1_mu_Wsrc, l2_um_W, l2_mu_W, Wo};
        const float* pV[5] = {V_u1, V_m1, V_u2, V_m2, nullptr};
        ushort* pB[5] = {Wb_u1, Wb_m1, Wb_u2, Wb_m2, Wb_o};
        int pK[5] = {D, D, HC, HC, HC};
        int pN[5] = {HC, HC, HC, HC, 64};
        int cum = 0;
        for (int i = 0; i < 5; ++i) {
            pt.W[i] = pW[i]; pt.V[i] = pV[i]; pt.Wb[i] = pB[i];
            pt.K[i] = pK[i]; pt.Nw[i] = pN[i];
            pt.start[i] = cum;
            cum += (i < 4 ? 144 : 64) * pK[i];
        }
        pt.start[5] = cum;
        pack_all_k<<<cdiv(cum, 256), 256, 0, stream>>>(pt);
    }

    // ---- CSR build via LDS counting sort (zero global atomics) ----
    part_count_k<<<NB1, 256, 0, stream>>>(um_dst, E1, mu_dst, E2, Nm, cntmat, NB1);
    {
        int nb = cdiv(CM, 256);
        scan_block_k<<<nb, 256, 0, stream>>>(cntmat, CM, scanned, part);
        scan_partial_k<<<1, 512, 0, stream>>>(part, nb);
        add_off_k<<<nb, 256, 0, stream>>>(scanned, part, CM);
    }
    part_scatter_k<<<NB1, 256, 0, stream>>>(um_src, um_dst, E1, mu_src, mu_dst, E2,
                                            Nm, scanned, NB1, buf);
    csort_k<<<WPART, 512, 0, stream>>>(buf, scanned, NB1, E, NK, rs, csr);

    // output slots: [out_user | out_movie | xu | xm]
    float* OU = (float*)d_out;
    float* OM = OU + (size_t)Nu * O;
    float* XU = OM + (size_t)Nm * O;
    float* XM = XU + (size_t)Nu * HC;

    int gbU = cdiv(Nu, 128), gbM = cdiv(Nm, 128);
    int aggBlocks = cdiv((Nm + Nu) * 16, 256);

    // ---- layer 1: A = fp32 embeddings (gathered), K = D ----
    gemm_dual_k<9, 0, false><<<gbU + gbM, 256, 0, stream>>>(
        user_emb, user_ids, Wb_u1, hs_u, atts_u, attd_u, nullptr, nullptr, Nu, gbU,
        movie_emb, movie_ids, Wb_m1, hs_m, atts_m, attd_m, nullptr, nullptr, Nm,
        D, 0);
    // layer-1 agg: bf16 activations only (fp32 slot would be overwritten by L2)
    agg16_dual_k<false, true, false><<<aggBlocks, 256, 0, stream>>>(
        rs, csr, hs_u, atts_u, attd_m, l1_um_b, nullptr, XMb, Nm,
        rs + Nm, csr, hs_m, atts_m, attd_u, l1_mu_b, nullptr, XUb, Nu,
        nullptr, nullptr, nullptr, nullptr);

    // ---- layer 2: A = bf16 activations, K = HC ----
    gemm_dual_k<9, 0, true><<<gbU + gbM, 256, 0, stream>>>(
        XUb, nullptr, Wb_u2, hs_u, atts_u, attd_u, nullptr, nullptr, Nu, gbU,
        XMb, nullptr, Wb_m2, hs_m, atts_m, attd_m, nullptr, nullptr, Nm,
        HC, 0);
    // layer-2 agg: fp32 xu/xm outputs + FUSED final projection (OU/OM)
    agg16_dual_k<true, false, true><<<aggBlocks, 256, 0, stream>>>(
        rs, csr, hs_u, atts_u, attd_m, l2_um_b, XM, nullptr, Nm,
        rs + Nm, csr, hs_m, atts_m, attd_u, l2_mu_b, XU, nullptr, Nu,
        Wb_o, bo, OM, OU);
}

// Round 17
// 206.079 us; speedup vs baseline: 4.9267x; 1.0143x over previous
//
#include <hip/hip_runtime.h>
#include <hip/hip_bf16.h>
#include <cstdint>

// ---------------------------------------------------------------------------
// HGAT: 2-layer hetero GAT (user<->movie), H=4 heads, C=32, HC=128.
// Layer-1 GEMM on bf16 MFMA 16x16x32 (folded attention V appended -> hs+att
// in one pass). CSR build: zero-global-atomic LDS counting sort (r15).
// MEGA-FUSION (r16/r17): both agg kernels have idle MFMA/VALU pipes
// (MfmaUtil 1%, VALUBusy 35%), so dense epilogues ride along per block:
//   agg1 + GEMM2: block computes 16 activation rows -> LDS [16][136] ->
//     9-tile MFMA vs Wb_{m2,u2} -> writes layer-2 hs + atts + attd directly.
//     XUb/XMb intermediates (31MB write + 31MB read) and the 30us gemm2
//     dispatch are eliminated. L1/L2 hs+att arrays double-buffered (race).
//   agg2 + PROJ: same pattern vs Wb_o -> writes OU/OM (r16, validated).
// Edge aggregation: CSR by dst, 16 lanes/node, ushort8 loads; src logits
// bf16 (L2-resident). Blocks are type-pure (movie blocks, then user blocks).
// REVERTED (net-negative): degree-sort perm (r9/10), src-windowed CSR (r11),
// hist-GEMM fusion (r13/14: returning-atomic floor can't be hidden).
// Softmax max-subtraction skipped (logits bounded; shift-invariant; validated).
// ---------------------------------------------------------------------------

#define HC 128
#define HH 4
#define WPART 256       // key windows (key>>9, covers keys < 131072)
#define EPB 2048        // edges per partition block

typedef __attribute__((ext_vector_type(8))) short bf16x8;
typedef __attribute__((ext_vector_type(4))) float f32x4;

__device__ __forceinline__ short f2bf(float f) {
    return __builtin_bit_cast(short, __float2bfloat16(f));
}
__device__ __forceinline__ float bf2f(ushort u) {
    return __builtin_bit_cast(float, ((unsigned)u) << 16);
}

// ---------------- fold attention: v[k, coff+h] = sum_c W[k,h*32+c]*a[h,c] ---
struct VT { const float* W[8]; const float* a[8]; float* v[8]; };
__global__ void make_v_all_k(VT t) {
    int gid = blockIdx.x * 256 + threadIdx.x;
    int task, base;
    if (gid < 1024) { task = gid >> 8; base = gid & 255; }
    else if (gid < 3072) { int g = gid - 1024; task = 4 + (g >> 9); base = g & 511; }
    else return;
    int k = base >> 2, h = base & 3;
    int coff = (task & 1) * 4;
    const float* wr = t.W[task] + (size_t)k * HC + h * 32;
    const float* ar = t.a[task] + h * 32;
    float s = 0.f;
    #pragma unroll
    for (int c = 0; c < 32; ++c) s = fmaf(wr[c], ar[c], s);
    t.v[task][k * 8 + coff + h] = s;
}

// ---------------- pack Wb[n][k] = bf16(W[k][n]); rows Nw..Nw+7 = V ----------
struct PT { const float* W[5]; const float* V[5]; ushort* Wb[5];
            int K[5]; int Nw[5]; int start[6]; };
__global__ void pack_all_k(PT t) {
    int gid = blockIdx.x * 256 + threadIdx.x;
    if (gid >= t.start[5]) return;
    int task = 0;
    while (gid >= t.start[task + 1]) ++task;
    int loc = gid - t.start[task];
    int K = t.K[task], Nw = t.Nw[task];
    int n = loc / K, k = loc % K;
    float v = 0.f;
    if (n < Nw) v = t.W[task][(size_t)k * Nw + n];
    else if (t.V[task] != nullptr && n < Nw + 8) v = t.V[task][k * 8 + (n - Nw)];
    t.Wb[task][loc] = (ushort)f2bf(v);
}

// ---------------- dual-segment bf16 MFMA GEMM (layer 1 only now) ------------
// MODE 0: hs out (bf16 [M,128]) + atts bf16 [M,4] + attd fp32 [M,4].
template <int NT, int MODE, bool ABF>
__global__ __launch_bounds__(256) void gemm_dual_k(
    const void* A0, const int* idx0, const ushort* Wb0, ushort* hsb0,
    ushort* atts0, float* attd0, float* C0, const float* bias0, int M0, int nb0,
    const void* A1, const int* idx1, const ushort* Wb1, ushort* hsb1,
    ushort* atts1, float* attd1, float* C1, const float* bias1, int M1,
    int K, int ldc) {
    const void* A; const int* aidx; const ushort* Wb; ushort* hsb;
    ushort* atts; float* attd; float* C; const float* bias; int M, bid;
    if ((int)blockIdx.x < nb0) {
        A = A0; aidx = idx0; Wb = Wb0; hsb = hsb0; atts = atts0; attd = attd0;
        C = C0; bias = bias0; M = M0; bid = blockIdx.x;
    } else {
        A = A1; aidx = idx1; Wb = Wb1; hsb = hsb1; atts = atts1; attd = attd1;
        C = C1; bias = bias1; M = M1; bid = blockIdx.x - nb0;
    }
    int lane = threadIdx.x & 63;
    int wave = threadIdx.x >> 6;
    int m_base = bid * 128 + wave * 32;
    int lm = lane & 15;      // A row-in-tile / C col-in-tile
    int kg = lane >> 4;      // k-group (8 consecutive k)

    int r0 = m_base + lm, r1 = r0 + 16;
    int cr0 = r0 < M ? r0 : M - 1;
    int cr1 = r1 < M ? r1 : M - 1;
    int row0 = aidx ? aidx[cr0] : cr0;
    int row1 = aidx ? aidx[cr1] : cr1;
    const ushort* bp = Wb + (size_t)lm * K + kg * 8;

    f32x4 acc[2][NT] = {};
    for (int k0 = 0; k0 < K; k0 += 32) {
        bf16x8 a[2];
        if (ABF) {
            const ushort* a0p = (const ushort*)A + (size_t)row0 * K + kg * 8;
            const ushort* a1p = (const ushort*)A + (size_t)row1 * K + kg * 8;
            a[0] = *reinterpret_cast<const bf16x8*>(a0p + k0);
            a[1] = *reinterpret_cast<const bf16x8*>(a1p + k0);
        } else {
            const float* a0p = (const float*)A + (size_t)row0 * K + kg * 8;
            const float* a1p = (const float*)A + (size_t)row1 * K + kg * 8;
            float af[2][8];
            *reinterpret_cast<float4*>(&af[0][0]) = *reinterpret_cast<const float4*>(a0p + k0);
            *reinterpret_cast<float4*>(&af[0][4]) = *reinterpret_cast<const float4*>(a0p + k0 + 4);
            *reinterpret_cast<float4*>(&af[1][0]) = *reinterpret_cast<const float4*>(a1p + k0);
            *reinterpret_cast<float4*>(&af[1][4]) = *reinterpret_cast<const float4*>(a1p + k0 + 4);
            #pragma unroll
            for (int mi = 0; mi < 2; ++mi)
                #pragma unroll
                for (int j = 0; j < 8; ++j) a[mi][j] = f2bf(af[mi][j]);
        }
        #pragma unroll
        for (int nt = 0; nt < NT; ++nt) {
            bf16x8 b = *reinterpret_cast<const bf16x8*>(bp + (size_t)nt * 16 * K + k0);
            acc[0][nt] = __builtin_amdgcn_mfma_f32_16x16x32_bf16(a[0], b, acc[0][nt], 0, 0, 0);
            acc[1][nt] = __builtin_amdgcn_mfma_f32_16x16x32_bf16(a[1], b, acc[1][nt], 0, 0, 0);
        }
    }
    #pragma unroll
    for (int mi = 0; mi < 2; ++mi) {
        int rowb = m_base + mi * 16 + kg * 4;
        if (MODE == 0) {
            #pragma unroll
            for (int nt = 0; nt < NT - 1; ++nt) {
                int col = nt * 16 + lm;
                #pragma unroll
                for (int r = 0; r < 4; ++r) {
                    int row = rowb + r;
                    if (row < M) hsb[(size_t)row * HC + col] = (ushort)f2bf(acc[mi][nt][r]);
                }
            }
            #pragma unroll
            for (int r = 0; r < 4; ++r) {
                int row = rowb + r;
                if (row < M) {
                    float v = acc[mi][NT - 1][r];
                    if (lm < 4) atts[(size_t)row * 4 + lm] = (ushort)f2bf(v);
                    else if (lm < 8) attd[(size_t)row * 4 + (lm - 4)] = v;
                }
            }
        } else {
            #pragma unroll
            for (int nt = 0; nt < NT; ++nt) {
                int col = nt * 16 + lm;
                float bv = bias[col];
                #pragma unroll
                for (int r = 0; r < 4; ++r) {
                    int row = rowb + r;
                    if (row < M) C[(size_t)row * ldc + col] = acc[mi][nt][r] + bv;
                }
            }
        }
    }
}

// ---------------- P1a: per-block window histogram (LDS, no global atomics) --
__global__ __launch_bounds__(256) void part_count_k(
    const int* __restrict__ d0, int E0,
    const int* __restrict__ d1, int E1, int Nm,
    int* __restrict__ cntmat, int NB1) {
    __shared__ int lh[WPART];
    int t = threadIdx.x;
    lh[t] = 0;
    __syncthreads();
    int base = blockIdx.x * EPB + t;
    #pragma unroll
    for (int j = 0; j < EPB / 256; ++j) {
        int e = base + j * 256;
        int key = -1;
        if (e < E0) key = d0[e];
        else if (e - E0 < E1) key = Nm + d1[e - E0];
        if (key >= 0) atomicAdd(&lh[key >> 9], 1);
    }
    __syncthreads();
    cntmat[(size_t)t * NB1 + blockIdx.x] = lh[t];
}

// ---------------- P1b: scatter (src,key) into window partitions -------------
__global__ __launch_bounds__(256) void part_scatter_k(
    const int* __restrict__ s0, const int* __restrict__ d0, int E0,
    const int* __restrict__ s1, const int* __restrict__ d1, int E1, int Nm,
    const int* __restrict__ scanned, int NB1, int2* __restrict__ buf) {
    __shared__ int lb[WPART];
    __shared__ int lc[WPART];
    int t = threadIdx.x;
    lb[t] = scanned[(size_t)t * NB1 + blockIdx.x];
    lc[t] = 0;
    __syncthreads();
    int base = blockIdx.x * EPB + t;
    #pragma unroll
    for (int j = 0; j < EPB / 256; ++j) {
        int e = base + j * 256;
        int key = -1, src = 0;
        if (e < E0) { key = d0[e]; src = s0[e]; }
        else if (e - E0 < E1) { key = Nm + d1[e - E0]; src = s1[e - E0]; }
        if (key >= 0) {
            int w = key >> 9;
            int r = atomicAdd(&lc[w], 1);
            buf[lb[w] + r] = make_int2(src, key);
        }
    }
}

// ---------------- P2: per-window counting sort -> rs + csr ------------------
__global__ __launch_bounds__(512) void csort_k(
    const int2* __restrict__ buf, const int* __restrict__ scanned, int NB1,
    int E, int NK, int* __restrict__ rs, int* __restrict__ csr) {
    __shared__ int c1[512];
    __shared__ int ls[512];
    int b = blockIdx.x;
    int t = threadIdx.x;
    int lo = scanned[(size_t)b * NB1];
    int hi = (b + 1 < WPART) ? scanned[(size_t)(b + 1) * NB1] : E;
    int keylo = b << 9;
    c1[t] = 0;
    __syncthreads();
    for (int i = lo + t; i < hi; i += 512)
        atomicAdd(&c1[buf[i].y - keylo], 1);
    __syncthreads();
    int v = c1[t];
    ls[t] = v;
    __syncthreads();
    for (int off = 1; off < 512; off <<= 1) {
        int x = (t >= off) ? ls[t - off] : 0;
        __syncthreads();
        ls[t] += x;
        __syncthreads();
    }
    ls[t] -= v;            // exclusive
    int gk = keylo + t;
    if (gk <= NK) rs[gk] = lo + ls[t];
    c1[t] = 0;             // reuse as slot counters
    __syncthreads();
    for (int i = lo + t; i < hi; i += 512) {
        int2 p = buf[i];
        int k = p.y - keylo;
        int r = atomicAdd(&c1[k], 1);
        csr[lo + ls[k] + r] = p.x;
    }
}

// ---------------- scan helpers (exclusive, 3-kernel) -------------------------
__global__ void scan_block_k(const int* __restrict__ deg, int n,
                             int* __restrict__ out, int* __restrict__ partial) {
    __shared__ int s[256];
    int i = blockIdx.x * 256 + threadIdx.x;
    int v = (i < n) ? deg[i] : 0;
    s[threadIdx.x] = v;
    __syncthreads();
    for (int off = 1; off < 256; off <<= 1) {
        int x = (threadIdx.x >= off) ? s[threadIdx.x - off] : 0;
        __syncthreads();
        s[threadIdx.x] += x;
        __syncthreads();
    }
    if (i < n) out[i] = s[threadIdx.x] - v;
    if (threadIdx.x == 255) partial[blockIdx.x] = s[255];
}

__global__ void scan_partial_k(int* __restrict__ partial, int nb) {
    __shared__ int s[512];
    int t = threadIdx.x;
    int v = (t < nb) ? partial[t] : 0;
    s[t] = v;
    __syncthreads();
    for (int off = 1; off < 512; off <<= 1) {
        int x = (t >= off) ? s[t - off] : 0;
        __syncthreads();
        s[t] += x;
        __syncthreads();
    }
    if (t < nb) partial[t] = s[t] - v;
}

__global__ void add_off_k(int* __restrict__ out, const int* __restrict__ partial, int n) {
    int i = blockIdx.x * 256 + threadIdx.x;
    if (i < n) out[i] += partial[blockIdx.x];
}

// ---------------- fused per-dst aggregation ---------------------------------
// 16 lanes/node, ushort8 loads; blocks are type-pure: [0, blocksM) = type 0
// (movie dst), rest = type 1 (user dst).
// GEMM2: after gather, block's 16 activation rows -> LDS -> 9-tile MFMA vs
//   W2 (layer-2 weights + folded V) -> writes hs2 + atts2 + attd2 directly.
// PROJ: same pattern vs Wbo (4 tiles) -> writes final outputs pj.
template <bool WF32, bool PROJ, bool GEMM2>
__global__ __launch_bounds__(256) void agg16_dual_k(
    const int* __restrict__ rs0, const int* __restrict__ csr0,
    const ushort* __restrict__ hsb0, const ushort* __restrict__ atts0,
    const float* __restrict__ attd0, const float* __restrict__ bias0,
    float* __restrict__ out0, int n0,
    const int* __restrict__ rs1, const int* __restrict__ csr1,
    const ushort* __restrict__ hsb1, const ushort* __restrict__ atts1,
    const float* __restrict__ attd1, const float* __restrict__ bias1,
    float* __restrict__ out1, int n1,
    const ushort* __restrict__ Wbo, const float* __restrict__ bo,
    float* __restrict__ pj0, float* __restrict__ pj1,
    const ushort* __restrict__ W2_0, ushort* __restrict__ hs2_0,
    ushort* __restrict__ atts2_0, float* __restrict__ attd2_0,
    const ushort* __restrict__ W2_1, ushort* __restrict__ hs2_1,
    ushort* __restrict__ atts2_1, float* __restrict__ attd2_1) {
    int blocksM = (n0 + 15) >> 4;
    bool ty1 = (int)blockIdx.x >= blocksM;
    int base = ty1 ? ((int)blockIdx.x - blocksM) * 16 : (int)blockIdx.x * 16;
    int gl = threadIdx.x >> 4;       // node slot 0..15
    int c  = threadIdx.x & 15;       // channels 8c..8c+7
    int h  = c >> 2;                 // head
    const int* rs = ty1 ? rs1 : rs0;
    const int* csr = ty1 ? csr1 : csr0;
    const ushort* hsb = ty1 ? hsb1 : hsb0;
    const ushort* atts = ty1 ? atts1 : atts0;
    const float* attd = ty1 ? attd1 : attd0;
    const float* bias = ty1 ? bias1 : bias0;
    int n = ty1 ? n1 : n0;
    int node = base + gl;
    bool active = node < n;
    int nodeC = active ? node : 0;

    float ad = attd[nodeC * 4 + h];
    int s0 = 0, s1 = 0;
    if (active) { s0 = rs[nodeC]; s1 = rs[nodeC + 1]; }
    float acc[8] = {};
    float wsum = 0.f;
    int i = s0;
    for (; i + 4 <= s1; i += 4) {            // 4 edge-rows in flight
        int sx[4];
        #pragma unroll
        for (int j = 0; j < 4; ++j) sx[j] = csr[i + j];
        bf16x8 hv[4]; float el[4];
        #pragma unroll
        for (int j = 0; j < 4; ++j) {
            hv[j] = *reinterpret_cast<const bf16x8*>(hsb + (size_t)sx[j] * HC + 8 * c);
            el[j] = bf2f(atts[(size_t)sx[j] * 4 + h]);
        }
        #pragma unroll
        for (int j = 0; j < 4; ++j) {
            float e = el[j] + ad;
            e = e > 0.f ? e : 0.2f * e;
            float w = __expf(e);
            wsum += w;
            #pragma unroll
            for (int k = 0; k < 8; ++k)
                acc[k] = fmaf(w, bf2f((ushort)hv[j][k]), acc[k]);
        }
    }
    for (; i < s1; ++i) {
        int src = csr[i];
        bf16x8 hv = *reinterpret_cast<const bf16x8*>(hsb + (size_t)src * HC + 8 * c);
        float e = bf2f(atts[(size_t)src * 4 + h]) + ad;
        e = e > 0.f ? e : 0.2f * e;
        float w = __expf(e);
        wsum += w;
        #pragma unroll
        for (int k = 0; k < 8; ++k)
            acc[k] = fmaf(w, bf2f((ushort)hv[k]), acc[k]);
    }
    float inv = 1.f / (wsum + 1e-16f);
    float v[8];
    #pragma unroll
    for (int k = 0; k < 8; ++k) {
        v[k] = fmaf(acc[k], inv, bias[8 * c + k]);
        v[k] = v[k] > 0.f ? v[k] : 0.01f * v[k];
    }
    if (WF32 && active) {
        float* out = ty1 ? out1 : out0;
        float4 o0 = make_float4(v[0], v[1], v[2], v[3]);
        float4 o1 = make_float4(v[4], v[5], v[6], v[7]);
        reinterpret_cast<float4*>(out + (size_t)node * HC + 8 * c)[0] = o0;
        reinterpret_cast<float4*>(out + (size_t)node * HC + 8 * c)[1] = o1;
    }
    if constexpr (PROJ || GEMM2) {
        __shared__ ushort As[16][136];   // +8 pad
        bf16x8 u;
        #pragma unroll
        for (int k = 0; k < 8; ++k) u[k] = active ? f2bf(v[k]) : (short)0;
        *reinterpret_cast<bf16x8*>(&As[gl][8 * c]) = u;
        __syncthreads();
        int lane = threadIdx.x & 63;
        int wv = threadIdx.x >> 6;       // wave
        int lm = lane & 15;
        int kg = lane >> 4;
        if constexpr (PROJ) {
            int col = wv * 16 + lm;
            const ushort* bp = Wbo + (size_t)col * HC + kg * 8;
            f32x4 pacc = {};
            #pragma unroll
            for (int k0 = 0; k0 < HC; k0 += 32) {
                bf16x8 a = *reinterpret_cast<const bf16x8*>(&As[lm][k0 + kg * 8]);
                bf16x8 b = *reinterpret_cast<const bf16x8*>(bp + k0);
                pacc = __builtin_amdgcn_mfma_f32_16x16x32_bf16(a, b, pacc, 0, 0, 0);
            }
            float bv = bo[col];
            float* pj = ty1 ? pj1 : pj0;
            #pragma unroll
            for (int r = 0; r < 4; ++r) {
                int nd = base + kg * 4 + r;
                if (nd < n) pj[(size_t)nd * 64 + col] = pacc[r] + bv;
            }
        }
        if constexpr (GEMM2) {
            const ushort* W2 = ty1 ? W2_1 : W2_0;
            ushort* hs2 = ty1 ? hs2_1 : hs2_0;
            ushort* atts2 = ty1 ? atts2_1 : atts2_0;
            float* attd2 = ty1 ? attd2_1 : attd2_0;
            #pragma unroll
            for (int ti = 0; ti < 3; ++ti) {
                int t = wv + ti * 4;             // tiles wv, wv+4, wv+8
                if (t > 8) break;                // only wave 0 does tile 8
                int col = t * 16 + lm;
                const ushort* bp = W2 + (size_t)col * HC + kg * 8;
                f32x4 gacc = {};
                #pragma unroll
                for (int k0 = 0; k0 < HC; k0 += 32) {
                    bf16x8 a = *reinterpret_cast<const bf16x8*>(&As[lm][k0 + kg * 8]);
                    bf16x8 b = *reinterpret_cast<const bf16x8*>(bp + k0);
                    gacc = __builtin_amdgcn_mfma_f32_16x16x32_bf16(a, b, gacc, 0, 0, 0);
                }
                #pragma unroll
                for (int r = 0; r < 4; ++r) {
                    int nd = base + kg * 4 + r;
                    if (nd < n) {
                        if (t < 8) {
                            hs2[(size_t)nd * HC + col] = (ushort)f2bf(gacc[r]);
                        } else {
                            if (lm < 4) atts2[(size_t)nd * 4 + lm] = (ushort)f2bf(gacc[r]);
                            else if (lm < 8) attd2[(size_t)nd * 4 + (lm - 4)] = gacc[r];
                        }
                    }
                }
            }
        }
    }
}

// ---------------------------------------------------------------------------
extern "C" void kernel_launch(void* const* d_in, const int* in_sizes, int n_in,
                              void* d_out, int out_size, void* d_ws, size_t ws_size,
                              hipStream_t stream) {
    const int Nu = in_sizes[0];
    const int Nm = in_sizes[1];
    const int E1 = in_sizes[2];   // um edges
    const int E2 = in_sizes[4];   // mu edges
    const int D  = in_sizes[6] / Nu;   // 64
    const int O  = in_sizes[27];       // 64
    const int E  = E1 + E2;
    const int NK = Nm + Nu;       // combined key range

    const int*   user_ids  = (const int*)d_in[0];
    const int*   movie_ids = (const int*)d_in[1];
    const int*   um_src    = (const int*)d_in[2];
    const int*   um_dst    = (const int*)d_in[3];
    const int*   mu_src    = (const int*)d_in[4];
    const int*   mu_dst    = (const int*)d_in[5];
    const float* user_emb  = (const float*)d_in[6];
    const float* movie_emb = (const float*)d_in[7];
    const float* l1_um_Wsrc = (const float*)d_in[8];
    const float* l1_um_Wdst = (const float*)d_in[9];
    const float* l1_um_asrc = (const float*)d_in[10];
    const float* l1_um_adst = (const float*)d_in[11];
    const float* l1_um_b    = (const float*)d_in[12];
    const float* l1_mu_Wsrc = (const float*)d_in[13];
    const float* l1_mu_Wdst = (const float*)d_in[14];
    const float* l1_mu_asrc = (const float*)d_in[15];
    const float* l1_mu_adst = (const float*)d_in[16];
    const float* l1_mu_b    = (const float*)d_in[17];
    const float* l2_um_W    = (const float*)d_in[18];
    const float* l2_um_asrc = (const float*)d_in[19];
    const float* l2_um_adst = (const float*)d_in[20];
    const float* l2_um_b    = (const float*)d_in[21];
    const float* l2_mu_W    = (const float*)d_in[22];
    const float* l2_mu_asrc = (const float*)d_in[23];
    const float* l2_mu_adst = (const float*)d_in[24];
    const float* l2_mu_b    = (const float*)d_in[25];
    const float* Wo         = (const float*)d_in[26];
    const float* bo         = (const float*)d_in[27];

    auto cdiv = [](int a, int b) { return (a + b - 1) / b; };
    const int NB1 = cdiv(E, EPB);            // partition blocks
    const int CM  = WPART * NB1;             // count matrix size

    // ---- workspace carve ----
    char* p = (char*)d_ws;
    auto alloc = [&](size_t bytes) { void* r = p; p += (bytes + 255) & ~(size_t)255; return r; };
    ushort* hs_u  = (ushort*)alloc((size_t)Nu * HC * 2);   // layer-1 hs
    ushort* hs_m  = (ushort*)alloc((size_t)Nm * HC * 2);
    ushort* hs_u2 = (ushort*)alloc((size_t)Nu * HC * 2);   // layer-2 hs
    ushort* hs_m2 = (ushort*)alloc((size_t)Nm * HC * 2);
    ushort* atts_u  = (ushort*)alloc((size_t)Nu * 4 * 2);  // L1 src logits
    ushort* atts_m  = (ushort*)alloc((size_t)Nm * 4 * 2);
    ushort* atts_u2 = (ushort*)alloc((size_t)Nu * 4 * 2);  // L2 src logits
    ushort* atts_m2 = (ushort*)alloc((size_t)Nm * 4 * 2);
    float* attd_u  = (float*)alloc((size_t)Nu * 4 * 4);
    float* attd_m  = (float*)alloc((size_t)Nm * 4 * 4);
    float* attd_u2 = (float*)alloc((size_t)Nu * 4 * 4);
    float* attd_m2 = (float*)alloc((size_t)Nm * 4 * 4);
    float* V_u1  = (float*)alloc((size_t)HC * 8 * 4);
    float* V_m1  = (float*)alloc((size_t)HC * 8 * 4);
    float* V_u2  = (float*)alloc((size_t)HC * 8 * 4);
    float* V_m2  = (float*)alloc((size_t)HC * 8 * 4);
    ushort* Wb_u1 = (ushort*)alloc((size_t)144 * D * 2);
    ushort* Wb_m1 = (ushort*)alloc((size_t)144 * D * 2);
    ushort* Wb_u2 = (ushort*)alloc((size_t)144 * HC * 2);
    ushort* Wb_m2 = (ushort*)alloc((size_t)144 * HC * 2);
    ushort* Wb_o  = (ushort*)alloc((size_t)64 * HC * 2);
    int* rs      = (int*)alloc((size_t)(NK + 2) * 4);
    int* cntmat  = (int*)alloc((size_t)(CM + 256) * 4);
    int* scanned = (int*)alloc((size_t)(CM + 256) * 4);
    int2* buf    = (int2*)alloc((size_t)E * 8);
    int* csr     = (int*)alloc((size_t)E * 4);
    int* part    = (int*)alloc(1024 * 4);

    // ---- fold attention + pack weights (x-independent) ----
    {
        VT vt;
        const float* Ws[8] = {l1_um_Wsrc, l1_mu_Wdst, l1_mu_Wsrc, l1_um_Wdst,
                              l2_um_W, l2_mu_W, l2_mu_W, l2_um_W};
        const float* as[8] = {l1_um_asrc, l1_mu_adst, l1_mu_asrc, l1_um_adst,
                              l2_um_asrc, l2_mu_adst, l2_mu_asrc, l2_um_adst};
        float* vs[8] = {V_u1, V_u1, V_m1, V_m1, V_u2, V_u2, V_m2, V_m2};
        for (int i = 0; i < 8; ++i) { vt.W[i] = Ws[i]; vt.a[i] = as[i]; vt.v[i] = vs[i]; }
        make_v_all_k<<<12, 256, 0, stream>>>(vt);

        PT pt;
        const float* pW[5] = {l1_um_Wsrc, l1_mu_Wsrc, l2_um_W, l2_mu_W, Wo};
        const float* pV[5] = {V_u1, V_m1, V_u2, V_m2, nullptr};
        ushort* pB[5] = {Wb_u1, Wb_m1, Wb_u2, Wb_m2, Wb_o};
        int pK[5] = {D, D, HC, HC, HC};
        int pN[5] = {HC, HC, HC, HC, 64};
        int cum = 0;
        for (int i = 0; i < 5; ++i) {
            pt.W[i] = pW[i]; pt.V[i] = pV[i]; pt.Wb[i] = pB[i];
            pt.K[i] = pK[i]; pt.Nw[i] = pN[i];
            pt.start[i] = cum;
            cum += (i < 4 ? 144 : 64) * pK[i];
        }
        pt.start[5] = cum;
        pack_all_k<<<cdiv(cum, 256), 256, 0, stream>>>(pt);
    }

    // ---- CSR build via LDS counting sort (zero global atomics) ----
    part_count_k<<<NB1, 256, 0, stream>>>(um_dst, E1, mu_dst, E2, Nm, cntmat, NB1);
    {
        int nb = cdiv(CM, 256);
        scan_block_k<<<nb, 256, 0, stream>>>(cntmat, CM, scanned, part);
        scan_partial_k<<<1, 512, 0, stream>>>(part, nb);
        add_off_k<<<nb, 256, 0, stream>>>(scanned, part, CM);
    }
    part_scatter_k<<<NB1, 256, 0, stream>>>(um_src, um_dst, E1, mu_src, mu_dst, E2,
                                            Nm, scanned, NB1, buf);
    csort_k<<<WPART, 512, 0, stream>>>(buf, scanned, NB1, E, NK, rs, csr);

    // output slots: [out_user | out_movie | xu | xm]
    float* OU = (float*)d_out;
    float* OM = OU + (size_t)Nu * O;
    float* XU = OM + (size_t)Nm * O;
    float* XM = XU + (size_t)Nu * HC;

    int gbU = cdiv(Nu, 128), gbM = cdiv(Nm, 128);
    int aggBlocks = cdiv(Nm, 16) + cdiv(Nu, 16);

    // ---- layer 1: A = fp32 embeddings (gathered), K = D ----
    gemm_dual_k<9, 0, false><<<gbU + gbM, 256, 0, stream>>>(
        user_emb, user_ids, Wb_u1, hs_u, atts_u, attd_u, nullptr, nullptr, Nu, gbU,
        movie_emb, movie_ids, Wb_m1, hs_m, atts_m, attd_m, nullptr, nullptr, Nm,
        D, 0);
    // layer-1 agg FUSED with layer-2 GEMM: writes hs2/atts2/attd2 directly
    agg16_dual_k<false, false, true><<<aggBlocks, 256, 0, stream>>>(
        rs, csr, hs_u, atts_u, attd_m, l1_um_b, nullptr, Nm,
        rs + Nm, csr, hs_m, atts_m, attd_u, l1_mu_b, nullptr, Nu,
        nullptr, nullptr, nullptr, nullptr,
        Wb_m2, hs_m2, atts_m2, attd_m2,      // type 0 (movie activations)
        Wb_u2, hs_u2, atts_u2, attd_u2);     // type 1 (user activations)

    // layer-2 agg: fp32 xu/xm outputs + FUSED final projection (OU/OM)
    agg16_dual_k<true, true, false><<<aggBlocks, 256, 0, stream>>>(
        rs, csr, hs_u2, atts_u2, attd_m2, l2_um_b, XM, Nm,
        rs + Nm, csr, hs_m2, atts_m2, attd_u2, l2_mu_b, XU, Nu,
        Wb_o, bo, OM, OU,
        nullptr, nullptr, nullptr, nullptr,
        nullptr, nullptr, nullptr, nullptr);
}